// Round 1
// baseline (1154.921 us; speedup 1.0000x reference)
//
#include <hip/hip_runtime.h>
#include <hip/hip_bf16.h>

// Problem constants
constexpr int Bn  = 8;
constexpr int Cn  = 192;   // hidden channels
constexpr int Tn  = 1024;  // sequence length
constexpr int Hn  = 2;     // heads
constexpr int DKn = 96;    // head dim
constexpr int FCn = 768;   // filter channels
constexpr int Ln  = 6;     // layers
constexpr int WINn = 4;    // rel-attn window
constexpr int QKS = 384;   // QK transposed row stride (Q|K concat)
constexpr int NSPLIT = 4;  // attention s-split (flash-decoding)
constexpr int RN  = Bn * Hn * Tn;  // 16384 attention rows

typedef __hip_bfloat16 bf16;
typedef __attribute__((ext_vector_type(8))) short short8;
typedef __attribute__((ext_vector_type(4))) float f32x4;

// ---------------------------------------------------------------------------
// One-time transforms
__global__ void cast_bf(const float* __restrict__ src, bf16* __restrict__ dst, int n) {
    int i = blockIdx.x * 256 + threadIdx.x;
    if (i < n) dst[i] = __float2bfloat16(src[i]);
}

// w [L][CO][CIN][3] -> [L][3][CO][CIN] bf16
__global__ void reorder_w(const float* __restrict__ src, bf16* __restrict__ dst,
                          int CO, int CIN) {
    int i = blockIdx.x * 256 + threadIdx.x;
    int n = Ln * 3 * CO * CIN;
    if (i >= n) return;
    int c = i % CIN;
    int f = (i / CIN) % CO;
    int ko = (i / (CIN * CO)) % 3;
    int l = i / (3 * CIN * CO);
    dst[i] = __float2bfloat16(src[(((size_t)(l * CO + f)) * CIN + c) * 3 + ko]);
}

// erk fp32 [L][9][96] -> bf16 [L][16][96], rows 9..15 zero (MFMA B-frag ready)
__global__ void erk_prep(const float* __restrict__ src, bf16* __restrict__ dst) {
    int i = blockIdx.x * 256 + threadIdx.x;       // < Ln*16*96
    if (i >= Ln * 16 * 96) return;
    int d = i % 96, row = (i / 96) % 16, l = i / (96 * 16);
    float v = (row < 9) ? src[((size_t)l * 9 + row) * 96 + d] : 0.f;
    dst[i] = __float2bfloat16(v);
}

// Build fused QKV weight [L][576][C] bf16 (qscale folded into Q) + bias fp32
__global__ void qkv_prep(const float* __restrict__ Wq, const float* __restrict__ Wk,
                         const float* __restrict__ Wv, const float* __restrict__ bq,
                         const float* __restrict__ bk, const float* __restrict__ bv,
                         bf16* __restrict__ Wout, float* __restrict__ bout, float qscale) {
    int i = blockIdx.x * 256 + threadIdx.x;
    const int nW = Ln * 576 * Cn;
    if (i < nW) {
        int c = i % Cn, f = (i / Cn) % 576, l = i / (Cn * 576);
        float v;
        if (f < 192)      v = Wq[((size_t)l * Cn + f) * Cn + c] * qscale;
        else if (f < 384) v = Wk[((size_t)l * Cn + f - 192) * Cn + c];
        else              v = Wv[((size_t)l * Cn + f - 384) * Cn + c];
        Wout[i] = __float2bfloat16(v);
    } else if (i < nW + Ln * 576) {
        int j = i - nW, f = j % 576, l = j / 576;
        float v;
        if (f < 192)      v = bq[l * Cn + f] * qscale;
        else if (f < 384) v = bk[l * Cn + f - 192];
        else              v = bv[l * Cn + f - 384];
        bout[j] = v;
    }
}

// ---------------------------------------------------------------------------
// Input: X = x*mask (fp32, NCT) + XT = bf16 transposed [b][t][c]
__global__ __launch_bounds__(256) void cvt_in_k(
        const float* __restrict__ x, const float* __restrict__ mask,
        float* __restrict__ X, bf16* __restrict__ XT) {
    __shared__ float tile[Cn][33];
    const int tid = threadIdx.x, lane = tid & 31, w = tid >> 5;
    const int b = blockIdx.x >> 5;
    const int t0 = (blockIdx.x & 31) * 32;
    const float mk = mask[b * Tn + t0 + lane];
    for (int c = w; c < Cn; c += 8) {
        float v = x[((b * Cn + c) * Tn) + t0 + lane] * mk;
        X[((b * Cn + c) * Tn) + t0 + lane] = v;
        tile[c][lane] = v;
    }
    __syncthreads();
    for (int idx = tid; idx < 32 * Cn; idx += 256) {
        int tl = idx / Cn, c = idx % Cn;
        XT[((size_t)b * Tn + t0 + tl) * Cn + c] = __float2bfloat16(tile[c][tl]);
    }
}

// ---------------------------------------------------------------------------
// MFMA conv1d, LDS-staged (m97 structure) — R12 winner, unchanged.
// MODE 0: fp32 NCT out (+bias, *mask if mask!=null)
// MODE 2: bf16 transposed [b][t][CO] out relu(+bias)*mask   [FFN1]
// MODE 4: QKV split: f<384 -> bf16 T (stride QKS) into Y0; else bf16 NCT Y1
// MODE 5: fp32 NCT K-split partial, NO bias: ks==0 -> Y0, ks==1 -> Y1 [FFN2]
template <int KS, int TT, int MODE, int NSP>
__global__ __launch_bounds__(256) void conv_mfma(
        const bf16* __restrict__ Xt, const bf16* __restrict__ W,
        const float* __restrict__ bias, const float* __restrict__ mask,
        void* __restrict__ Y0, void* __restrict__ Y1, int CIN, int CO) {
    constexpr int PAD = KS / 2;
    constexpr int NMB = TT / 16;
    constexpr int AR  = TT + KS - 1;   // A rows staged
    constexpr int RS  = 72;            // padded row stride (bf16 cols)
    __shared__ bf16 As[AR][RS];
    __shared__ bf16 Bs[KS][64][RS];

    const int tid = threadIdx.x;
    const int wv = tid >> 6, lane = tid & 63;
    const int m = lane & 15, kq = lane >> 4;
    const int b = blockIdx.z / NSP, ks = blockIdx.z % NSP;
    const int t0 = blockIdx.x * TT;
    const int f0 = blockIdx.y * 64;
    const int f = f0 + wv * 16 + m;

    const bf16* xb = Xt + (size_t)b * Tn * CIN;
    const size_t wko = (size_t)CO * CIN;

    f32x4 acc[NMB] = {};

    const int cbeg = ks * (CIN / NSP);
    const int cend = cbeg + CIN / NSP;
    for (int c0 = cbeg; c0 < cend; c0 += 64) {
        __syncthreads();   // previous chunk's fragment reads complete
        for (int s = tid; s < AR * 8; s += 256) {
            int r = s >> 3, cs = (s & 7) * 8;
            int gt = t0 + r - PAD;
            short8 v = {0, 0, 0, 0, 0, 0, 0, 0};
            if (PAD == 0 || (unsigned)gt < (unsigned)Tn)
                v = *(const short8*)(xb + (size_t)gt * CIN + c0 + cs);
            *(short8*)&As[r][cs] = v;
        }
        for (int s = tid; s < KS * 512; s += 256) {
            int ko = s >> 9, r = (s >> 3) & 63, cs = (s & 7) * 8;
            short8 v = *(const short8*)(W + (size_t)ko * wko + (size_t)(f0 + r) * CIN + c0 + cs);
            *(short8*)&Bs[ko][r][cs] = v;
        }
        __syncthreads();   // staged data visible
#pragma unroll
        for (int kk = 0; kk < 2; ++kk)
#pragma unroll
            for (int ko = 0; ko < KS; ++ko) {
                short8 bfr = *(const short8*)&Bs[ko][wv * 16 + m][kk * 32 + kq * 8];
#pragma unroll
                for (int mb = 0; mb < NMB; ++mb) {
                    short8 afr = *(const short8*)&As[mb * 16 + m + ko][kk * 32 + kq * 8];
                    acc[mb] = __builtin_amdgcn_mfma_f32_16x16x32_bf16(afr, bfr, acc[mb], 0, 0, 0);
                }
            }
    }

    if (MODE == 5) {
        float* Y = (float*)(ks ? Y1 : Y0) + ((size_t)b * CO + f) * Tn;
#pragma unroll
        for (int mb = 0; mb < NMB; ++mb) {
            int t = t0 + mb * 16 + kq * 4;
            float4 o;
            o.x = acc[mb][0]; o.y = acc[mb][1]; o.z = acc[mb][2]; o.w = acc[mb][3];
            *(float4*)(Y + t) = o;
        }
        return;
    }
    const float bs = bias[f];
    if (MODE == 0) {
        float* Y = (float*)Y0 + ((size_t)b * CO + f) * Tn;
#pragma unroll
        for (int mb = 0; mb < NMB; ++mb) {
            int t = t0 + mb * 16 + kq * 4;
            float4 o;
            o.x = acc[mb][0] + bs; o.y = acc[mb][1] + bs;
            o.z = acc[mb][2] + bs; o.w = acc[mb][3] + bs;
            if (mask) {
                o.x *= mask[b * Tn + t];     o.y *= mask[b * Tn + t + 1];
                o.z *= mask[b * Tn + t + 2]; o.w *= mask[b * Tn + t + 3];
            }
            *(float4*)(Y + t) = o;
        }
    } else if (MODE == 2) {
        bf16* Y = (bf16*)Y0;
#pragma unroll
        for (int mb = 0; mb < NMB; ++mb)
#pragma unroll
            for (int r = 0; r < 4; ++r) {
                int t = t0 + mb * 16 + kq * 4 + r;
                float v = fmaxf(acc[mb][r] + bs, 0.f) * mask[b * Tn + t];
                Y[((size_t)b * Tn + t) * CO + f] = __float2bfloat16(v);
            }
    } else {  // MODE 4
        if (blockIdx.y < 6) {          // Q|K -> transposed, stride QKS
            bf16* Y = (bf16*)Y0;
#pragma unroll
            for (int mb = 0; mb < NMB; ++mb)
#pragma unroll
                for (int r = 0; r < 4; ++r) {
                    int t = t0 + mb * 16 + kq * 4 + r;
                    Y[((size_t)b * Tn + t) * QKS + f] = __float2bfloat16(acc[mb][r] + bs);
                }
        } else {                        // V -> bf16 NCT
            bf16* Y = (bf16*)Y1 + ((size_t)b * Cn + f - 384) * Tn;
#pragma unroll
            for (int mb = 0; mb < NMB; ++mb) {
                int t = t0 + mb * 16 + kq * 4;
                bf16 tmp[4];
#pragma unroll
                for (int r = 0; r < 4; ++r) tmp[r] = __float2bfloat16(acc[mb][r] + bs);
                *(uint2*)(Y + t) = *(uint2*)tmp;
            }
        }
    }
}

// ---------------------------------------------------------------------------
// MFMA flash attention, split-K over s, FIXED-MAX softmax, BARRIER-FREE.
// K/V chunks are tiny (12 KB each) and L2-resident (re-read by the 16
// t0-blocks of a panel), so LDS staging was pure serialization overhead
// (Common-mistake #7): B-frags for QK^T and PV are now loaded DIRECTLY
// from global (each frag-load = 16 rows x 64 B segments, full L2 lines).
// No __syncthreads remain — only per-wave LDS (rq band, pT transpose).
// V frags are prefetched into registers before the softmax VALU block so
// their L2 latency hides under exp/shuffle work.
// Block swizzle: 1024 = 8 XCD x 128; the 16 t0-blocks sharing one
// (b,h,sp) K/V-panel land on ONE XCD -> per-XCD L2 working set ~0.8 MB.
// Writes UNNORMALIZED partials: Op bf16 [sp][rid][96], Lp fp32 [sp][rid].
__global__ __launch_bounds__(256) void attn_mfma(
        const bf16* __restrict__ QK, const bf16* __restrict__ V,
        const float* __restrict__ mask, const bf16* __restrict__ erkb,
        const float* __restrict__ erv, bf16* __restrict__ Op,
        float* __restrict__ Lp, int layer) {
    __shared__ float rq[4][16][17];   // per-wave rel-K band: [m][dd]
    __shared__ bf16 pT[4][16][68];    // per-wave P: [m][s]

    const int tid = threadIdx.x, wv = tid >> 6, lane = tid & 63;
    const int col = lane & 15, quad = lane >> 4;
    // XCD-bijective swizzle (id%8 = XCD round-robin assumption, perf-only)
    const int w = (blockIdx.x & 7) * 128 + (blockIdx.x >> 3);
    const int t0 = (w & 15) * 64;
    const int yz = w >> 4;            // = h + 2*z of the old 3D grid
    const int h = yz & 1;
    const int z = yz >> 1;
    const int b = z >> 2, sp = z & 3;
    const int hd = h * DKn;
    const int t0w = t0 + wv * 16;

    // Q A-frags (persist): A[m=col][k=quad*8+j+32*kd]
    short8 aq[3];
    {
        const bf16* qrow = QK + ((size_t)b * Tn + t0w + col) * QKS + hd + quad * 8;
#pragma unroll
        for (int kd = 0; kd < 3; ++kd) aq[kd] = *(const short8*)(qrow + kd * 32);
    }
    // rel-K band via MFMA: R = Q . erk^T  (B rows 9..15 are zero)
    {
        const bf16* erow = erkb + ((size_t)layer * 16 + col) * 96 + quad * 8;
        f32x4 R = {};
#pragma unroll
        for (int kd = 0; kd < 3; ++kd) {
            short8 be = *(const short8*)(erow + kd * 32);
            R = __builtin_amdgcn_mfma_f32_16x16x32_bf16(aq[kd], be, R, 0, 0, 0);
        }
#pragma unroll
        for (int r = 0; r < 4; ++r) rq[wv][quad * 4 + r][col] = R[r];
    }
    float mtv[4];
#pragma unroll
    for (int r = 0; r < 4; ++r) mtv[r] = mask[b * Tn + t0w + quad * 4 + r];

    float lrow[4] = {};
    f32x4 O[6] = {};
    const float* ervl = erv + (size_t)layer * 9 * DKn;

    // lane-fixed base pointers for direct B-frag loads
    const bf16* kcol = QK + ((size_t)b * Tn + col) * QKS + 192 + hd + quad * 8;
    const bf16* vcol = V + ((size_t)(b * Cn + hd + col)) * Tn + quad * 8;

    const int sbeg = sp * (Tn / NSPLIT);
    const int send = sbeg + Tn / NSPLIT;
    for (int s0 = sbeg; s0 < send; s0 += 64) {
        // S = Q K^T, B-frags straight from global (L2-hot panel)
        f32x4 S[4] = {};
#pragma unroll
        for (int nb = 0; nb < 4; ++nb)
#pragma unroll
            for (int kd = 0; kd < 3; ++kd) {
                short8 bkf = *(const short8*)(kcol + (size_t)(s0 + 16 * nb) * QKS + kd * 32);
                S[nb] = __builtin_amdgcn_mfma_f32_16x16x32_bf16(aq[kd], bkf, S[nb], 0, 0, 0);
            }

        // prefetch V B-frags now — independent of softmax, L2 latency
        // hides under the exp/shuffle VALU work below
        short8 vf[12];
#pragma unroll
        for (int nd = 0; nd < 6; ++nd)
#pragma unroll
            for (int kk = 0; kk < 2; ++kk)
                vf[nd * 2 + kk] = *(const short8*)(vcol + (size_t)nd * 16 * Tn + s0 + kk * 32);

#pragma unroll
        for (int nb = 0; nb < 4; ++nb) {
            const int sg = s0 + 16 * nb + col;
            const float msv = mask[b * Tn + sg];
#pragma unroll
            for (int r = 0; r < 4; ++r) {
                const int tq = t0w + quad * 4 + r;
                float v = S[nb][r];
                int dd = sg - tq + WINn;
                if (dd >= 0 && dd <= 2 * WINn) v += rq[wv][quad * 4 + r][dd];
                if (msv * mtv[r] == 0.f) v = -1e4f;
                S[nb][r] = v;
            }
        }

        // fixed-max softmax: P = exp(S); row-sum via 16-lane shuffle reduce
        float psum[4] = {};
#pragma unroll
        for (int nb = 0; nb < 4; ++nb)
#pragma unroll
            for (int r = 0; r < 4; ++r) {
                bf16 pb = __float2bfloat16(__expf(S[nb][r]));
                pT[wv][quad * 4 + r][16 * nb + col] = pb;
                psum[r] += __bfloat162float(pb);
            }
#pragma unroll
        for (int r = 0; r < 4; ++r) {
#pragma unroll
            for (int mk2 = 1; mk2 < 16; mk2 <<= 1) psum[r] += __shfl_xor(psum[r], mk2);
            lrow[r] += psum[r];
        }

        // P A-frags from per-wave LDS; PV with prefetched V B-frags
        short8 aP[2];
#pragma unroll
        for (int kk = 0; kk < 2; ++kk)
            aP[kk] = *(const short8*)&pT[wv][col][kk * 32 + quad * 8];
#pragma unroll
        for (int nd = 0; nd < 6; ++nd)
#pragma unroll
            for (int kk = 0; kk < 2; ++kk)
                O[nd] = __builtin_amdgcn_mfma_f32_16x16x32_bf16(aP[kk], vf[nd * 2 + kk], O[nd], 0, 0, 0);

        // rel-V on diagonal chunks
        if (s0 <= t0w + 15 + WINn && s0 + 63 >= t0w - WINn) {
#pragma unroll
            for (int r = 0; r < 4; ++r) {
                const int tq = t0w + quad * 4 + r;
                for (int dd = 0; dd <= 2 * WINn; ++dd) {
                    int sg = tq + dd - WINn;
                    if (sg >= s0 && sg < s0 + 64) {
                        float p = __bfloat162float(pT[wv][quad * 4 + r][sg - s0]);
#pragma unroll
                        for (int nd = 0; nd < 6; ++nd)
                            O[nd][r] += p * ervl[dd * DKn + 16 * nd + col];
                    }
                }
            }
        }
    }

    // epilogue: write unnormalized partials
    const int rbase = (b * Hn + h) * Tn + t0w;
#pragma unroll
    for (int r = 0; r < 4; ++r) {
        const int rid = rbase + quad * 4 + r;
        bf16* dst = Op + ((size_t)sp * RN + rid) * 96 + col;
#pragma unroll
        for (int nd = 0; nd < 6; ++nd)
            dst[16 * nd] = __float2bfloat16(O[nd][r]);
        if (col == 0) Lp[sp * RN + rid] = lrow[r];
    }
}

// Combine split partials -> AT bf16 [b][t][C]. One thread per (rid, 8-chan).
__global__ __launch_bounds__(256) void attn_combine(
        const bf16* __restrict__ Op, const float* __restrict__ Lp,
        bf16* __restrict__ AT) {
    int i = blockIdx.x * 256 + threadIdx.x;       // < RN*12
    int rid = i / 12, j = i - rid * 12;
    float denom = 0.f;
    float o[8] = {};
#pragma unroll
    for (int s = 0; s < NSPLIT; ++s) {
        denom += Lp[s * RN + rid];
        short8 v = *(const short8*)(Op + ((size_t)s * RN + rid) * 96 + j * 8);
        const bf16* vb = (const bf16*)&v;
#pragma unroll
        for (int e = 0; e < 8; ++e) o[e] += __bfloat162float(vb[e]);
    }
    float inv = 1.f / fmaxf(denom, 1e-30f);
    int t = rid & (Tn - 1), h = (rid >> 10) & (Hn - 1), b = rid >> 11;
    bf16 outv[8];
#pragma unroll
    for (int e = 0; e < 8; ++e) outv[e] = __float2bfloat16(o[e] * inv);
    *(uint4*)(AT + ((size_t)b * Tn + t) * Cn + h * DKn + j * 8) = *(uint4*)outv;
}

// ---------------------------------------------------------------------------
// Residual add + LayerNorm over channels. X <- LN(X+Y)*g+b (fp32) and
// XT <- bf16 transposed [b][t][C], optionally *mask.
__global__ __launch_bounds__(256) void ln_k(
        float* __restrict__ X, const float* __restrict__ Y,
        const float* __restrict__ G, const float* __restrict__ Bt,
        const float* __restrict__ mask, bf16* __restrict__ XT, int apply_mask) {
    __shared__ float tile[Cn][33];
    __shared__ float r1[8][32];
    __shared__ float r2[8][32];
    const int tid = threadIdx.x;
    const int lane = tid & 31, w = tid >> 5;
    const int b = blockIdx.x >> 5;
    const int t0 = (blockIdx.x & 31) * 32;
    const int t = t0 + lane;

    float s1 = 0.f, s2 = 0.f;
    for (int c = w; c < Cn; c += 8) {
        float v = X[((b * Cn + c) * Tn) + t] + Y[((b * Cn + c) * Tn) + t];
        tile[c][lane] = v;
        s1 += v;
        s2 += v * v;
    }
    r1[w][lane] = s1;
    r2[w][lane] = s2;
    __syncthreads();
    if (w == 0) {
        float a = 0.f, q = 0.f;
        for (int i = 0; i < 8; ++i) { a += r1[i][lane]; q += r2[i][lane]; }
        float m = a / Cn;
        float var = q / Cn - m * m;
        r1[0][lane] = m;
        r2[0][lane] = rsqrtf(var + 1e-5f);
    }
    __syncthreads();
    const float m = r1[0][lane], rs = r2[0][lane];
    for (int c = w; c < Cn; c += 8) {
        float y = (tile[c][lane] - m) * rs * G[c] + Bt[c];
        X[((b * Cn + c) * Tn) + t] = y;
        tile[c][lane] = y;
    }
    __syncthreads();
    for (int idx = tid; idx < 32 * Cn; idx += 256) {
        int tl = idx / Cn, c = idx % Cn;
        float v = tile[c][tl];
        if (apply_mask) v *= mask[b * Tn + t0 + tl];
        XT[((size_t)b * Tn + t0 + tl) * Cn + c] = __float2bfloat16(v);
    }
}

// FFN2-combine + residual + LN2: Y = (P0+P1+bias)*mask; Xn = LN(X+Y)*g+b.
// OUT==null: X <- Xn, XT <- bf16(Xn).  OUT!=null (last layer): OUT <- Xn*mask.
__global__ __launch_bounds__(256) void ln_ffn2(
        float* __restrict__ X, const float* __restrict__ P0,
        const float* __restrict__ P1, const float* __restrict__ bias,
        const float* __restrict__ G, const float* __restrict__ Bt,
        const float* __restrict__ mask, bf16* __restrict__ XT,
        float* __restrict__ OUT) {
    __shared__ float tile[Cn][33];
    __shared__ float r1[8][32];
    __shared__ float r2[8][32];
    const int tid = threadIdx.x;
    const int lane = tid & 31, w = tid >> 5;
    const int b = blockIdx.x >> 5;
    const int t0 = (blockIdx.x & 31) * 32;
    const int t = t0 + lane;
    const float mk = mask[b * Tn + t];

    float s1 = 0.f, s2 = 0.f;
    for (int c = w; c < Cn; c += 8) {
        size_t i = ((size_t)b * Cn + c) * Tn + t;
        float y = (P0[i] + P1[i] + bias[c]) * mk;
        float v = X[i] + y;
        tile[c][lane] = v;
        s1 += v;
        s2 += v * v;
    }
    r1[w][lane] = s1;
    r2[w][lane] = s2;
    __syncthreads();
    if (w == 0) {
        float a = 0.f, q = 0.f;
        for (int i = 0; i < 8; ++i) { a += r1[i][lane]; q += r2[i][lane]; }
        float m = a / Cn;
        float var = q / Cn - m * m;
        r1[0][lane] = m;
        r2[0][lane] = rsqrtf(var + 1e-5f);
    }
    __syncthreads();
    const float m = r1[0][lane], rs = r2[0][lane];
    if (OUT) {   // final layer: write output = LN(...)*mask directly, done
        for (int c = w; c < Cn; c += 8) {
            float y = (tile[c][lane] - m) * rs * G[c] + Bt[c];
            OUT[((b * Cn + c) * Tn) + t] = y * mk;
        }
        return;
    }
    for (int c = w; c < Cn; c += 8) {
        float y = (tile[c][lane] - m) * rs * G[c] + Bt[c];
        X[((b * Cn + c) * Tn) + t] = y;
        tile[c][lane] = y;
    }
    __syncthreads();
    for (int idx = tid; idx < 32 * Cn; idx += 256) {
        int tl = idx / Cn, c = idx % Cn;
        XT[((size_t)b * Tn + t0 + tl) * Cn + c] = __float2bfloat16(tile[c][tl]);
    }
}

// ---------------------------------------------------------------------------
extern "C" void kernel_launch(void* const* d_in, const int* in_sizes, int n_in,
                              void* d_out, int out_size, void* d_ws, size_t ws_size,
                              hipStream_t stream) {
    const float* x    = (const float*)d_in[0];
    const float* mask = (const float*)d_in[1];
    const float* Wq   = (const float*)d_in[2];
    const float* bq   = (const float*)d_in[3];
    const float* Wk   = (const float*)d_in[4];
    const float* bk   = (const float*)d_in[5];
    const float* Wv   = (const float*)d_in[6];
    const float* bv   = (const float*)d_in[7];
    const float* Wo   = (const float*)d_in[8];
    const float* bo   = (const float*)d_in[9];
    const float* erk  = (const float*)d_in[10];
    const float* erv  = (const float*)d_in[11];
    const float* ln1g = (const float*)d_in[12];
    const float* ln1b = (const float*)d_in[13];
    const float* w1   = (const float*)d_in[14];
    const float* b1   = (const float*)d_in[15];
    const float* w2   = (const float*)d_in[16];
    const float* b2   = (const float*)d_in[17];
    const float* ln2g = (const float*)d_in[18];
    const float* ln2b = (const float*)d_in[19];

    const size_t N = (size_t)Bn * Cn * Tn;         // 1,572,864
    const int WC = Ln * Cn * Cn;                   // 221,184
    const size_t WF = (size_t)Ln * 3 * FCn * Cn;   // 2,654,208
    const size_t WQKV = (size_t)Ln * 576 * Cn;     // 663,552
    const size_t NSCR = (size_t)Bn * Tn * FCn;     // 6,291,456 == NSPLIT*RN*96

    float* X    = (float*)d_ws;
    float* Yb   = X + N;                           // conv_o out / FFN2 partial 0
    float* bqkv = Yb + N;                          // L*576 floats
    float* Lp   = bqkv + Ln * 576;                 // NSPLIT*RN floats
    bf16* p16 = (bf16*)(Lp + (size_t)NSPLIT * RN);
    bf16* XT   = p16; p16 += N;
    bf16* QKT  = p16; p16 += (size_t)Bn * Tn * QKS;  // 2N bf16; dead after attn
    bf16* Vb   = p16; p16 += N;
    bf16* AT   = p16; p16 += N;
    bf16* SCR  = p16; p16 += NSCR;   // shared: attn O-partials <-> FFN hidden
    bf16* Wqkv = p16; p16 += WQKV;
    bf16* Wob  = p16; p16 += WC;
    bf16* W1t  = p16; p16 += WF;
    bf16* W2t  = p16; p16 += WF;
    bf16* ERKB = p16; p16 += Ln * 16 * 96;
    float* P1  = (float*)QKT;        // FFN2 partial 1 aliases dead QKT (N fp32)

    const float qscale = 0.10206207261596575f;  // 1/sqrt(96)

    // one-time transforms
    qkv_prep<<<(int)((WQKV + Ln * 576 + 255) / 256), 256, 0, stream>>>(
        Wq, Wk, Wv, bq, bk, bv, Wqkv, bqkv, qscale);
    cast_bf<<<(WC + 255) / 256, 256, 0, stream>>>(Wo, Wob, WC);
    reorder_w<<<(int)((WF + 255) / 256), 256, 0, stream>>>(w1, W1t, FCn, Cn);
    reorder_w<<<(int)((WF + 255) / 256), 256, 0, stream>>>(w2, W2t, Cn, FCn);
    erk_prep<<<(Ln * 16 * 96 + 255) / 256, 256, 0, stream>>>(erk, ERKB);
    cvt_in_k<<<Bn * 32, 256, 0, stream>>>(x, mask, X, XT);

    for (int l = 0; l < Ln; ++l) {
        conv_mfma<1, 64, 4, 1><<<dim3(Tn / 64, 9, Bn), 256, 0, stream>>>(
            XT, Wqkv + (size_t)l * 576 * Cn, bqkv + l * 576, nullptr, QKT, Vb, Cn, 576);
        attn_mfma<<<dim3(Tn / 64 * Hn * Bn * NSPLIT), 256, 0, stream>>>(
            QKT, Vb, mask, ERKB, erv, SCR, Lp, l);
        attn_combine<<<RN * 12 / 256, 256, 0, stream>>>(SCR, Lp, AT);
        conv_mfma<1, 32, 0, 1><<<dim3(Tn / 32, 3, Bn), 256, 0, stream>>>(
            AT, Wob + (size_t)l * Cn * Cn, bo + l * Cn, nullptr, Yb, nullptr, Cn, Cn);
        ln_k<<<Bn * 32, 256, 0, stream>>>(X, Yb, ln1g + l * Cn, ln1b + l * Cn, mask, XT, 1);
        conv_mfma<3, 64, 2, 1><<<dim3(Tn / 64, FCn / 64, Bn), 256, 0, stream>>>(
            XT, W1t + (size_t)l * 3 * FCn * Cn, b1 + l * FCn, mask, SCR, nullptr, Cn, FCn);
        conv_mfma<3, 64, 5, 2><<<dim3(Tn / 64, 3, Bn * 2), 256, 0, stream>>>(
            SCR, W2t + (size_t)l * 3 * Cn * FCn, b2 + l * Cn, mask, Yb, P1, FCn, Cn);
        ln_ffn2<<<Bn * 32, 256, 0, stream>>>(X, Yb, P1, b2 + l * Cn,
                                             ln2g + l * Cn, ln2b + l * Cn, mask, XT,
                                             (l == Ln - 1) ? (float*)d_out : nullptr);
    }
}

// Round 2
// 981.104 us; speedup vs baseline: 1.1772x; 1.1772x over previous
//
#include <hip/hip_runtime.h>
#include <hip/hip_bf16.h>

// Problem constants
constexpr int Bn  = 8;
constexpr int Cn  = 192;   // hidden channels
constexpr int Tn  = 1024;  // sequence length
constexpr int Hn  = 2;     // heads
constexpr int DKn = 96;    // head dim
constexpr int FCn = 768;   // filter channels
constexpr int Ln  = 6;     // layers
constexpr int WINn = 4;    // rel-attn window
constexpr int QKS = 384;   // QK transposed row stride (Q|K concat)
constexpr int NSPLIT = 4;  // attention s-split (flash-decoding)
constexpr int RN  = Bn * Hn * Tn;  // 16384 attention rows

typedef __hip_bfloat16 bf16;
typedef __attribute__((ext_vector_type(8))) short short8;
typedef __attribute__((ext_vector_type(4))) float f32x4;

// ---------------------------------------------------------------------------
// One-time transforms
__global__ void cast_bf(const float* __restrict__ src, bf16* __restrict__ dst, int n) {
    int i = blockIdx.x * 256 + threadIdx.x;
    if (i < n) dst[i] = __float2bfloat16(src[i]);
}

// w [L][CO][CIN][3] -> [L][3][CO][CIN] bf16
__global__ void reorder_w(const float* __restrict__ src, bf16* __restrict__ dst,
                          int CO, int CIN) {
    int i = blockIdx.x * 256 + threadIdx.x;
    int n = Ln * 3 * CO * CIN;
    if (i >= n) return;
    int c = i % CIN;
    int f = (i / CIN) % CO;
    int ko = (i / (CIN * CO)) % 3;
    int l = i / (3 * CIN * CO);
    dst[i] = __float2bfloat16(src[(((size_t)(l * CO + f)) * CIN + c) * 3 + ko]);
}

// erk fp32 [L][9][96] -> bf16 [L][16][96], rows 9..15 zero (MFMA B-frag ready)
__global__ void erk_prep(const float* __restrict__ src, bf16* __restrict__ dst) {
    int i = blockIdx.x * 256 + threadIdx.x;       // < Ln*16*96
    if (i >= Ln * 16 * 96) return;
    int d = i % 96, row = (i / 96) % 16, l = i / (96 * 16);
    float v = (row < 9) ? src[((size_t)l * 9 + row) * 96 + d] : 0.f;
    dst[i] = __float2bfloat16(v);
}

// Build fused QKV weight [L][576][C] bf16 (qscale folded into Q) + bias fp32
__global__ void qkv_prep(const float* __restrict__ Wq, const float* __restrict__ Wk,
                         const float* __restrict__ Wv, const float* __restrict__ bq,
                         const float* __restrict__ bk, const float* __restrict__ bv,
                         bf16* __restrict__ Wout, float* __restrict__ bout, float qscale) {
    int i = blockIdx.x * 256 + threadIdx.x;
    const int nW = Ln * 576 * Cn;
    if (i < nW) {
        int c = i % Cn, f = (i / Cn) % 576, l = i / (Cn * 576);
        float v;
        if (f < 192)      v = Wq[((size_t)l * Cn + f) * Cn + c] * qscale;
        else if (f < 384) v = Wk[((size_t)l * Cn + f - 192) * Cn + c];
        else              v = Wv[((size_t)l * Cn + f - 384) * Cn + c];
        Wout[i] = __float2bfloat16(v);
    } else if (i < nW + Ln * 576) {
        int j = i - nW, f = j % 576, l = j / 576;
        float v;
        if (f < 192)      v = bq[l * Cn + f] * qscale;
        else if (f < 384) v = bk[l * Cn + f - 192];
        else              v = bv[l * Cn + f - 384];
        bout[j] = v;
    }
}

// ---------------------------------------------------------------------------
// Input: X = x*mask (fp32, NCT) + XT = bf16 transposed [b][t][c]
__global__ __launch_bounds__(256) void cvt_in_k(
        const float* __restrict__ x, const float* __restrict__ mask,
        float* __restrict__ X, bf16* __restrict__ XT) {
    __shared__ float tile[Cn][33];
    const int tid = threadIdx.x, lane = tid & 31, w = tid >> 5;
    const int b = blockIdx.x >> 5;
    const int t0 = (blockIdx.x & 31) * 32;
    const float mk = mask[b * Tn + t0 + lane];
    for (int c = w; c < Cn; c += 8) {
        float v = x[((b * Cn + c) * Tn) + t0 + lane] * mk;
        X[((b * Cn + c) * Tn) + t0 + lane] = v;
        tile[c][lane] = v;
    }
    __syncthreads();
    for (int idx = tid; idx < 32 * Cn; idx += 256) {
        int tl = idx / Cn, c = idx % Cn;
        XT[((size_t)b * Tn + t0 + tl) * Cn + c] = __float2bfloat16(tile[c][tl]);
    }
}

// ---------------------------------------------------------------------------
// MFMA conv1d, LDS-staged (m97 structure) — R12 winner, unchanged.
// MODE 0: fp32 NCT out (+bias, *mask if mask!=null)
// MODE 2: bf16 transposed [b][t][CO] out relu(+bias)*mask   [FFN1]
// MODE 4: QKV split: f<384 -> bf16 T (stride QKS) into Y0; else bf16 NCT Y1
// MODE 5: fp32 NCT K-split partial, NO bias: ks==0 -> Y0, ks==1 -> Y1 [FFN2]
template <int KS, int TT, int MODE, int NSP>
__global__ __launch_bounds__(256) void conv_mfma(
        const bf16* __restrict__ Xt, const bf16* __restrict__ W,
        const float* __restrict__ bias, const float* __restrict__ mask,
        void* __restrict__ Y0, void* __restrict__ Y1, int CIN, int CO) {
    constexpr int PAD = KS / 2;
    constexpr int NMB = TT / 16;
    constexpr int AR  = TT + KS - 1;   // A rows staged
    constexpr int RS  = 72;            // padded row stride (bf16 cols)
    __shared__ bf16 As[AR][RS];
    __shared__ bf16 Bs[KS][64][RS];

    const int tid = threadIdx.x;
    const int wv = tid >> 6, lane = tid & 63;
    const int m = lane & 15, kq = lane >> 4;
    const int b = blockIdx.z / NSP, ks = blockIdx.z % NSP;
    const int t0 = blockIdx.x * TT;
    const int f0 = blockIdx.y * 64;
    const int f = f0 + wv * 16 + m;

    const bf16* xb = Xt + (size_t)b * Tn * CIN;
    const size_t wko = (size_t)CO * CIN;

    f32x4 acc[NMB] = {};

    const int cbeg = ks * (CIN / NSP);
    const int cend = cbeg + CIN / NSP;
    for (int c0 = cbeg; c0 < cend; c0 += 64) {
        __syncthreads();   // previous chunk's fragment reads complete
        for (int s = tid; s < AR * 8; s += 256) {
            int r = s >> 3, cs = (s & 7) * 8;
            int gt = t0 + r - PAD;
            short8 v = {0, 0, 0, 0, 0, 0, 0, 0};
            if (PAD == 0 || (unsigned)gt < (unsigned)Tn)
                v = *(const short8*)(xb + (size_t)gt * CIN + c0 + cs);
            *(short8*)&As[r][cs] = v;
        }
        for (int s = tid; s < KS * 512; s += 256) {
            int ko = s >> 9, r = (s >> 3) & 63, cs = (s & 7) * 8;
            short8 v = *(const short8*)(W + (size_t)ko * wko + (size_t)(f0 + r) * CIN + c0 + cs);
            *(short8*)&Bs[ko][r][cs] = v;
        }
        __syncthreads();   // staged data visible
#pragma unroll
        for (int kk = 0; kk < 2; ++kk)
#pragma unroll
            for (int ko = 0; ko < KS; ++ko) {
                short8 bfr = *(const short8*)&Bs[ko][wv * 16 + m][kk * 32 + kq * 8];
#pragma unroll
                for (int mb = 0; mb < NMB; ++mb) {
                    short8 afr = *(const short8*)&As[mb * 16 + m + ko][kk * 32 + kq * 8];
                    acc[mb] = __builtin_amdgcn_mfma_f32_16x16x32_bf16(afr, bfr, acc[mb], 0, 0, 0);
                }
            }
    }

    if (MODE == 5) {
        float* Y = (float*)(ks ? Y1 : Y0) + ((size_t)b * CO + f) * Tn;
#pragma unroll
        for (int mb = 0; mb < NMB; ++mb) {
            int t = t0 + mb * 16 + kq * 4;
            float4 o;
            o.x = acc[mb][0]; o.y = acc[mb][1]; o.z = acc[mb][2]; o.w = acc[mb][3];
            *(float4*)(Y + t) = o;
        }
        return;
    }
    const float bs = bias[f];
    if (MODE == 0) {
        float* Y = (float*)Y0 + ((size_t)b * CO + f) * Tn;
#pragma unroll
        for (int mb = 0; mb < NMB; ++mb) {
            int t = t0 + mb * 16 + kq * 4;
            float4 o;
            o.x = acc[mb][0] + bs; o.y = acc[mb][1] + bs;
            o.z = acc[mb][2] + bs; o.w = acc[mb][3] + bs;
            if (mask) {
                o.x *= mask[b * Tn + t];     o.y *= mask[b * Tn + t + 1];
                o.z *= mask[b * Tn + t + 2]; o.w *= mask[b * Tn + t + 3];
            }
            *(float4*)(Y + t) = o;
        }
    } else if (MODE == 2) {
        bf16* Y = (bf16*)Y0;
#pragma unroll
        for (int mb = 0; mb < NMB; ++mb)
#pragma unroll
            for (int r = 0; r < 4; ++r) {
                int t = t0 + mb * 16 + kq * 4 + r;
                float v = fmaxf(acc[mb][r] + bs, 0.f) * mask[b * Tn + t];
                Y[((size_t)b * Tn + t) * CO + f] = __float2bfloat16(v);
            }
    } else {  // MODE 4
        if (blockIdx.y < 6) {          // Q|K -> transposed, stride QKS
            bf16* Y = (bf16*)Y0;
#pragma unroll
            for (int mb = 0; mb < NMB; ++mb)
#pragma unroll
                for (int r = 0; r < 4; ++r) {
                    int t = t0 + mb * 16 + kq * 4 + r;
                    Y[((size_t)b * Tn + t) * QKS + f] = __float2bfloat16(acc[mb][r] + bs);
                }
        } else {                        // V -> bf16 NCT
            bf16* Y = (bf16*)Y1 + ((size_t)b * Cn + f - 384) * Tn;
#pragma unroll
            for (int mb = 0; mb < NMB; ++mb) {
                int t = t0 + mb * 16 + kq * 4;
                bf16 tmp[4];
#pragma unroll
                for (int r = 0; r < 4; ++r) tmp[r] = __float2bfloat16(acc[mb][r] + bs);
                *(uint2*)(Y + t) = *(uint2*)tmp;
            }
        }
    }
}

// ---------------------------------------------------------------------------
// MFMA flash attention, split-K over s, LDS-staged K/V (round-0 structure:
// coalesced cooperative staging + 2 barriers/chunk — proven better than
// per-wave global B-frags, which put L2 latency on the MFMA operand chain).
// R1 post-mortem additions:
//  * XCD swizzle (kept from R1): the 16 t0-blocks sharing one (b,h,sp)
//    K/V panel land on ONE XCD -> panel L2-resident, FETCH 26MB->5MB,
//    so the pre-barrier vmcnt drain is ~200cy L2-hit, not ~900cy HBM.
//  * T14 async-STAGE split: chunk n+1's K/V global loads are ISSUED into
//    6 staging regs (24 VGPR) BEFORE chunk n's compute; the ds_write
//    happens after the read-complete barrier. Load latency hides under
//    QK^T+softmax+PV instead of sitting serially between barriers.
// FIXED-MAX softmax (scores O(5), exp safe in fp32) — unchanged.
// Writes UNNORMALIZED partials: Op bf16 [sp][rid][96], Lp fp32 [sp][rid].
__global__ __launch_bounds__(256) void attn_mfma(
        const bf16* __restrict__ QK, const bf16* __restrict__ V,
        const float* __restrict__ mask, const bf16* __restrict__ erkb,
        const float* __restrict__ erv, bf16* __restrict__ Op,
        float* __restrict__ Lp, int layer) {
    __shared__ bf16 Ks[64][100];      // K chunk [s][d]
    __shared__ bf16 Vs[96][68];       // V chunk [d][s]
    __shared__ float rq[4][16][17];   // per-wave rel-K band: [m][dd]
    __shared__ bf16 pT[4][16][68];    // per-wave P: [m][s]

    const int tid = threadIdx.x, wv = tid >> 6, lane = tid & 63;
    const int col = lane & 15, quad = lane >> 4;
    // XCD-bijective swizzle (1024 = 8 XCD x 128; id%8 = XCD round-robin)
    const int w = (blockIdx.x & 7) * 128 + (blockIdx.x >> 3);
    const int t0 = (w & 15) * 64;
    const int yz = w >> 4;
    const int h = yz & 1;
    const int z = yz >> 1;
    const int b = z >> 2, sp = z & 3;
    const int hd = h * DKn;
    const int t0w = t0 + wv * 16;

    // staging geometry (3 short8 per thread for K, 3 for V)
    int rK[3], cK[3], rV[3], cV[3];
#pragma unroll
    for (int i = 0; i < 3; ++i) {
        int s = tid + i * 256;
        rK[i] = s / 12; cK[i] = (s % 12) * 8;   // 64 rows x 96 cols
        rV[i] = s >> 3; cV[i] = (s & 7) * 8;    // 96 rows x 64 cols
    }
    const bf16* kbase = QK + (size_t)b * Tn * QKS + 192 + hd;
    const bf16* vbase = V + ((size_t)b * Cn + hd) * Tn;

    short8 kst[3], vst[3];
    const int sbeg = sp * (Tn / NSPLIT);
    const int send = sbeg + Tn / NSPLIT;

    // issue first chunk's loads immediately (latency hides under Q/rq prep)
#pragma unroll
    for (int i = 0; i < 3; ++i) {
        kst[i] = *(const short8*)(kbase + (size_t)(sbeg + rK[i]) * QKS + cK[i]);
        vst[i] = *(const short8*)(vbase + (size_t)rV[i] * Tn + sbeg + cV[i]);
    }

    // Q A-frags (persist): A[m=col][k=quad*8+j+32*kd]
    short8 aq[3];
    {
        const bf16* qrow = QK + ((size_t)b * Tn + t0w + col) * QKS + hd + quad * 8;
#pragma unroll
        for (int kd = 0; kd < 3; ++kd) aq[kd] = *(const short8*)(qrow + kd * 32);
    }
    // rel-K band via MFMA: R = Q . erk^T  (B rows 9..15 are zero)
    {
        const bf16* erow = erkb + ((size_t)layer * 16 + col) * 96 + quad * 8;
        f32x4 R = {};
#pragma unroll
        for (int kd = 0; kd < 3; ++kd) {
            short8 be = *(const short8*)(erow + kd * 32);
            R = __builtin_amdgcn_mfma_f32_16x16x32_bf16(aq[kd], be, R, 0, 0, 0);
        }
#pragma unroll
        for (int r = 0; r < 4; ++r) rq[wv][quad * 4 + r][col] = R[r];
    }
    float mtv[4];
#pragma unroll
    for (int r = 0; r < 4; ++r) mtv[r] = mask[b * Tn + t0w + quad * 4 + r];

    // first chunk into LDS
#pragma unroll
    for (int i = 0; i < 3; ++i) {
        *(short8*)&Ks[rK[i]][cK[i]] = kst[i];
        *(short8*)&Vs[rV[i]][cV[i]] = vst[i];
    }
    __syncthreads();

    float lrow[4] = {};
    f32x4 O[6] = {};
    const float* ervl = erv + (size_t)layer * 9 * DKn;

    for (int s0 = sbeg; s0 < send; s0 += 64) {
        const bool nxt = (s0 + 64 < send);
        // T14: issue NEXT chunk's global loads now; ds_write after barrier
        if (nxt) {
#pragma unroll
            for (int i = 0; i < 3; ++i) {
                kst[i] = *(const short8*)(kbase + (size_t)(s0 + 64 + rK[i]) * QKS + cK[i]);
                vst[i] = *(const short8*)(vbase + (size_t)rV[i] * Tn + s0 + 64 + cV[i]);
            }
        }

        // S = Q K^T (B-frags from LDS)
        f32x4 S[4] = {};
#pragma unroll
        for (int nb = 0; nb < 4; ++nb)
#pragma unroll
            for (int kd = 0; kd < 3; ++kd) {
                short8 bkf = *(const short8*)&Ks[16 * nb + col][kd * 32 + quad * 8];
                S[nb] = __builtin_amdgcn_mfma_f32_16x16x32_bf16(aq[kd], bkf, S[nb], 0, 0, 0);
            }

#pragma unroll
        for (int nb = 0; nb < 4; ++nb) {
            const int sg = s0 + 16 * nb + col;
            const float msv = mask[b * Tn + sg];
#pragma unroll
            for (int r = 0; r < 4; ++r) {
                const int tq = t0w + quad * 4 + r;
                float v = S[nb][r];
                int dd = sg - tq + WINn;
                if (dd >= 0 && dd <= 2 * WINn) v += rq[wv][quad * 4 + r][dd];
                if (msv * mtv[r] == 0.f) v = -1e4f;
                S[nb][r] = v;
            }
        }

        // fixed-max softmax: P = exp(S); row-sum via 16-lane shuffle reduce
        float psum[4] = {};
#pragma unroll
        for (int nb = 0; nb < 4; ++nb)
#pragma unroll
            for (int r = 0; r < 4; ++r) {
                bf16 pb = __float2bfloat16(__expf(S[nb][r]));
                pT[wv][quad * 4 + r][16 * nb + col] = pb;
                psum[r] += __bfloat162float(pb);
            }
#pragma unroll
        for (int r = 0; r < 4; ++r) {
#pragma unroll
            for (int mk2 = 1; mk2 < 16; mk2 <<= 1) psum[r] += __shfl_xor(psum[r], mk2);
            lrow[r] += psum[r];
        }

        // P A-frags from per-wave LDS; PV (V B-frags from shared LDS)
        short8 aP[2];
#pragma unroll
        for (int kk = 0; kk < 2; ++kk)
            aP[kk] = *(const short8*)&pT[wv][col][kk * 32 + quad * 8];
#pragma unroll
        for (int nd = 0; nd < 6; ++nd)
#pragma unroll
            for (int kk = 0; kk < 2; ++kk) {
                short8 bvf = *(const short8*)&Vs[16 * nd + col][kk * 32 + quad * 8];
                O[nd] = __builtin_amdgcn_mfma_f32_16x16x32_bf16(aP[kk], bvf, O[nd], 0, 0, 0);
            }

        // rel-V on diagonal chunks
        if (s0 <= t0w + 15 + WINn && s0 + 63 >= t0w - WINn) {
#pragma unroll
            for (int r = 0; r < 4; ++r) {
                const int tq = t0w + quad * 4 + r;
                for (int dd = 0; dd <= 2 * WINn; ++dd) {
                    int sg = tq + dd - WINn;
                    if (sg >= s0 && sg < s0 + 64) {
                        float p = __bfloat162float(pT[wv][quad * 4 + r][sg - s0]);
#pragma unroll
                        for (int nd = 0; nd < 6; ++nd)
                            O[nd][r] += p * ervl[dd * DKn + 16 * nd + col];
                    }
                }
            }
        }

        __syncthreads();   // all waves done reading Ks/Vs
        if (nxt) {
            // vmcnt wait on kst/vst is implicit at first use; loads were
            // issued one full compute-phase ago -> mostly drained
#pragma unroll
            for (int i = 0; i < 3; ++i) {
                *(short8*)&Ks[rK[i]][cK[i]] = kst[i];
                *(short8*)&Vs[rV[i]][cV[i]] = vst[i];
            }
            __syncthreads();
        }
    }

    // epilogue: write unnormalized partials
    const int rbase = (b * Hn + h) * Tn + t0w;
#pragma unroll
    for (int r = 0; r < 4; ++r) {
        const int rid = rbase + quad * 4 + r;
        bf16* dst = Op + ((size_t)sp * RN + rid) * 96 + col;
#pragma unroll
        for (int nd = 0; nd < 6; ++nd)
            dst[16 * nd] = __float2bfloat16(O[nd][r]);
        if (col == 0) Lp[sp * RN + rid] = lrow[r];
    }
}

// Combine split partials -> AT bf16 [b][t][C]. One thread per (rid, 8-chan).
__global__ __launch_bounds__(256) void attn_combine(
        const bf16* __restrict__ Op, const float* __restrict__ Lp,
        bf16* __restrict__ AT) {
    int i = blockIdx.x * 256 + threadIdx.x;       // < RN*12
    int rid = i / 12, j = i - rid * 12;
    float denom = 0.f;
    float o[8] = {};
#pragma unroll
    for (int s = 0; s < NSPLIT; ++s) {
        denom += Lp[s * RN + rid];
        short8 v = *(const short8*)(Op + ((size_t)s * RN + rid) * 96 + j * 8);
        const bf16* vb = (const bf16*)&v;
#pragma unroll
        for (int e = 0; e < 8; ++e) o[e] += __bfloat162float(vb[e]);
    }
    float inv = 1.f / fmaxf(denom, 1e-30f);
    int t = rid & (Tn - 1), h = (rid >> 10) & (Hn - 1), b = rid >> 11;
    bf16 outv[8];
#pragma unroll
    for (int e = 0; e < 8; ++e) outv[e] = __float2bfloat16(o[e] * inv);
    *(uint4*)(AT + ((size_t)b * Tn + t) * Cn + h * DKn + j * 8) = *(uint4*)outv;
}

// ---------------------------------------------------------------------------
// Residual add + LayerNorm over channels. X <- LN(X+Y)*g+b (fp32) and
// XT <- bf16 transposed [b][t][C], optionally *mask.
__global__ __launch_bounds__(256) void ln_k(
        float* __restrict__ X, const float* __restrict__ Y,
        const float* __restrict__ G, const float* __restrict__ Bt,
        const float* __restrict__ mask, bf16* __restrict__ XT, int apply_mask) {
    __shared__ float tile[Cn][33];
    __shared__ float r1[8][32];
    __shared__ float r2[8][32];
    const int tid = threadIdx.x;
    const int lane = tid & 31, w = tid >> 5;
    const int b = blockIdx.x >> 5;
    const int t0 = (blockIdx.x & 31) * 32;
    const int t = t0 + lane;

    float s1 = 0.f, s2 = 0.f;
    for (int c = w; c < Cn; c += 8) {
        float v = X[((b * Cn + c) * Tn) + t] + Y[((b * Cn + c) * Tn) + t];
        tile[c][lane] = v;
        s1 += v;
        s2 += v * v;
    }
    r1[w][lane] = s1;
    r2[w][lane] = s2;
    __syncthreads();
    if (w == 0) {
        float a = 0.f, q = 0.f;
        for (int i = 0; i < 8; ++i) { a += r1[i][lane]; q += r2[i][lane]; }
        float m = a / Cn;
        float var = q / Cn - m * m;
        r1[0][lane] = m;
        r2[0][lane] = rsqrtf(var + 1e-5f);
    }
    __syncthreads();
    const float m = r1[0][lane], rs = r2[0][lane];
    for (int c = w; c < Cn; c += 8) {
        float y = (tile[c][lane] - m) * rs * G[c] + Bt[c];
        X[((b * Cn + c) * Tn) + t] = y;
        tile[c][lane] = y;
    }
    __syncthreads();
    for (int idx = tid; idx < 32 * Cn; idx += 256) {
        int tl = idx / Cn, c = idx % Cn;
        float v = tile[c][tl];
        if (apply_mask) v *= mask[b * Tn + t0 + tl];
        XT[((size_t)b * Tn + t0 + tl) * Cn + c] = __float2bfloat16(v);
    }
}

// FFN2-combine + residual + LN2: Y = (P0+P1+bias)*mask; Xn = LN(X+Y)*g+b.
// OUT==null: X <- Xn, XT <- bf16(Xn).  OUT!=null (last layer): OUT <- Xn*mask.
__global__ __launch_bounds__(256) void ln_ffn2(
        float* __restrict__ X, const float* __restrict__ P0,
        const float* __restrict__ P1, const float* __restrict__ bias,
        const float* __restrict__ G, const float* __restrict__ Bt,
        const float* __restrict__ mask, bf16* __restrict__ XT,
        float* __restrict__ OUT) {
    __shared__ float tile[Cn][33];
    __shared__ float r1[8][32];
    __shared__ float r2[8][32];
    const int tid = threadIdx.x;
    const int lane = tid & 31, w = tid >> 5;
    const int b = blockIdx.x >> 5;
    const int t0 = (blockIdx.x & 31) * 32;
    const int t = t0 + lane;
    const float mk = mask[b * Tn + t];

    float s1 = 0.f, s2 = 0.f;
    for (int c = w; c < Cn; c += 8) {
        size_t i = ((size_t)b * Cn + c) * Tn + t;
        float y = (P0[i] + P1[i] + bias[c]) * mk;
        float v = X[i] + y;
        tile[c][lane] = v;
        s1 += v;
        s2 += v * v;
    }
    r1[w][lane] = s1;
    r2[w][lane] = s2;
    __syncthreads();
    if (w == 0) {
        float a = 0.f, q = 0.f;
        for (int i = 0; i < 8; ++i) { a += r1[i][lane]; q += r2[i][lane]; }
        float m = a / Cn;
        float var = q / Cn - m * m;
        r1[0][lane] = m;
        r2[0][lane] = rsqrtf(var + 1e-5f);
    }
    __syncthreads();
    const float m = r1[0][lane], rs = r2[0][lane];
    if (OUT) {   // final layer: write output = LN(...)*mask directly, done
        for (int c = w; c < Cn; c += 8) {
            float y = (tile[c][lane] - m) * rs * G[c] + Bt[c];
            OUT[((b * Cn + c) * Tn) + t] = y * mk;
        }
        return;
    }
    for (int c = w; c < Cn; c += 8) {
        float y = (tile[c][lane] - m) * rs * G[c] + Bt[c];
        X[((b * Cn + c) * Tn) + t] = y;
        tile[c][lane] = y;
    }
    __syncthreads();
    for (int idx = tid; idx < 32 * Cn; idx += 256) {
        int tl = idx / Cn, c = idx % Cn;
        XT[((size_t)b * Tn + t0 + tl) * Cn + c] = __float2bfloat16(tile[c][tl]);
    }
}

// ---------------------------------------------------------------------------
extern "C" void kernel_launch(void* const* d_in, const int* in_sizes, int n_in,
                              void* d_out, int out_size, void* d_ws, size_t ws_size,
                              hipStream_t stream) {
    const float* x    = (const float*)d_in[0];
    const float* mask = (const float*)d_in[1];
    const float* Wq   = (const float*)d_in[2];
    const float* bq   = (const float*)d_in[3];
    const float* Wk   = (const float*)d_in[4];
    const float* bk   = (const float*)d_in[5];
    const float* Wv   = (const float*)d_in[6];
    const float* bv   = (const float*)d_in[7];
    const float* Wo   = (const float*)d_in[8];
    const float* bo   = (const float*)d_in[9];
    const float* erk  = (const float*)d_in[10];
    const float* erv  = (const float*)d_in[11];
    const float* ln1g = (const float*)d_in[12];
    const float* ln1b = (const float*)d_in[13];
    const float* w1   = (const float*)d_in[14];
    const float* b1   = (const float*)d_in[15];
    const float* w2   = (const float*)d_in[16];
    const float* b2   = (const float*)d_in[17];
    const float* ln2g = (const float*)d_in[18];
    const float* ln2b = (const float*)d_in[19];

    const size_t N = (size_t)Bn * Cn * Tn;         // 1,572,864
    const int WC = Ln * Cn * Cn;                   // 221,184
    const size_t WF = (size_t)Ln * 3 * FCn * Cn;   // 2,654,208
    const size_t WQKV = (size_t)Ln * 576 * Cn;     // 663,552
    const size_t NSCR = (size_t)Bn * Tn * FCn;     // 6,291,456 == NSPLIT*RN*96

    float* X    = (float*)d_ws;
    float* Yb   = X + N;                           // conv_o out / FFN2 partial 0
    float* bqkv = Yb + N;                          // L*576 floats
    float* Lp   = bqkv + Ln * 576;                 // NSPLIT*RN floats
    bf16* p16 = (bf16*)(Lp + (size_t)NSPLIT * RN);
    bf16* XT   = p16; p16 += N;
    bf16* QKT  = p16; p16 += (size_t)Bn * Tn * QKS;  // 2N bf16; dead after attn
    bf16* Vb   = p16; p16 += N;
    bf16* AT   = p16; p16 += N;
    bf16* SCR  = p16; p16 += NSCR;   // shared: attn O-partials <-> FFN hidden
    bf16* Wqkv = p16; p16 += WQKV;
    bf16* Wob  = p16; p16 += WC;
    bf16* W1t  = p16; p16 += WF;
    bf16* W2t  = p16; p16 += WF;
    bf16* ERKB = p16; p16 += Ln * 16 * 96;
    float* P1  = (float*)QKT;        // FFN2 partial 1 aliases dead QKT (N fp32)

    const float qscale = 0.10206207261596575f;  // 1/sqrt(96)

    // one-time transforms
    qkv_prep<<<(int)((WQKV + Ln * 576 + 255) / 256), 256, 0, stream>>>(
        Wq, Wk, Wv, bq, bk, bv, Wqkv, bqkv, qscale);
    cast_bf<<<(WC + 255) / 256, 256, 0, stream>>>(Wo, Wob, WC);
    reorder_w<<<(int)((WF + 255) / 256), 256, 0, stream>>>(w1, W1t, FCn, Cn);
    reorder_w<<<(int)((WF + 255) / 256), 256, 0, stream>>>(w2, W2t, Cn, FCn);
    erk_prep<<<(Ln * 16 * 96 + 255) / 256, 256, 0, stream>>>(erk, ERKB);
    cvt_in_k<<<Bn * 32, 256, 0, stream>>>(x, mask, X, XT);

    for (int l = 0; l < Ln; ++l) {
        conv_mfma<1, 64, 4, 1><<<dim3(Tn / 64, 9, Bn), 256, 0, stream>>>(
            XT, Wqkv + (size_t)l * 576 * Cn, bqkv + l * 576, nullptr, QKT, Vb, Cn, 576);
        attn_mfma<<<dim3(Tn / 64 * Hn * Bn * NSPLIT), 256, 0, stream>>>(
            QKT, Vb, mask, ERKB, erv, SCR, Lp, l);
        attn_combine<<<RN * 12 / 256, 256, 0, stream>>>(SCR, Lp, AT);
        conv_mfma<1, 32, 0, 1><<<dim3(Tn / 32, 3, Bn), 256, 0, stream>>>(
            AT, Wob + (size_t)l * Cn * Cn, bo + l * Cn, nullptr, Yb, nullptr, Cn, Cn);
        ln_k<<<Bn * 32, 256, 0, stream>>>(X, Yb, ln1g + l * Cn, ln1b + l * Cn, mask, XT, 1);
        conv_mfma<3, 64, 2, 1><<<dim3(Tn / 64, FCn / 64, Bn), 256, 0, stream>>>(
            XT, W1t + (size_t)l * 3 * FCn * Cn, b1 + l * FCn, mask, SCR, nullptr, Cn, FCn);
        conv_mfma<3, 64, 5, 2><<<dim3(Tn / 64, 3, Bn * 2), 256, 0, stream>>>(
            SCR, W2t + (size_t)l * 3 * Cn * FCn, b2 + l * Cn, mask, Yb, P1, FCn, Cn);
        ln_ffn2<<<Bn * 32, 256, 0, stream>>>(X, Yb, P1, b2 + l * Cn,
                                             ln2g + l * Cn, ln2b + l * Cn, mask, XT,
                                             (l == Ln - 1) ? (float*)d_out : nullptr);
    }
}

// Round 3
// 910.309 us; speedup vs baseline: 1.2687x; 1.0778x over previous
//
#include <hip/hip_runtime.h>
#include <hip/hip_bf16.h>

// Problem constants
constexpr int Bn  = 8;
constexpr int Cn  = 192;   // hidden channels
constexpr int Tn  = 1024;  // sequence length
constexpr int Hn  = 2;     // heads
constexpr int DKn = 96;    // head dim
constexpr int FCn = 768;   // filter channels
constexpr int Ln  = 6;     // layers
constexpr int WINn = 4;    // rel-attn window
constexpr int QKS = 384;   // QK transposed row stride (Q|K concat)
constexpr int NSPLIT = 4;  // attention s-split (flash-decoding)
constexpr int RN  = Bn * Hn * Tn;  // 16384 attention rows

typedef __hip_bfloat16 bf16;
typedef __attribute__((ext_vector_type(8))) short short8;
typedef __attribute__((ext_vector_type(4))) float f32x4;

// ---------------------------------------------------------------------------
// One-time transforms
__global__ void cast_bf(const float* __restrict__ src, bf16* __restrict__ dst, int n) {
    int i = blockIdx.x * 256 + threadIdx.x;
    if (i < n) dst[i] = __float2bfloat16(src[i]);
}

// w [L][CO][CIN][3] -> [L][3][CO][CIN] bf16
__global__ void reorder_w(const float* __restrict__ src, bf16* __restrict__ dst,
                          int CO, int CIN) {
    int i = blockIdx.x * 256 + threadIdx.x;
    int n = Ln * 3 * CO * CIN;
    if (i >= n) return;
    int c = i % CIN;
    int f = (i / CIN) % CO;
    int ko = (i / (CIN * CO)) % 3;
    int l = i / (3 * CIN * CO);
    dst[i] = __float2bfloat16(src[(((size_t)(l * CO + f)) * CIN + c) * 3 + ko]);
}

// erk fp32 [L][9][96] -> bf16 [L][16][96], rows 9..15 zero (MFMA B-frag ready)
__global__ void erk_prep(const float* __restrict__ src, bf16* __restrict__ dst) {
    int i = blockIdx.x * 256 + threadIdx.x;       // < Ln*16*96
    if (i >= Ln * 16 * 96) return;
    int d = i % 96, row = (i / 96) % 16, l = i / (96 * 16);
    float v = (row < 9) ? src[((size_t)l * 9 + row) * 96 + d] : 0.f;
    dst[i] = __float2bfloat16(v);
}

// erv fp32 [L][9][96] -> bf16 [L][96][32] transposed [d][dd], dd 9..31 zero
// (MFMA B-frag layout for the rel-V band matmul)
__global__ void erv_prep(const float* __restrict__ src, bf16* __restrict__ dst) {
    int i = blockIdx.x * 256 + threadIdx.x;       // < Ln*96*32
    if (i >= Ln * 96 * 32) return;
    int k = i & 31, d = (i >> 5) % 96, l = i / (96 * 32);
    float v = (k < 9) ? src[((size_t)l * 9 + k) * 96 + d] : 0.f;
    dst[i] = __float2bfloat16(v);
}

// Build fused QKV weight [L][576][C] bf16 (qscale folded into Q) + bias fp32
__global__ void qkv_prep(const float* __restrict__ Wq, const float* __restrict__ Wk,
                         const float* __restrict__ Wv, const float* __restrict__ bq,
                         const float* __restrict__ bk, const float* __restrict__ bv,
                         bf16* __restrict__ Wout, float* __restrict__ bout, float qscale) {
    int i = blockIdx.x * 256 + threadIdx.x;
    const int nW = Ln * 576 * Cn;
    if (i < nW) {
        int c = i % Cn, f = (i / Cn) % 576, l = i / (Cn * 576);
        float v;
        if (f < 192)      v = Wq[((size_t)l * Cn + f) * Cn + c] * qscale;
        else if (f < 384) v = Wk[((size_t)l * Cn + f - 192) * Cn + c];
        else              v = Wv[((size_t)l * Cn + f - 384) * Cn + c];
        Wout[i] = __float2bfloat16(v);
    } else if (i < nW + Ln * 576) {
        int j = i - nW, f = j % 576, l = j / 576;
        float v;
        if (f < 192)      v = bq[l * Cn + f] * qscale;
        else if (f < 384) v = bk[l * Cn + f - 192];
        else              v = bv[l * Cn + f - 384];
        bout[j] = v;
    }
}

// ---------------------------------------------------------------------------
// Input: X = x*mask (fp32, NCT) + XT = bf16 transposed [b][t][c]
__global__ __launch_bounds__(256) void cvt_in_k(
        const float* __restrict__ x, const float* __restrict__ mask,
        float* __restrict__ X, bf16* __restrict__ XT) {
    __shared__ float tile[Cn][33];
    const int tid = threadIdx.x, lane = tid & 31, w = tid >> 5;
    const int b = blockIdx.x >> 5;
    const int t0 = (blockIdx.x & 31) * 32;
    const float mk = mask[b * Tn + t0 + lane];
    for (int c = w; c < Cn; c += 8) {
        float v = x[((b * Cn + c) * Tn) + t0 + lane] * mk;
        X[((b * Cn + c) * Tn) + t0 + lane] = v;
        tile[c][lane] = v;
    }
    __syncthreads();
    for (int idx = tid; idx < 32 * Cn; idx += 256) {
        int tl = idx / Cn, c = idx % Cn;
        XT[((size_t)b * Tn + t0 + tl) * Cn + c] = __float2bfloat16(tile[c][tl]);
    }
}

// ---------------------------------------------------------------------------
// MFMA conv1d, LDS-staged (m97 structure) — R12 winner, unchanged.
// MODE 0: fp32 NCT out (+bias, *mask if mask!=null)
// MODE 2: bf16 transposed [b][t][CO] out relu(+bias)*mask   [FFN1]
// MODE 4: QKV split: f<384 -> bf16 T (stride QKS) into Y0; else bf16 NCT Y1
// MODE 5: fp32 NCT K-split partial, NO bias: ks==0 -> Y0, ks==1 -> Y1 [FFN2]
template <int KS, int TT, int MODE, int NSP>
__global__ __launch_bounds__(256) void conv_mfma(
        const bf16* __restrict__ Xt, const bf16* __restrict__ W,
        const float* __restrict__ bias, const float* __restrict__ mask,
        void* __restrict__ Y0, void* __restrict__ Y1, int CIN, int CO) {
    constexpr int PAD = KS / 2;
    constexpr int NMB = TT / 16;
    constexpr int AR  = TT + KS - 1;   // A rows staged
    constexpr int RS  = 72;            // padded row stride (bf16 cols)
    __shared__ bf16 As[AR][RS];
    __shared__ bf16 Bs[KS][64][RS];

    const int tid = threadIdx.x;
    const int wv = tid >> 6, lane = tid & 63;
    const int m = lane & 15, kq = lane >> 4;
    const int b = blockIdx.z / NSP, ks = blockIdx.z % NSP;
    const int t0 = blockIdx.x * TT;
    const int f0 = blockIdx.y * 64;
    const int f = f0 + wv * 16 + m;

    const bf16* xb = Xt + (size_t)b * Tn * CIN;
    const size_t wko = (size_t)CO * CIN;

    f32x4 acc[NMB] = {};

    const int cbeg = ks * (CIN / NSP);
    const int cend = cbeg + CIN / NSP;
    for (int c0 = cbeg; c0 < cend; c0 += 64) {
        __syncthreads();   // previous chunk's fragment reads complete
        for (int s = tid; s < AR * 8; s += 256) {
            int r = s >> 3, cs = (s & 7) * 8;
            int gt = t0 + r - PAD;
            short8 v = {0, 0, 0, 0, 0, 0, 0, 0};
            if (PAD == 0 || (unsigned)gt < (unsigned)Tn)
                v = *(const short8*)(xb + (size_t)gt * CIN + c0 + cs);
            *(short8*)&As[r][cs] = v;
        }
        for (int s = tid; s < KS * 512; s += 256) {
            int ko = s >> 9, r = (s >> 3) & 63, cs = (s & 7) * 8;
            short8 v = *(const short8*)(W + (size_t)ko * wko + (size_t)(f0 + r) * CIN + c0 + cs);
            *(short8*)&Bs[ko][r][cs] = v;
        }
        __syncthreads();   // staged data visible
#pragma unroll
        for (int kk = 0; kk < 2; ++kk)
#pragma unroll
            for (int ko = 0; ko < KS; ++ko) {
                short8 bfr = *(const short8*)&Bs[ko][wv * 16 + m][kk * 32 + kq * 8];
#pragma unroll
                for (int mb = 0; mb < NMB; ++mb) {
                    short8 afr = *(const short8*)&As[mb * 16 + m + ko][kk * 32 + kq * 8];
                    acc[mb] = __builtin_amdgcn_mfma_f32_16x16x32_bf16(afr, bfr, acc[mb], 0, 0, 0);
                }
            }
    }

    if (MODE == 5) {
        float* Y = (float*)(ks ? Y1 : Y0) + ((size_t)b * CO + f) * Tn;
#pragma unroll
        for (int mb = 0; mb < NMB; ++mb) {
            int t = t0 + mb * 16 + kq * 4;
            float4 o;
            o.x = acc[mb][0]; o.y = acc[mb][1]; o.z = acc[mb][2]; o.w = acc[mb][3];
            *(float4*)(Y + t) = o;
        }
        return;
    }
    const float bs = bias[f];
    if (MODE == 0) {
        float* Y = (float*)Y0 + ((size_t)b * CO + f) * Tn;
#pragma unroll
        for (int mb = 0; mb < NMB; ++mb) {
            int t = t0 + mb * 16 + kq * 4;
            float4 o;
            o.x = acc[mb][0] + bs; o.y = acc[mb][1] + bs;
            o.z = acc[mb][2] + bs; o.w = acc[mb][3] + bs;
            if (mask) {
                o.x *= mask[b * Tn + t];     o.y *= mask[b * Tn + t + 1];
                o.z *= mask[b * Tn + t + 2]; o.w *= mask[b * Tn + t + 3];
            }
            *(float4*)(Y + t) = o;
        }
    } else if (MODE == 2) {
        bf16* Y = (bf16*)Y0;
#pragma unroll
        for (int mb = 0; mb < NMB; ++mb)
#pragma unroll
            for (int r = 0; r < 4; ++r) {
                int t = t0 + mb * 16 + kq * 4 + r;
                float v = fmaxf(acc[mb][r] + bs, 0.f) * mask[b * Tn + t];
                Y[((size_t)b * Tn + t) * CO + f] = __float2bfloat16(v);
            }
    } else {  // MODE 4
        if (blockIdx.y < 6) {          // Q|K -> transposed, stride QKS
            bf16* Y = (bf16*)Y0;
#pragma unroll
            for (int mb = 0; mb < NMB; ++mb)
#pragma unroll
                for (int r = 0; r < 4; ++r) {
                    int t = t0 + mb * 16 + kq * 4 + r;
                    Y[((size_t)b * Tn + t) * QKS + f] = __float2bfloat16(acc[mb][r] + bs);
                }
        } else {                        // V -> bf16 NCT
            bf16* Y = (bf16*)Y1 + ((size_t)b * Cn + f - 384) * Tn;
#pragma unroll
            for (int mb = 0; mb < NMB; ++mb) {
                int t = t0 + mb * 16 + kq * 4;
                bf16 tmp[4];
#pragma unroll
                for (int r = 0; r < 4; ++r) tmp[r] = __float2bfloat16(acc[mb][r] + bs);
                *(uint2*)(Y + t) = *(uint2*)tmp;
            }
        }
    }
}

// ---------------------------------------------------------------------------
// MFMA flash attention, split-K over s, LDS-staged K/V, XCD swizzle (R2),
// T14 async-STAGE split (R2).
// R3: rel-V via MFMA. The old rel-V epilogue ran up to ~216 per-lane fp32
// global loads + 216 FMAs per thread on diagonal chunks, serialized inside
// the barrier region (straggler blocks). It is matmul-shaped:
//   relV[t,d] = sum_dd pdiag[t,dd] * erv[dd,d],  pdiag[t,dd] = P[t, t+dd-W].
// Now: the softmax loop drops P band values into a per-wave pdg[16][16]
// (k 9..15 zero), and after the s-loop 6 MFMAs with precomputed ERVB
// [d][dd] B-frags produce the whole contribution.
// FIXED-MAX softmax (scores O(5), exp safe in fp32) — unchanged.
// Writes UNNORMALIZED partials: Op bf16 [sp][rid][96], Lp fp32 [sp][rid].
__global__ __launch_bounds__(256) void attn_mfma(
        const bf16* __restrict__ QK, const bf16* __restrict__ V,
        const float* __restrict__ mask, const bf16* __restrict__ erkb,
        const bf16* __restrict__ ervb, bf16* __restrict__ Op,
        float* __restrict__ Lp, int layer) {
    __shared__ bf16 Ks[64][100];      // K chunk [s][d]
    __shared__ bf16 Vs[96][68];       // V chunk [d][s]
    __shared__ float rq[4][16][17];   // per-wave rel-K band: [m][dd]
    __shared__ bf16 pT[4][16][68];    // per-wave P: [m][s]
    __shared__ bf16 pdg[4][16][16];   // per-wave rel-V band: [m][dd], 9..15 zero
    // LDS total: 12800+13056+4352+8704+2048 = 40960 B -> 4 blocks/CU exactly

    const int tid = threadIdx.x, wv = tid >> 6, lane = tid & 63;
    const int col = lane & 15, quad = lane >> 4;
    // XCD-bijective swizzle (1024 = 8 XCD x 128; id%8 = XCD round-robin)
    const int w = (blockIdx.x & 7) * 128 + (blockIdx.x >> 3);
    const int t0 = (w & 15) * 64;
    const int yz = w >> 4;
    const int h = yz & 1;
    const int z = yz >> 1;
    const int b = z >> 2, sp = z & 3;
    const int hd = h * DKn;
    const int t0w = t0 + wv * 16;

    // zero per-wave rel-V band (rows not hit by any chunk stay zero)
    *(uint2*)&pdg[wv][lane & 15][(lane >> 4) * 4] = (uint2){0, 0};

    // staging geometry (3 short8 per thread for K, 3 for V)
    int rK[3], cK[3], rV[3], cV[3];
#pragma unroll
    for (int i = 0; i < 3; ++i) {
        int s = tid + i * 256;
        rK[i] = s / 12; cK[i] = (s % 12) * 8;   // 64 rows x 96 cols
        rV[i] = s >> 3; cV[i] = (s & 7) * 8;    // 96 rows x 64 cols
    }
    const bf16* kbase = QK + (size_t)b * Tn * QKS + 192 + hd;
    const bf16* vbase = V + ((size_t)b * Cn + hd) * Tn;

    short8 kst[3], vst[3];
    const int sbeg = sp * (Tn / NSPLIT);
    const int send = sbeg + Tn / NSPLIT;

    // issue first chunk's loads immediately (latency hides under Q/rq prep)
#pragma unroll
    for (int i = 0; i < 3; ++i) {
        kst[i] = *(const short8*)(kbase + (size_t)(sbeg + rK[i]) * QKS + cK[i]);
        vst[i] = *(const short8*)(vbase + (size_t)rV[i] * Tn + sbeg + cV[i]);
    }

    // Q A-frags (persist): A[m=col][k=quad*8+j+32*kd]
    short8 aq[3];
    {
        const bf16* qrow = QK + ((size_t)b * Tn + t0w + col) * QKS + hd + quad * 8;
#pragma unroll
        for (int kd = 0; kd < 3; ++kd) aq[kd] = *(const short8*)(qrow + kd * 32);
    }
    // rel-K band via MFMA: R = Q . erk^T  (B rows 9..15 are zero)
    {
        const bf16* erow = erkb + ((size_t)layer * 16 + col) * 96 + quad * 8;
        f32x4 R = {};
#pragma unroll
        for (int kd = 0; kd < 3; ++kd) {
            short8 be = *(const short8*)(erow + kd * 32);
            R = __builtin_amdgcn_mfma_f32_16x16x32_bf16(aq[kd], be, R, 0, 0, 0);
        }
#pragma unroll
        for (int r = 0; r < 4; ++r) rq[wv][quad * 4 + r][col] = R[r];
    }
    float mtv[4];
#pragma unroll
    for (int r = 0; r < 4; ++r) mtv[r] = mask[b * Tn + t0w + quad * 4 + r];

    // first chunk into LDS
#pragma unroll
    for (int i = 0; i < 3; ++i) {
        *(short8*)&Ks[rK[i]][cK[i]] = kst[i];
        *(short8*)&Vs[rV[i]][cV[i]] = vst[i];
    }
    __syncthreads();

    float lrow[4] = {};
    f32x4 O[6] = {};

    for (int s0 = sbeg; s0 < send; s0 += 64) {
        const bool nxt = (s0 + 64 < send);
        // T14: issue NEXT chunk's global loads now; ds_write after barrier
        if (nxt) {
#pragma unroll
            for (int i = 0; i < 3; ++i) {
                kst[i] = *(const short8*)(kbase + (size_t)(s0 + 64 + rK[i]) * QKS + cK[i]);
                vst[i] = *(const short8*)(vbase + (size_t)rV[i] * Tn + s0 + 64 + cV[i]);
            }
        }

        // S = Q K^T (B-frags from LDS)
        f32x4 S[4] = {};
#pragma unroll
        for (int nb = 0; nb < 4; ++nb)
#pragma unroll
            for (int kd = 0; kd < 3; ++kd) {
                short8 bkf = *(const short8*)&Ks[16 * nb + col][kd * 32 + quad * 8];
                S[nb] = __builtin_amdgcn_mfma_f32_16x16x32_bf16(aq[kd], bkf, S[nb], 0, 0, 0);
            }

#pragma unroll
        for (int nb = 0; nb < 4; ++nb) {
            const int sg = s0 + 16 * nb + col;
            const float msv = mask[b * Tn + sg];
#pragma unroll
            for (int r = 0; r < 4; ++r) {
                const int tq = t0w + quad * 4 + r;
                float v = S[nb][r];
                int dd = sg - tq + WINn;
                if (dd >= 0 && dd <= 2 * WINn) v += rq[wv][quad * 4 + r][dd];
                if (msv * mtv[r] == 0.f) v = -1e4f;
                S[nb][r] = v;
            }
        }

        // fixed-max softmax: P = exp(S); row-sum via 16-lane shuffle reduce.
        // Band values additionally dropped into pdg for the rel-V MFMA.
        float psum[4] = {};
#pragma unroll
        for (int nb = 0; nb < 4; ++nb) {
            const int sg = s0 + 16 * nb + col;
#pragma unroll
            for (int r = 0; r < 4; ++r) {
                bf16 pb = __float2bfloat16(__expf(S[nb][r]));
                pT[wv][quad * 4 + r][16 * nb + col] = pb;
                int dd = sg - (t0w + quad * 4 + r) + WINn;
                if ((unsigned)dd <= 2u * WINn) pdg[wv][quad * 4 + r][dd] = pb;
                psum[r] += __bfloat162float(pb);
            }
        }
#pragma unroll
        for (int r = 0; r < 4; ++r) {
#pragma unroll
            for (int mk2 = 1; mk2 < 16; mk2 <<= 1) psum[r] += __shfl_xor(psum[r], mk2);
            lrow[r] += psum[r];
        }

        // P A-frags from per-wave LDS; PV (V B-frags from shared LDS)
        short8 aP[2];
#pragma unroll
        for (int kk = 0; kk < 2; ++kk)
            aP[kk] = *(const short8*)&pT[wv][col][kk * 32 + quad * 8];
#pragma unroll
        for (int nd = 0; nd < 6; ++nd)
#pragma unroll
            for (int kk = 0; kk < 2; ++kk) {
                short8 bvf = *(const short8*)&Vs[16 * nd + col][kk * 32 + quad * 8];
                O[nd] = __builtin_amdgcn_mfma_f32_16x16x32_bf16(aP[kk], bvf, O[nd], 0, 0, 0);
            }

        __syncthreads();   // all waves done reading Ks/Vs
        if (nxt) {
#pragma unroll
            for (int i = 0; i < 3; ++i) {
                *(short8*)&Ks[rK[i]][cK[i]] = kst[i];
                *(short8*)&Vs[rV[i]][cV[i]] = vst[i];
            }
            __syncthreads();
        }
    }

    // rel-V band contribution: O += pdg(16x16, k 9..15 zero) . ERVB(k x 96)
    {
        short8 ad = {0, 0, 0, 0, 0, 0, 0, 0};
        if (quad < 2) ad = *(const short8*)&pdg[wv][col][quad * 8];
        const bf16* eb = ervb + (size_t)layer * 96 * 32 + (size_t)col * 32 + quad * 8;
#pragma unroll
        for (int nd = 0; nd < 6; ++nd) {
            short8 bd = *(const short8*)(eb + (size_t)nd * 16 * 32);
            O[nd] = __builtin_amdgcn_mfma_f32_16x16x32_bf16(ad, bd, O[nd], 0, 0, 0);
        }
    }

    // epilogue: write unnormalized partials
    const int rbase = (b * Hn + h) * Tn + t0w;
#pragma unroll
    for (int r = 0; r < 4; ++r) {
        const int rid = rbase + quad * 4 + r;
        bf16* dst = Op + ((size_t)sp * RN + rid) * 96 + col;
#pragma unroll
        for (int nd = 0; nd < 6; ++nd)
            dst[16 * nd] = __float2bfloat16(O[nd][r]);
        if (col == 0) Lp[sp * RN + rid] = lrow[r];
    }
}

// Combine split partials -> AT bf16 [b][t][C]. One thread per (rid, 8-chan).
__global__ __launch_bounds__(256) void attn_combine(
        const bf16* __restrict__ Op, const float* __restrict__ Lp,
        bf16* __restrict__ AT) {
    int i = blockIdx.x * 256 + threadIdx.x;       // < RN*12
    int rid = i / 12, j = i - rid * 12;
    float denom = 0.f;
    float o[8] = {};
#pragma unroll
    for (int s = 0; s < NSPLIT; ++s) {
        denom += Lp[s * RN + rid];
        short8 v = *(const short8*)(Op + ((size_t)s * RN + rid) * 96 + j * 8);
        const bf16* vb = (const bf16*)&v;
#pragma unroll
        for (int e = 0; e < 8; ++e) o[e] += __bfloat162float(vb[e]);
    }
    float inv = 1.f / fmaxf(denom, 1e-30f);
    int t = rid & (Tn - 1), h = (rid >> 10) & (Hn - 1), b = rid >> 11;
    bf16 outv[8];
#pragma unroll
    for (int e = 0; e < 8; ++e) outv[e] = __float2bfloat16(o[e] * inv);
    *(uint4*)(AT + ((size_t)b * Tn + t) * Cn + h * DKn + j * 8) = *(uint4*)outv;
}

// ---------------------------------------------------------------------------
// Residual add + LayerNorm over channels. X <- LN(X+Y)*g+b (fp32) and
// XT <- bf16 transposed [b][t][C], optionally *mask.
__global__ __launch_bounds__(256) void ln_k(
        float* __restrict__ X, const float* __restrict__ Y,
        const float* __restrict__ G, const float* __restrict__ Bt,
        const float* __restrict__ mask, bf16* __restrict__ XT, int apply_mask) {
    __shared__ float tile[Cn][33];
    __shared__ float r1[8][32];
    __shared__ float r2[8][32];
    const int tid = threadIdx.x;
    const int lane = tid & 31, w = tid >> 5;
    const int b = blockIdx.x >> 5;
    const int t0 = (blockIdx.x & 31) * 32;
    const int t = t0 + lane;

    float s1 = 0.f, s2 = 0.f;
    for (int c = w; c < Cn; c += 8) {
        float v = X[((b * Cn + c) * Tn) + t] + Y[((b * Cn + c) * Tn) + t];
        tile[c][lane] = v;
        s1 += v;
        s2 += v * v;
    }
    r1[w][lane] = s1;
    r2[w][lane] = s2;
    __syncthreads();
    if (w == 0) {
        float a = 0.f, q = 0.f;
        for (int i = 0; i < 8; ++i) { a += r1[i][lane]; q += r2[i][lane]; }
        float m = a / Cn;
        float var = q / Cn - m * m;
        r1[0][lane] = m;
        r2[0][lane] = rsqrtf(var + 1e-5f);
    }
    __syncthreads();
    const float m = r1[0][lane], rs = r2[0][lane];
    for (int c = w; c < Cn; c += 8) {
        float y = (tile[c][lane] - m) * rs * G[c] + Bt[c];
        X[((b * Cn + c) * Tn) + t] = y;
        tile[c][lane] = y;
    }
    __syncthreads();
    for (int idx = tid; idx < 32 * Cn; idx += 256) {
        int tl = idx / Cn, c = idx % Cn;
        float v = tile[c][tl];
        if (apply_mask) v *= mask[b * Tn + t0 + tl];
        XT[((size_t)b * Tn + t0 + tl) * Cn + c] = __float2bfloat16(v);
    }
}

// FFN2-combine + residual + LN2: Y = (P0+P1+bias)*mask; Xn = LN(X+Y)*g+b.
// OUT==null: X <- Xn, XT <- bf16(Xn).  OUT!=null (last layer): OUT <- Xn*mask.
__global__ __launch_bounds__(256) void ln_ffn2(
        float* __restrict__ X, const float* __restrict__ P0,
        const float* __restrict__ P1, const float* __restrict__ bias,
        const float* __restrict__ G, const float* __restrict__ Bt,
        const float* __restrict__ mask, bf16* __restrict__ XT,
        float* __restrict__ OUT) {
    __shared__ float tile[Cn][33];
    __shared__ float r1[8][32];
    __shared__ float r2[8][32];
    const int tid = threadIdx.x;
    const int lane = tid & 31, w = tid >> 5;
    const int b = blockIdx.x >> 5;
    const int t0 = (blockIdx.x & 31) * 32;
    const int t = t0 + lane;
    const float mk = mask[b * Tn + t];

    float s1 = 0.f, s2 = 0.f;
    for (int c = w; c < Cn; c += 8) {
        size_t i = ((size_t)b * Cn + c) * Tn + t;
        float y = (P0[i] + P1[i] + bias[c]) * mk;
        float v = X[i] + y;
        tile[c][lane] = v;
        s1 += v;
        s2 += v * v;
    }
    r1[w][lane] = s1;
    r2[w][lane] = s2;
    __syncthreads();
    if (w == 0) {
        float a = 0.f, q = 0.f;
        for (int i = 0; i < 8; ++i) { a += r1[i][lane]; q += r2[i][lane]; }
        float m = a / Cn;
        float var = q / Cn - m * m;
        r1[0][lane] = m;
        r2[0][lane] = rsqrtf(var + 1e-5f);
    }
    __syncthreads();
    const float m = r1[0][lane], rs = r2[0][lane];
    if (OUT) {   // final layer: write output = LN(...)*mask directly, done
        for (int c = w; c < Cn; c += 8) {
            float y = (tile[c][lane] - m) * rs * G[c] + Bt[c];
            OUT[((b * Cn + c) * Tn) + t] = y * mk;
        }
        return;
    }
    for (int c = w; c < Cn; c += 8) {
        float y = (tile[c][lane] - m) * rs * G[c] + Bt[c];
        X[((b * Cn + c) * Tn) + t] = y;
        tile[c][lane] = y;
    }
    __syncthreads();
    for (int idx = tid; idx < 32 * Cn; idx += 256) {
        int tl = idx / Cn, c = idx % Cn;
        XT[((size_t)b * Tn + t0 + tl) * Cn + c] = __float2bfloat16(tile[c][tl]);
    }
}

// ---------------------------------------------------------------------------
extern "C" void kernel_launch(void* const* d_in, const int* in_sizes, int n_in,
                              void* d_out, int out_size, void* d_ws, size_t ws_size,
                              hipStream_t stream) {
    const float* x    = (const float*)d_in[0];
    const float* mask = (const float*)d_in[1];
    const float* Wq   = (const float*)d_in[2];
    const float* bq   = (const float*)d_in[3];
    const float* Wk   = (const float*)d_in[4];
    const float* bk   = (const float*)d_in[5];
    const float* Wv   = (const float*)d_in[6];
    const float* bv   = (const float*)d_in[7];
    const float* Wo   = (const float*)d_in[8];
    const float* bo   = (const float*)d_in[9];
    const float* erk  = (const float*)d_in[10];
    const float* erv  = (const float*)d_in[11];
    const float* ln1g = (const float*)d_in[12];
    const float* ln1b = (const float*)d_in[13];
    const float* w1   = (const float*)d_in[14];
    const float* b1   = (const float*)d_in[15];
    const float* w2   = (const float*)d_in[16];
    const float* b2   = (const float*)d_in[17];
    const float* ln2g = (const float*)d_in[18];
    const float* ln2b = (const float*)d_in[19];

    const size_t N = (size_t)Bn * Cn * Tn;         // 1,572,864
    const int WC = Ln * Cn * Cn;                   // 221,184
    const size_t WF = (size_t)Ln * 3 * FCn * Cn;   // 2,654,208
    const size_t WQKV = (size_t)Ln * 576 * Cn;     // 663,552
    const size_t NSCR = (size_t)Bn * Tn * FCn;     // 6,291,456 == NSPLIT*RN*96

    float* X    = (float*)d_ws;
    float* Yb   = X + N;                           // conv_o out / FFN2 partial 0
    float* bqkv = Yb + N;                          // L*576 floats
    float* Lp   = bqkv + Ln * 576;                 // NSPLIT*RN floats
    bf16* p16 = (bf16*)(Lp + (size_t)NSPLIT * RN);
    bf16* XT   = p16; p16 += N;
    bf16* QKT  = p16; p16 += (size_t)Bn * Tn * QKS;  // 2N bf16; dead after attn
    bf16* Vb   = p16; p16 += N;
    bf16* AT   = p16; p16 += N;
    bf16* SCR  = p16; p16 += NSCR;   // shared: attn O-partials <-> FFN hidden
    bf16* Wqkv = p16; p16 += WQKV;
    bf16* Wob  = p16; p16 += WC;
    bf16* W1t  = p16; p16 += WF;
    bf16* W2t  = p16; p16 += WF;
    bf16* ERKB = p16; p16 += Ln * 16 * 96;
    bf16* ERVB = p16; p16 += Ln * 96 * 32;
    float* P1  = (float*)QKT;        // FFN2 partial 1 aliases dead QKT (N fp32)

    const float qscale = 0.10206207261596575f;  // 1/sqrt(96)

    // one-time transforms
    qkv_prep<<<(int)((WQKV + Ln * 576 + 255) / 256), 256, 0, stream>>>(
        Wq, Wk, Wv, bq, bk, bv, Wqkv, bqkv, qscale);
    cast_bf<<<(WC + 255) / 256, 256, 0, stream>>>(Wo, Wob, WC);
    reorder_w<<<(int)((WF + 255) / 256), 256, 0, stream>>>(w1, W1t, FCn, Cn);
    reorder_w<<<(int)((WF + 255) / 256), 256, 0, stream>>>(w2, W2t, Cn, FCn);
    erk_prep<<<(Ln * 16 * 96 + 255) / 256, 256, 0, stream>>>(erk, ERKB);
    erv_prep<<<(Ln * 96 * 32 + 255) / 256, 256, 0, stream>>>(erv, ERVB);
    cvt_in_k<<<Bn * 32, 256, 0, stream>>>(x, mask, X, XT);

    for (int l = 0; l < Ln; ++l) {
        conv_mfma<1, 64, 4, 1><<<dim3(Tn / 64, 9, Bn), 256, 0, stream>>>(
            XT, Wqkv + (size_t)l * 576 * Cn, bqkv + l * 576, nullptr, QKT, Vb, Cn, 576);
        attn_mfma<<<dim3(Tn / 64 * Hn * Bn * NSPLIT), 256, 0, stream>>>(
            QKT, Vb, mask, ERKB, ERVB, SCR, Lp, l);
        attn_combine<<<RN * 12 / 256, 256, 0, stream>>>(SCR, Lp, AT);
        conv_mfma<1, 32, 0, 1><<<dim3(Tn / 32, 3, Bn), 256, 0, stream>>>(
            AT, Wob + (size_t)l * Cn * Cn, bo + l * Cn, nullptr, Yb, nullptr, Cn, Cn);
        ln_k<<<Bn * 32, 256, 0, stream>>>(X, Yb, ln1g + l * Cn, ln1b + l * Cn, mask, XT, 1);
        conv_mfma<3, 64, 2, 1><<<dim3(Tn / 64, FCn / 64, Bn), 256, 0, stream>>>(
            XT, W1t + (size_t)l * 3 * FCn * Cn, b1 + l * FCn, mask, SCR, nullptr, Cn, FCn);
        conv_mfma<3, 64, 5, 2><<<dim3(Tn / 64, 3, Bn * 2), 256, 0, stream>>>(
            SCR, W2t + (size_t)l * 3 * Cn * FCn, b2 + l * Cn, mask, Yb, P1, FCn, Cn);
        ln_ffn2<<<Bn * 32, 256, 0, stream>>>(X, Yb, P1, b2 + l * Cn,
                                             ln2g + l * Cn, ln2b + l * Cn, mask, XT,
                                             (l == Ln - 1) ? (float*)d_out : nullptr);
    }
}

// Round 4
// 809.104 us; speedup vs baseline: 1.4274x; 1.1251x over previous
//
#include <hip/hip_runtime.h>
#include <hip/hip_bf16.h>

// Problem constants
constexpr int Bn  = 8;
constexpr int Cn  = 192;   // hidden channels
constexpr int Tn  = 1024;  // sequence length
constexpr int Hn  = 2;     // heads
constexpr int DKn = 96;    // head dim
constexpr int FCn = 768;   // filter channels
constexpr int Ln  = 6;     // layers
constexpr int WINn = 4;    // rel-attn window
constexpr int QKS = 384;   // QK transposed row stride (Q|K concat)
constexpr int NSPLIT = 4;  // attention s-split (flash-decoding)
constexpr int RN  = Bn * Hn * Tn;  // 16384 attention rows

typedef __hip_bfloat16 bf16;
typedef __attribute__((ext_vector_type(8))) short short8;
typedef __attribute__((ext_vector_type(4))) float f32x4;

// ---------------------------------------------------------------------------
// One-time transforms
__global__ void cast_bf(const float* __restrict__ src, bf16* __restrict__ dst, int n) {
    int i = blockIdx.x * 256 + threadIdx.x;
    if (i < n) dst[i] = __float2bfloat16(src[i]);
}

// w [L][CO][CIN][3] -> [L][3][CO][CIN] bf16
__global__ void reorder_w(const float* __restrict__ src, bf16* __restrict__ dst,
                          int CO, int CIN) {
    int i = blockIdx.x * 256 + threadIdx.x;
    int n = Ln * 3 * CO * CIN;
    if (i >= n) return;
    int c = i % CIN;
    int f = (i / CIN) % CO;
    int ko = (i / (CIN * CO)) % 3;
    int l = i / (3 * CIN * CO);
    dst[i] = __float2bfloat16(src[(((size_t)(l * CO + f)) * CIN + c) * 3 + ko]);
}

// erk fp32 [L][9][96] -> bf16 [L][16][96], rows 9..15 zero (MFMA B-frag ready)
__global__ void erk_prep(const float* __restrict__ src, bf16* __restrict__ dst) {
    int i = blockIdx.x * 256 + threadIdx.x;       // < Ln*16*96
    if (i >= Ln * 16 * 96) return;
    int d = i % 96, row = (i / 96) % 16, l = i / (96 * 16);
    float v = (row < 9) ? src[((size_t)l * 9 + row) * 96 + d] : 0.f;
    dst[i] = __float2bfloat16(v);
}

// erv fp32 [L][9][96] -> bf16 [L][96][32] transposed [d][dd], dd 9..31 zero
// (MFMA B-frag layout for the rel-V band matmul)
__global__ void erv_prep(const float* __restrict__ src, bf16* __restrict__ dst) {
    int i = blockIdx.x * 256 + threadIdx.x;       // < Ln*96*32
    if (i >= Ln * 96 * 32) return;
    int k = i & 31, d = (i >> 5) % 96, l = i / (96 * 32);
    float v = (k < 9) ? src[((size_t)l * 9 + k) * 96 + d] : 0.f;
    dst[i] = __float2bfloat16(v);
}

// Build fused QKV weight [L][576][C] bf16 (qscale folded into Q) + bias fp32
__global__ void qkv_prep(const float* __restrict__ Wq, const float* __restrict__ Wk,
                         const float* __restrict__ Wv, const float* __restrict__ bq,
                         const float* __restrict__ bk, const float* __restrict__ bv,
                         bf16* __restrict__ Wout, float* __restrict__ bout, float qscale) {
    int i = blockIdx.x * 256 + threadIdx.x;
    const int nW = Ln * 576 * Cn;
    if (i < nW) {
        int c = i % Cn, f = (i / Cn) % 576, l = i / (Cn * 576);
        float v;
        if (f < 192)      v = Wq[((size_t)l * Cn + f) * Cn + c] * qscale;
        else if (f < 384) v = Wk[((size_t)l * Cn + f - 192) * Cn + c];
        else              v = Wv[((size_t)l * Cn + f - 384) * Cn + c];
        Wout[i] = __float2bfloat16(v);
    } else if (i < nW + Ln * 576) {
        int j = i - nW, f = j % 576, l = j / 576;
        float v;
        if (f < 192)      v = bq[l * Cn + f] * qscale;
        else if (f < 384) v = bk[l * Cn + f - 192];
        else              v = bv[l * Cn + f - 384];
        bout[j] = v;
    }
}

// ---------------------------------------------------------------------------
// Input: X = x*mask (fp32, NCT) + XT = bf16 transposed [b][t][c]
__global__ __launch_bounds__(256) void cvt_in_k(
        const float* __restrict__ x, const float* __restrict__ mask,
        float* __restrict__ X, bf16* __restrict__ XT) {
    __shared__ float tile[Cn][33];
    const int tid = threadIdx.x, lane = tid & 31, w = tid >> 5;
    const int b = blockIdx.x >> 5;
    const int t0 = (blockIdx.x & 31) * 32;
    const float mk = mask[b * Tn + t0 + lane];
    for (int c = w; c < Cn; c += 8) {
        float v = x[((b * Cn + c) * Tn) + t0 + lane] * mk;
        X[((b * Cn + c) * Tn) + t0 + lane] = v;
        tile[c][lane] = v;
    }
    __syncthreads();
    for (int idx = tid; idx < 32 * Cn; idx += 256) {
        int tl = idx / Cn, c = idx % Cn;
        XT[((size_t)b * Tn + t0 + tl) * Cn + c] = __float2bfloat16(tile[c][tl]);
    }
}

// ---------------------------------------------------------------------------
// MFMA conv1d, LDS-staged.
// R4: TT=128 for the K-heavy convs (fewer blocks, 2x MFMA per barrier,
// half the B-panel re-staging) + T14 async-STAGE split: next chunk's A/B
// panels issued into registers BEFORE current chunk's compute, ds_write
// after the read-complete barrier (global latency hides under MFMAs) —
// same pattern that won in attn (R2).
// MODE 0: fp32 NCT out (+bias, *mask if mask!=null)
// MODE 2: bf16 transposed [b][t][CO] out relu(+bias)*mask   [FFN1]
// MODE 4: QKV split: f<384 -> bf16 T (stride QKS) into Y0; else bf16 NCT Y1
// MODE 5: fp32 NCT K-split partial, NO bias: ks==0 -> Y0, ks==1 -> Y1 [FFN2]
template <int KS, int TT, int MODE, int NSP>
__global__ __launch_bounds__(256) void conv_mfma(
        const bf16* __restrict__ Xt, const bf16* __restrict__ W,
        const float* __restrict__ bias, const float* __restrict__ mask,
        void* __restrict__ Y0, void* __restrict__ Y1, int CIN, int CO) {
    constexpr int PAD = KS / 2;
    constexpr int NMB = TT / 16;
    constexpr int AR  = TT + KS - 1;        // A rows staged
    constexpr int RS  = 72;                 // padded row stride (bf16 cols)
    constexpr int NA  = (AR * 8 + 255) / 256;  // per-thread A short8 loads
    constexpr int NB  = KS * 2;                // per-thread B short8 loads
    __shared__ bf16 As[AR][RS];
    __shared__ bf16 Bs[KS][64][RS];

    const int tid = threadIdx.x;
    const int wv = tid >> 6, lane = tid & 63;
    const int m = lane & 15, kq = lane >> 4;
    const int b = blockIdx.z / NSP, ks = blockIdx.z % NSP;
    const int t0 = blockIdx.x * TT;
    const int f0 = blockIdx.y * 64;
    const int f = f0 + wv * 16 + m;

    const bf16* xb = Xt + (size_t)b * Tn * CIN;
    const size_t wko = (size_t)CO * CIN;

    // per-thread staging coordinates (fixed across chunks)
    int rA[NA], cA[NA];
    bool vA[NA];
#pragma unroll
    for (int i = 0; i < NA; ++i) {
        int s = tid + i * 256;
        rA[i] = s >> 3; cA[i] = (s & 7) * 8; vA[i] = (s < AR * 8);
    }
    int rB[NB], cB[NB], koB[NB];
#pragma unroll
    for (int i = 0; i < NB; ++i) {
        int s = tid + i * 256;          // always < KS*512
        koB[i] = s >> 9; rB[i] = (s >> 3) & 63; cB[i] = (s & 7) * 8;
    }

    short8 pa[NA], pb[NB];
    const int cbeg = ks * (CIN / NSP);
    const int cend = cbeg + CIN / NSP;

    // issue + commit helpers (T14 split)
    auto issue = [&](int c0) {
#pragma unroll
        for (int i = 0; i < NA; ++i) {
            short8 v = {0, 0, 0, 0, 0, 0, 0, 0};
            if (vA[i]) {
                int gt = t0 + rA[i] - PAD;
                if (PAD == 0 || (unsigned)gt < (unsigned)Tn)
                    v = *(const short8*)(xb + (size_t)gt * CIN + c0 + cA[i]);
            }
            pa[i] = v;
        }
#pragma unroll
        for (int i = 0; i < NB; ++i)
            pb[i] = *(const short8*)(W + (size_t)koB[i] * wko +
                                     (size_t)(f0 + rB[i]) * CIN + c0 + cB[i]);
    };
    auto commit = [&]() {
#pragma unroll
        for (int i = 0; i < NA; ++i)
            if (vA[i]) *(short8*)&As[rA[i]][cA[i]] = pa[i];
#pragma unroll
        for (int i = 0; i < NB; ++i)
            *(short8*)&Bs[koB[i]][rB[i]][cB[i]] = pb[i];
    };

    f32x4 acc[NMB] = {};

    issue(cbeg);
    commit();
    __syncthreads();

    for (int c0 = cbeg; c0 < cend; c0 += 64) {
        const bool nxt = (c0 + 64 < cend);
        if (nxt) issue(c0 + 64);
#pragma unroll
        for (int kk = 0; kk < 2; ++kk)
#pragma unroll
            for (int ko = 0; ko < KS; ++ko) {
                short8 bfr = *(const short8*)&Bs[ko][wv * 16 + m][kk * 32 + kq * 8];
#pragma unroll
                for (int mb = 0; mb < NMB; ++mb) {
                    short8 afr = *(const short8*)&As[mb * 16 + m + ko][kk * 32 + kq * 8];
                    acc[mb] = __builtin_amdgcn_mfma_f32_16x16x32_bf16(afr, bfr, acc[mb], 0, 0, 0);
                }
            }
        if (nxt) {
            __syncthreads();   // all fragment reads of this chunk complete
            commit();
            __syncthreads();   // staged data visible
        }
    }

    if (MODE == 5) {
        float* Y = (float*)(ks ? Y1 : Y0) + ((size_t)b * CO + f) * Tn;
#pragma unroll
        for (int mb = 0; mb < NMB; ++mb) {
            int t = t0 + mb * 16 + kq * 4;
            float4 o;
            o.x = acc[mb][0]; o.y = acc[mb][1]; o.z = acc[mb][2]; o.w = acc[mb][3];
            *(float4*)(Y + t) = o;
        }
        return;
    }
    const float bs = bias[f];
    if (MODE == 0) {
        float* Y = (float*)Y0 + ((size_t)b * CO + f) * Tn;
#pragma unroll
        for (int mb = 0; mb < NMB; ++mb) {
            int t = t0 + mb * 16 + kq * 4;
            float4 o;
            o.x = acc[mb][0] + bs; o.y = acc[mb][1] + bs;
            o.z = acc[mb][2] + bs; o.w = acc[mb][3] + bs;
            if (mask) {
                o.x *= mask[b * Tn + t];     o.y *= mask[b * Tn + t + 1];
                o.z *= mask[b * Tn + t + 2]; o.w *= mask[b * Tn + t + 3];
            }
            *(float4*)(Y + t) = o;
        }
    } else if (MODE == 2) {
        bf16* Y = (bf16*)Y0;
#pragma unroll
        for (int mb = 0; mb < NMB; ++mb)
#pragma unroll
            for (int r = 0; r < 4; ++r) {
                int t = t0 + mb * 16 + kq * 4 + r;
                float v = fmaxf(acc[mb][r] + bs, 0.f) * mask[b * Tn + t];
                Y[((size_t)b * Tn + t) * CO + f] = __float2bfloat16(v);
            }
    } else {  // MODE 4
        if (blockIdx.y < 6) {          // Q|K -> transposed, stride QKS
            bf16* Y = (bf16*)Y0;
#pragma unroll
            for (int mb = 0; mb < NMB; ++mb)
#pragma unroll
                for (int r = 0; r < 4; ++r) {
                    int t = t0 + mb * 16 + kq * 4 + r;
                    Y[((size_t)b * Tn + t) * QKS + f] = __float2bfloat16(acc[mb][r] + bs);
                }
        } else {                        // V -> bf16 NCT
            bf16* Y = (bf16*)Y1 + ((size_t)b * Cn + f - 384) * Tn;
#pragma unroll
            for (int mb = 0; mb < NMB; ++mb) {
                int t = t0 + mb * 16 + kq * 4;
                bf16 tmp[4];
#pragma unroll
                for (int r = 0; r < 4; ++r) tmp[r] = __float2bfloat16(acc[mb][r] + bs);
                *(uint2*)(Y + t) = *(uint2*)tmp;
            }
        }
    }
}

// ---------------------------------------------------------------------------
// MFMA flash attention, split-K over s, LDS-staged K/V, XCD swizzle (R2),
// T14 async-STAGE split (R2), rel-V via MFMA (R3).
// FIXED-MAX softmax (scores O(5), exp safe in fp32).
// Writes UNNORMALIZED partials: Op bf16 [sp][rid][96], Lp fp32 [sp][rid].
__global__ __launch_bounds__(256) void attn_mfma(
        const bf16* __restrict__ QK, const bf16* __restrict__ V,
        const float* __restrict__ mask, const bf16* __restrict__ erkb,
        const bf16* __restrict__ ervb, bf16* __restrict__ Op,
        float* __restrict__ Lp, int layer) {
    __shared__ bf16 Ks[64][100];      // K chunk [s][d]
    __shared__ bf16 Vs[96][68];       // V chunk [d][s]
    __shared__ float rq[4][16][17];   // per-wave rel-K band: [m][dd]
    __shared__ bf16 pT[4][16][68];    // per-wave P: [m][s]
    __shared__ bf16 pdg[4][16][16];   // per-wave rel-V band: [m][dd], 9..15 zero
    // LDS total: 12800+13056+4352+8704+2048 = 40960 B -> 4 blocks/CU exactly

    const int tid = threadIdx.x, wv = tid >> 6, lane = tid & 63;
    const int col = lane & 15, quad = lane >> 4;
    // XCD-bijective swizzle (1024 = 8 XCD x 128; id%8 = XCD round-robin)
    const int w = (blockIdx.x & 7) * 128 + (blockIdx.x >> 3);
    const int t0 = (w & 15) * 64;
    const int yz = w >> 4;
    const int h = yz & 1;
    const int z = yz >> 1;
    const int b = z >> 2, sp = z & 3;
    const int hd = h * DKn;
    const int t0w = t0 + wv * 16;

    // zero per-wave rel-V band (rows not hit by any chunk stay zero)
    *(uint2*)&pdg[wv][lane & 15][(lane >> 4) * 4] = (uint2){0, 0};

    // staging geometry (3 short8 per thread for K, 3 for V)
    int rK[3], cK[3], rV[3], cV[3];
#pragma unroll
    for (int i = 0; i < 3; ++i) {
        int s = tid + i * 256;
        rK[i] = s / 12; cK[i] = (s % 12) * 8;   // 64 rows x 96 cols
        rV[i] = s >> 3; cV[i] = (s & 7) * 8;    // 96 rows x 64 cols
    }
    const bf16* kbase = QK + (size_t)b * Tn * QKS + 192 + hd;
    const bf16* vbase = V + ((size_t)b * Cn + hd) * Tn;

    short8 kst[3], vst[3];
    const int sbeg = sp * (Tn / NSPLIT);
    const int send = sbeg + Tn / NSPLIT;

    // issue first chunk's loads immediately (latency hides under Q/rq prep)
#pragma unroll
    for (int i = 0; i < 3; ++i) {
        kst[i] = *(const short8*)(kbase + (size_t)(sbeg + rK[i]) * QKS + cK[i]);
        vst[i] = *(const short8*)(vbase + (size_t)rV[i] * Tn + sbeg + cV[i]);
    }

    // Q A-frags (persist): A[m=col][k=quad*8+j+32*kd]
    short8 aq[3];
    {
        const bf16* qrow = QK + ((size_t)b * Tn + t0w + col) * QKS + hd + quad * 8;
#pragma unroll
        for (int kd = 0; kd < 3; ++kd) aq[kd] = *(const short8*)(qrow + kd * 32);
    }
    // rel-K band via MFMA: R = Q . erk^T  (B rows 9..15 are zero)
    {
        const bf16* erow = erkb + ((size_t)layer * 16 + col) * 96 + quad * 8;
        f32x4 R = {};
#pragma unroll
        for (int kd = 0; kd < 3; ++kd) {
            short8 be = *(const short8*)(erow + kd * 32);
            R = __builtin_amdgcn_mfma_f32_16x16x32_bf16(aq[kd], be, R, 0, 0, 0);
        }
#pragma unroll
        for (int r = 0; r < 4; ++r) rq[wv][quad * 4 + r][col] = R[r];
    }
    float mtv[4];
#pragma unroll
    for (int r = 0; r < 4; ++r) mtv[r] = mask[b * Tn + t0w + quad * 4 + r];

    // first chunk into LDS
#pragma unroll
    for (int i = 0; i < 3; ++i) {
        *(short8*)&Ks[rK[i]][cK[i]] = kst[i];
        *(short8*)&Vs[rV[i]][cV[i]] = vst[i];
    }
    __syncthreads();

    float lrow[4] = {};
    f32x4 O[6] = {};

    for (int s0 = sbeg; s0 < send; s0 += 64) {
        const bool nxt = (s0 + 64 < send);
        // T14: issue NEXT chunk's global loads now; ds_write after barrier
        if (nxt) {
#pragma unroll
            for (int i = 0; i < 3; ++i) {
                kst[i] = *(const short8*)(kbase + (size_t)(s0 + 64 + rK[i]) * QKS + cK[i]);
                vst[i] = *(const short8*)(vbase + (size_t)rV[i] * Tn + s0 + 64 + cV[i]);
            }
        }

        // S = Q K^T (B-frags from LDS)
        f32x4 S[4] = {};
#pragma unroll
        for (int nb = 0; nb < 4; ++nb)
#pragma unroll
            for (int kd = 0; kd < 3; ++kd) {
                short8 bkf = *(const short8*)&Ks[16 * nb + col][kd * 32 + quad * 8];
                S[nb] = __builtin_amdgcn_mfma_f32_16x16x32_bf16(aq[kd], bkf, S[nb], 0, 0, 0);
            }

#pragma unroll
        for (int nb = 0; nb < 4; ++nb) {
            const int sg = s0 + 16 * nb + col;
            const float msv = mask[b * Tn + sg];
#pragma unroll
            for (int r = 0; r < 4; ++r) {
                const int tq = t0w + quad * 4 + r;
                float v = S[nb][r];
                int dd = sg - tq + WINn;
                if (dd >= 0 && dd <= 2 * WINn) v += rq[wv][quad * 4 + r][dd];
                if (msv * mtv[r] == 0.f) v = -1e4f;
                S[nb][r] = v;
            }
        }

        // fixed-max softmax: P = exp(S); row-sum via 16-lane shuffle reduce.
        // Band values additionally dropped into pdg for the rel-V MFMA.
        float psum[4] = {};
#pragma unroll
        for (int nb = 0; nb < 4; ++nb) {
            const int sg = s0 + 16 * nb + col;
#pragma unroll
            for (int r = 0; r < 4; ++r) {
                bf16 pb = __float2bfloat16(__expf(S[nb][r]));
                pT[wv][quad * 4 + r][16 * nb + col] = pb;
                int dd = sg - (t0w + quad * 4 + r) + WINn;
                if ((unsigned)dd <= 2u * WINn) pdg[wv][quad * 4 + r][dd] = pb;
                psum[r] += __bfloat162float(pb);
            }
        }
#pragma unroll
        for (int r = 0; r < 4; ++r) {
#pragma unroll
            for (int mk2 = 1; mk2 < 16; mk2 <<= 1) psum[r] += __shfl_xor(psum[r], mk2);
            lrow[r] += psum[r];
        }

        // P A-frags from per-wave LDS; PV (V B-frags from shared LDS)
        short8 aP[2];
#pragma unroll
        for (int kk = 0; kk < 2; ++kk)
            aP[kk] = *(const short8*)&pT[wv][col][kk * 32 + quad * 8];
#pragma unroll
        for (int nd = 0; nd < 6; ++nd)
#pragma unroll
            for (int kk = 0; kk < 2; ++kk) {
                short8 bvf = *(const short8*)&Vs[16 * nd + col][kk * 32 + quad * 8];
                O[nd] = __builtin_amdgcn_mfma_f32_16x16x32_bf16(aP[kk], bvf, O[nd], 0, 0, 0);
            }

        __syncthreads();   // all waves done reading Ks/Vs
        if (nxt) {
#pragma unroll
            for (int i = 0; i < 3; ++i) {
                *(short8*)&Ks[rK[i]][cK[i]] = kst[i];
                *(short8*)&Vs[rV[i]][cV[i]] = vst[i];
            }
            __syncthreads();
        }
    }

    // rel-V band contribution: O += pdg(16x16, k 9..15 zero) . ERVB(k x 96)
    {
        short8 ad = {0, 0, 0, 0, 0, 0, 0, 0};
        if (quad < 2) ad = *(const short8*)&pdg[wv][col][quad * 8];
        const bf16* eb = ervb + (size_t)layer * 96 * 32 + (size_t)col * 32 + quad * 8;
#pragma unroll
        for (int nd = 0; nd < 6; ++nd) {
            short8 bd = *(const short8*)(eb + (size_t)nd * 16 * 32);
            O[nd] = __builtin_amdgcn_mfma_f32_16x16x32_bf16(ad, bd, O[nd], 0, 0, 0);
        }
    }

    // epilogue: write unnormalized partials
    const int rbase = (b * Hn + h) * Tn + t0w;
#pragma unroll
    for (int r = 0; r < 4; ++r) {
        const int rid = rbase + quad * 4 + r;
        bf16* dst = Op + ((size_t)sp * RN + rid) * 96 + col;
#pragma unroll
        for (int nd = 0; nd < 6; ++nd)
            dst[16 * nd] = __float2bfloat16(O[nd][r]);
        if (col == 0) Lp[sp * RN + rid] = lrow[r];
    }
}

// Combine split partials -> AT bf16 [b][t][C]. One thread per (rid, 8-chan).
__global__ __launch_bounds__(256) void attn_combine(
        const bf16* __restrict__ Op, const float* __restrict__ Lp,
        bf16* __restrict__ AT) {
    int i = blockIdx.x * 256 + threadIdx.x;       // < RN*12
    int rid = i / 12, j = i - rid * 12;
    float denom = 0.f;
    float o[8] = {};
#pragma unroll
    for (int s = 0; s < NSPLIT; ++s) {
        denom += Lp[s * RN + rid];
        short8 v = *(const short8*)(Op + ((size_t)s * RN + rid) * 96 + j * 8);
        const bf16* vb = (const bf16*)&v;
#pragma unroll
        for (int e = 0; e < 8; ++e) o[e] += __bfloat162float(vb[e]);
    }
    float inv = 1.f / fmaxf(denom, 1e-30f);
    int t = rid & (Tn - 1), h = (rid >> 10) & (Hn - 1), b = rid >> 11;
    bf16 outv[8];
#pragma unroll
    for (int e = 0; e < 8; ++e) outv[e] = __float2bfloat16(o[e] * inv);
    *(uint4*)(AT + ((size_t)b * Tn + t) * Cn + h * DKn + j * 8) = *(uint4*)outv;
}

// ---------------------------------------------------------------------------
// Residual add + LayerNorm over channels. X <- LN(X+Y)*g+b (fp32) and
// XT <- bf16 transposed [b][t][C], optionally *mask.
__global__ __launch_bounds__(256) void ln_k(
        float* __restrict__ X, const float* __restrict__ Y,
        const float* __restrict__ G, const float* __restrict__ Bt,
        const float* __restrict__ mask, bf16* __restrict__ XT, int apply_mask) {
    __shared__ float tile[Cn][33];
    __shared__ float r1[8][32];
    __shared__ float r2[8][32];
    const int tid = threadIdx.x;
    const int lane = tid & 31, w = tid >> 5;
    const int b = blockIdx.x >> 5;
    const int t0 = (blockIdx.x & 31) * 32;
    const int t = t0 + lane;

    float s1 = 0.f, s2 = 0.f;
    for (int c = w; c < Cn; c += 8) {
        float v = X[((b * Cn + c) * Tn) + t] + Y[((b * Cn + c) * Tn) + t];
        tile[c][lane] = v;
        s1 += v;
        s2 += v * v;
    }
    r1[w][lane] = s1;
    r2[w][lane] = s2;
    __syncthreads();
    if (w == 0) {
        float a = 0.f, q = 0.f;
        for (int i = 0; i < 8; ++i) { a += r1[i][lane]; q += r2[i][lane]; }
        float m = a / Cn;
        float var = q / Cn - m * m;
        r1[0][lane] = m;
        r2[0][lane] = rsqrtf(var + 1e-5f);
    }
    __syncthreads();
    const float m = r1[0][lane], rs = r2[0][lane];
    for (int c = w; c < Cn; c += 8) {
        float y = (tile[c][lane] - m) * rs * G[c] + Bt[c];
        X[((b * Cn + c) * Tn) + t] = y;
        tile[c][lane] = y;
    }
    __syncthreads();
    for (int idx = tid; idx < 32 * Cn; idx += 256) {
        int tl = idx / Cn, c = idx % Cn;
        float v = tile[c][tl];
        if (apply_mask) v *= mask[b * Tn + t0 + tl];
        XT[((size_t)b * Tn + t0 + tl) * Cn + c] = __float2bfloat16(v);
    }
}

// FFN2-combine + residual + LN2: Y = (P0+P1+bias)*mask; Xn = LN(X+Y)*g+b.
// OUT==null: X <- Xn, XT <- bf16(Xn).  OUT!=null (last layer): OUT <- Xn*mask.
__global__ __launch_bounds__(256) void ln_ffn2(
        float* __restrict__ X, const float* __restrict__ P0,
        const float* __restrict__ P1, const float* __restrict__ bias,
        const float* __restrict__ G, const float* __restrict__ Bt,
        const float* __restrict__ mask, bf16* __restrict__ XT,
        float* __restrict__ OUT) {
    __shared__ float tile[Cn][33];
    __shared__ float r1[8][32];
    __shared__ float r2[8][32];
    const int tid = threadIdx.x;
    const int lane = tid & 31, w = tid >> 5;
    const int b = blockIdx.x >> 5;
    const int t0 = (blockIdx.x & 31) * 32;
    const int t = t0 + lane;
    const float mk = mask[b * Tn + t];

    float s1 = 0.f, s2 = 0.f;
    for (int c = w; c < Cn; c += 8) {
        size_t i = ((size_t)b * Cn + c) * Tn + t;
        float y = (P0[i] + P1[i] + bias[c]) * mk;
        float v = X[i] + y;
        tile[c][lane] = v;
        s1 += v;
        s2 += v * v;
    }
    r1[w][lane] = s1;
    r2[w][lane] = s2;
    __syncthreads();
    if (w == 0) {
        float a = 0.f, q = 0.f;
        for (int i = 0; i < 8; ++i) { a += r1[i][lane]; q += r2[i][lane]; }
        float m = a / Cn;
        float var = q / Cn - m * m;
        r1[0][lane] = m;
        r2[0][lane] = rsqrtf(var + 1e-5f);
    }
    __syncthreads();
    const float m = r1[0][lane], rs = r2[0][lane];
    if (OUT) {   // final layer: write output = LN(...)*mask directly, done
        for (int c = w; c < Cn; c += 8) {
            float y = (tile[c][lane] - m) * rs * G[c] + Bt[c];
            OUT[((b * Cn + c) * Tn) + t] = y * mk;
        }
        return;
    }
    for (int c = w; c < Cn; c += 8) {
        float y = (tile[c][lane] - m) * rs * G[c] + Bt[c];
        X[((b * Cn + c) * Tn) + t] = y;
        tile[c][lane] = y;
    }
    __syncthreads();
    for (int idx = tid; idx < 32 * Cn; idx += 256) {
        int tl = idx / Cn, c = idx % Cn;
        XT[((size_t)b * Tn + t0 + tl) * Cn + c] = __float2bfloat16(tile[c][tl]);
    }
}

// ---------------------------------------------------------------------------
extern "C" void kernel_launch(void* const* d_in, const int* in_sizes, int n_in,
                              void* d_out, int out_size, void* d_ws, size_t ws_size,
                              hipStream_t stream) {
    const float* x    = (const float*)d_in[0];
    const float* mask = (const float*)d_in[1];
    const float* Wq   = (const float*)d_in[2];
    const float* bq   = (const float*)d_in[3];
    const float* Wk   = (const float*)d_in[4];
    const float* bk   = (const float*)d_in[5];
    const float* Wv   = (const float*)d_in[6];
    const float* bv   = (const float*)d_in[7];
    const float* Wo   = (const float*)d_in[8];
    const float* bo   = (const float*)d_in[9];
    const float* erk  = (const float*)d_in[10];
    const float* erv  = (const float*)d_in[11];
    const float* ln1g = (const float*)d_in[12];
    const float* ln1b = (const float*)d_in[13];
    const float* w1   = (const float*)d_in[14];
    const float* b1   = (const float*)d_in[15];
    const float* w2   = (const float*)d_in[16];
    const float* b2   = (const float*)d_in[17];
    const float* ln2g = (const float*)d_in[18];
    const float* ln2b = (const float*)d_in[19];

    const size_t N = (size_t)Bn * Cn * Tn;         // 1,572,864
    const int WC = Ln * Cn * Cn;                   // 221,184
    const size_t WF = (size_t)Ln * 3 * FCn * Cn;   // 2,654,208
    const size_t WQKV = (size_t)Ln * 576 * Cn;     // 663,552
    const size_t NSCR = (size_t)Bn * Tn * FCn;     // 6,291,456 == NSPLIT*RN*96

    float* X    = (float*)d_ws;
    float* Yb   = X + N;                           // conv_o out / FFN2 partial 0
    float* bqkv = Yb + N;                          // L*576 floats
    float* Lp   = bqkv + Ln * 576;                 // NSPLIT*RN floats
    bf16* p16 = (bf16*)(Lp + (size_t)NSPLIT * RN);
    bf16* XT   = p16; p16 += N;
    bf16* QKT  = p16; p16 += (size_t)Bn * Tn * QKS;  // 2N bf16; dead after attn
    bf16* Vb   = p16; p16 += N;
    bf16* AT   = p16; p16 += N;
    bf16* SCR  = p16; p16 += NSCR;   // shared: attn O-partials <-> FFN hidden
    bf16* Wqkv = p16; p16 += WQKV;
    bf16* Wob  = p16; p16 += WC;
    bf16* W1t  = p16; p16 += WF;
    bf16* W2t  = p16; p16 += WF;
    bf16* ERKB = p16; p16 += Ln * 16 * 96;
    bf16* ERVB = p16; p16 += Ln * 96 * 32;
    float* P1  = (float*)QKT;        // FFN2 partial 1 aliases dead QKT (N fp32)

    const float qscale = 0.10206207261596575f;  // 1/sqrt(96)

    // one-time transforms
    qkv_prep<<<(int)((WQKV + Ln * 576 + 255) / 256), 256, 0, stream>>>(
        Wq, Wk, Wv, bq, bk, bv, Wqkv, bqkv, qscale);
    cast_bf<<<(WC + 255) / 256, 256, 0, stream>>>(Wo, Wob, WC);
    reorder_w<<<(int)((WF + 255) / 256), 256, 0, stream>>>(w1, W1t, FCn, Cn);
    reorder_w<<<(int)((WF + 255) / 256), 256, 0, stream>>>(w2, W2t, Cn, FCn);
    erk_prep<<<(Ln * 16 * 96 + 255) / 256, 256, 0, stream>>>(erk, ERKB);
    erv_prep<<<(Ln * 96 * 32 + 255) / 256, 256, 0, stream>>>(erv, ERVB);
    cvt_in_k<<<Bn * 32, 256, 0, stream>>>(x, mask, X, XT);

    for (int l = 0; l < Ln; ++l) {
        conv_mfma<1, 128, 4, 1><<<dim3(Tn / 128, 9, Bn), 256, 0, stream>>>(
            XT, Wqkv + (size_t)l * 576 * Cn, bqkv + l * 576, nullptr, QKT, Vb, Cn, 576);
        attn_mfma<<<dim3(Tn / 64 * Hn * Bn * NSPLIT), 256, 0, stream>>>(
            QKT, Vb, mask, ERKB, ERVB, SCR, Lp, l);
        attn_combine<<<RN * 12 / 256, 256, 0, stream>>>(SCR, Lp, AT);
        conv_mfma<1, 64, 0, 1><<<dim3(Tn / 64, 3, Bn), 256, 0, stream>>>(
            AT, Wob + (size_t)l * Cn * Cn, bo + l * Cn, nullptr, Yb, nullptr, Cn, Cn);
        ln_k<<<Bn * 32, 256, 0, stream>>>(X, Yb, ln1g + l * Cn, ln1b + l * Cn, mask, XT, 1);
        conv_mfma<3, 128, 2, 1><<<dim3(Tn / 128, FCn / 64, Bn), 256, 0, stream>>>(
            XT, W1t + (size_t)l * 3 * FCn * Cn, b1 + l * FCn, mask, SCR, nullptr, Cn, FCn);
        conv_mfma<3, 128, 5, 2><<<dim3(Tn / 128, 3, Bn * 2), 256, 0, stream>>>(
            SCR, W2t + (size_t)l * 3 * Cn * FCn, b2 + l * Cn, mask, Yb, P1, FCn, Cn);
        ln_ffn2<<<Bn * 32, 256, 0, stream>>>(X, Yb, P1, b2 + l * Cn,
                                             ln2g + l * Cn, ln2b + l * Cn, mask, XT,
                                             (l == Ln - 1) ? (float*)d_out : nullptr);
    }
}

// Round 5
// 802.012 us; speedup vs baseline: 1.4400x; 1.0088x over previous
//
#include <hip/hip_runtime.h>
#include <hip/hip_bf16.h>

// Problem constants
constexpr int Bn  = 8;
constexpr int Cn  = 192;   // hidden channels
constexpr int Tn  = 1024;  // sequence length
constexpr int Hn  = 2;     // heads
constexpr int DKn = 96;    // head dim
constexpr int FCn = 768;   // filter channels
constexpr int Ln  = 6;     // layers
constexpr int WINn = 4;    // rel-attn window
constexpr int QKS = 384;   // QK transposed row stride (Q|K concat)
constexpr int NSPLIT = 4;  // attention s-split (flash-decoding)
constexpr int RN  = Bn * Hn * Tn;  // 16384 attention rows

typedef __hip_bfloat16 bf16;
typedef __attribute__((ext_vector_type(8))) short short8;
typedef __attribute__((ext_vector_type(4))) float f32x4;

// ---------------------------------------------------------------------------
// One-time transforms
__global__ void cast_bf(const float* __restrict__ src, bf16* __restrict__ dst, int n) {
    int i = blockIdx.x * 256 + threadIdx.x;
    if (i < n) dst[i] = __float2bfloat16(src[i]);
}

// w [L][CO][CIN][3] -> [L][3][CO][CIN] bf16
__global__ void reorder_w(const float* __restrict__ src, bf16* __restrict__ dst,
                          int CO, int CIN) {
    int i = blockIdx.x * 256 + threadIdx.x;
    int n = Ln * 3 * CO * CIN;
    if (i >= n) return;
    int c = i % CIN;
    int f = (i / CIN) % CO;
    int ko = (i / (CIN * CO)) % 3;
    int l = i / (3 * CIN * CO);
    dst[i] = __float2bfloat16(src[(((size_t)(l * CO + f)) * CIN + c) * 3 + ko]);
}

// erk fp32 [L][9][96] -> bf16 [L][16][96], rows 9..15 zero (MFMA B-frag ready)
__global__ void erk_prep(const float* __restrict__ src, bf16* __restrict__ dst) {
    int i = blockIdx.x * 256 + threadIdx.x;       // < Ln*16*96
    if (i >= Ln * 16 * 96) return;
    int d = i % 96, row = (i / 96) % 16, l = i / (96 * 16);
    float v = (row < 9) ? src[((size_t)l * 9 + row) * 96 + d] : 0.f;
    dst[i] = __float2bfloat16(v);
}

// erv fp32 [L][9][96] -> bf16 [L][96][32] transposed [d][dd], dd 9..31 zero
// (MFMA B-frag layout for the rel-V band matmul)
__global__ void erv_prep(const float* __restrict__ src, bf16* __restrict__ dst) {
    int i = blockIdx.x * 256 + threadIdx.x;       // < Ln*96*32
    if (i >= Ln * 96 * 32) return;
    int k = i & 31, d = (i >> 5) % 96, l = i / (96 * 32);
    float v = (k < 9) ? src[((size_t)l * 9 + k) * 96 + d] : 0.f;
    dst[i] = __float2bfloat16(v);
}

// Build fused QKV weight [L][576][C] bf16 (qscale folded into Q) + bias fp32
__global__ void qkv_prep(const float* __restrict__ Wq, const float* __restrict__ Wk,
                         const float* __restrict__ Wv, const float* __restrict__ bq,
                         const float* __restrict__ bk, const float* __restrict__ bv,
                         bf16* __restrict__ Wout, float* __restrict__ bout, float qscale) {
    int i = blockIdx.x * 256 + threadIdx.x;
    const int nW = Ln * 576 * Cn;
    if (i < nW) {
        int c = i % Cn, f = (i / Cn) % 576, l = i / (Cn * 576);
        float v;
        if (f < 192)      v = Wq[((size_t)l * Cn + f) * Cn + c] * qscale;
        else if (f < 384) v = Wk[((size_t)l * Cn + f - 192) * Cn + c];
        else              v = Wv[((size_t)l * Cn + f - 384) * Cn + c];
        Wout[i] = __float2bfloat16(v);
    } else if (i < nW + Ln * 576) {
        int j = i - nW, f = j % 576, l = j / 576;
        float v;
        if (f < 192)      v = bq[l * Cn + f] * qscale;
        else if (f < 384) v = bk[l * Cn + f - 192];
        else              v = bv[l * Cn + f - 384];
        bout[j] = v;
    }
}

// ---------------------------------------------------------------------------
// Input: X = x*mask (fp32, NCT) + XT = bf16 transposed [b][t][c]
__global__ __launch_bounds__(256) void cvt_in_k(
        const float* __restrict__ x, const float* __restrict__ mask,
        float* __restrict__ X, bf16* __restrict__ XT) {
    __shared__ float tile[Cn][33];
    const int tid = threadIdx.x, lane = tid & 31, w = tid >> 5;
    const int b = blockIdx.x >> 5;
    const int t0 = (blockIdx.x & 31) * 32;
    const float mk = mask[b * Tn + t0 + lane];
    for (int c = w; c < Cn; c += 8) {
        float v = x[((b * Cn + c) * Tn) + t0 + lane] * mk;
        X[((b * Cn + c) * Tn) + t0 + lane] = v;
        tile[c][lane] = v;
    }
    __syncthreads();
    for (int idx = tid; idx < 32 * Cn; idx += 256) {
        int tl = idx / Cn, c = idx % Cn;
        XT[((size_t)b * Tn + t0 + tl) * Cn + c] = __float2bfloat16(tile[c][tl]);
    }
}

// ---------------------------------------------------------------------------
// MFMA conv1d, LDS-staged, TT=128 for K-heavy convs, T14 async-STAGE (R4).
// MODE 0: fp32 NCT out (+bias, *mask if mask!=null)
// MODE 2: bf16 transposed [b][t][CO] out relu(+bias)*mask   [FFN1]
// MODE 4: QKV split: f<384 -> bf16 T (stride QKS) into Y0; else bf16 NCT Y1
// MODE 5: fp32 NCT K-split partial, NO bias: ks==0 -> Y0, ks==1 -> Y1 [FFN2]
// MODE 6 (R5): Wo conv with FUSED attn split-combine. Xt := Op partials
//   bf16 [sp][rid][96], mask := Lp fp32 [sp][rid]. A-staging loads the 4
//   partials + denominators, normalizes in registers at commit (math
//   identical to the old attn_combine kernel). fp32 NCT out + bias.
template <int KS, int TT, int MODE, int NSP>
__global__ __launch_bounds__(256) void conv_mfma(
        const bf16* __restrict__ Xt, const bf16* __restrict__ W,
        const float* __restrict__ bias, const float* __restrict__ mask,
        void* __restrict__ Y0, void* __restrict__ Y1, int CIN, int CO) {
    constexpr int PAD = KS / 2;
    constexpr int NMB = TT / 16;
    constexpr int AR  = TT + KS - 1;        // A rows staged
    constexpr int RS  = 72;                 // padded row stride (bf16 cols)
    constexpr int NA  = (AR * 8 + 255) / 256;  // per-thread A short8 loads
    constexpr int NB  = KS * 2;                // per-thread B short8 loads
    __shared__ bf16 As[AR][RS];
    __shared__ bf16 Bs[KS][64][RS];

    const int tid = threadIdx.x;
    const int wv = tid >> 6, lane = tid & 63;
    const int m = lane & 15, kq = lane >> 4;
    const int b = blockIdx.z / NSP, ks = blockIdx.z % NSP;
    const int t0 = blockIdx.x * TT;
    const int f0 = blockIdx.y * 64;
    const int f = f0 + wv * 16 + m;

    const bf16* xb = Xt + (size_t)b * Tn * CIN;
    const size_t wko = (size_t)CO * CIN;

    // per-thread staging coordinates (fixed across chunks)
    int rA[NA], cA[NA];
    bool vA[NA];
#pragma unroll
    for (int i = 0; i < NA; ++i) {
        int s = tid + i * 256;
        rA[i] = s >> 3; cA[i] = (s & 7) * 8; vA[i] = (s < AR * 8);
    }
    int rB[NB], cB[NB], koB[NB];
#pragma unroll
    for (int i = 0; i < NB; ++i) {
        int s = tid + i * 256;          // always < KS*512
        koB[i] = s >> 9; rB[i] = (s >> 3) & 63; cB[i] = (s & 7) * 8;
    }

    short8 pa[NA], pb[NB];
    short8 pa6[(MODE == 6) ? NA : 1][4];
    float  pl6[(MODE == 6) ? NA : 1][4];
    const int cbeg = ks * (CIN / NSP);
    const int cend = cbeg + CIN / NSP;

    // issue + commit helpers (T14 split)
    auto issue = [&](int c0) {
        if constexpr (MODE == 6) {
#pragma unroll
            for (int i = 0; i < NA; ++i) {
                int c = c0 + cA[i];
                int hh = (c >= 96) ? 1 : 0;
                int rid = (b * Hn + hh) * Tn + t0 + rA[i];
                int d0 = c - 96 * hh;
#pragma unroll
                for (int sp = 0; sp < 4; ++sp) {
                    pa6[i][sp] = *(const short8*)(Xt + ((size_t)sp * RN + rid) * 96 + d0);
                    pl6[i][sp] = mask[sp * RN + rid];
                }
            }
        } else {
#pragma unroll
            for (int i = 0; i < NA; ++i) {
                short8 v = {0, 0, 0, 0, 0, 0, 0, 0};
                if (vA[i]) {
                    int gt = t0 + rA[i] - PAD;
                    if (PAD == 0 || (unsigned)gt < (unsigned)Tn)
                        v = *(const short8*)(xb + (size_t)gt * CIN + c0 + cA[i]);
                }
                pa[i] = v;
            }
        }
#pragma unroll
        for (int i = 0; i < NB; ++i)
            pb[i] = *(const short8*)(W + (size_t)koB[i] * wko +
                                     (size_t)(f0 + rB[i]) * CIN + c0 + cB[i]);
    };
    auto commit = [&]() {
        if constexpr (MODE == 6) {
#pragma unroll
            for (int i = 0; i < NA; ++i) {
                float denom = pl6[i][0] + pl6[i][1] + pl6[i][2] + pl6[i][3];
                float inv = 1.f / fmaxf(denom, 1e-30f);
                bf16 tmp[8];
#pragma unroll
                for (int e = 0; e < 8; ++e) {
                    float o = 0.f;
#pragma unroll
                    for (int sp = 0; sp < 4; ++sp)
                        o += __bfloat162float(((const bf16*)&pa6[i][sp])[e]);
                    tmp[e] = __float2bfloat16(o * inv);
                }
                *(short8*)&As[rA[i]][cA[i]] = *(const short8*)tmp;
            }
        } else {
#pragma unroll
            for (int i = 0; i < NA; ++i)
                if (vA[i]) *(short8*)&As[rA[i]][cA[i]] = pa[i];
        }
#pragma unroll
        for (int i = 0; i < NB; ++i)
            *(short8*)&Bs[koB[i]][rB[i]][cB[i]] = pb[i];
    };

    f32x4 acc[NMB] = {};

    issue(cbeg);
    commit();
    __syncthreads();

    for (int c0 = cbeg; c0 < cend; c0 += 64) {
        const bool nxt = (c0 + 64 < cend);
        if (nxt) issue(c0 + 64);
#pragma unroll
        for (int kk = 0; kk < 2; ++kk)
#pragma unroll
            for (int ko = 0; ko < KS; ++ko) {
                short8 bfr = *(const short8*)&Bs[ko][wv * 16 + m][kk * 32 + kq * 8];
#pragma unroll
                for (int mb = 0; mb < NMB; ++mb) {
                    short8 afr = *(const short8*)&As[mb * 16 + m + ko][kk * 32 + kq * 8];
                    acc[mb] = __builtin_amdgcn_mfma_f32_16x16x32_bf16(afr, bfr, acc[mb], 0, 0, 0);
                }
            }
        if (nxt) {
            __syncthreads();   // all fragment reads of this chunk complete
            commit();
            __syncthreads();   // staged data visible
        }
    }

    if (MODE == 5) {
        float* Y = (float*)(ks ? Y1 : Y0) + ((size_t)b * CO + f) * Tn;
#pragma unroll
        for (int mb = 0; mb < NMB; ++mb) {
            int t = t0 + mb * 16 + kq * 4;
            float4 o;
            o.x = acc[mb][0]; o.y = acc[mb][1]; o.z = acc[mb][2]; o.w = acc[mb][3];
            *(float4*)(Y + t) = o;
        }
        return;
    }
    const float bs = bias[f];
    if (MODE == 0 || MODE == 6) {
        float* Y = (float*)Y0 + ((size_t)b * CO + f) * Tn;
#pragma unroll
        for (int mb = 0; mb < NMB; ++mb) {
            int t = t0 + mb * 16 + kq * 4;
            float4 o;
            o.x = acc[mb][0] + bs; o.y = acc[mb][1] + bs;
            o.z = acc[mb][2] + bs; o.w = acc[mb][3] + bs;
            if (MODE == 0 && mask) {
                o.x *= mask[b * Tn + t];     o.y *= mask[b * Tn + t + 1];
                o.z *= mask[b * Tn + t + 2]; o.w *= mask[b * Tn + t + 3];
            }
            *(float4*)(Y + t) = o;
        }
    } else if (MODE == 2) {
        bf16* Y = (bf16*)Y0;
#pragma unroll
        for (int mb = 0; mb < NMB; ++mb)
#pragma unroll
            for (int r = 0; r < 4; ++r) {
                int t = t0 + mb * 16 + kq * 4 + r;
                float v = fmaxf(acc[mb][r] + bs, 0.f) * mask[b * Tn + t];
                Y[((size_t)b * Tn + t) * CO + f] = __float2bfloat16(v);
            }
    } else {  // MODE 4
        if (blockIdx.y < 6) {          // Q|K -> transposed, stride QKS
            bf16* Y = (bf16*)Y0;
#pragma unroll
            for (int mb = 0; mb < NMB; ++mb)
#pragma unroll
                for (int r = 0; r < 4; ++r) {
                    int t = t0 + mb * 16 + kq * 4 + r;
                    Y[((size_t)b * Tn + t) * QKS + f] = __float2bfloat16(acc[mb][r] + bs);
                }
        } else {                        // V -> bf16 NCT
            bf16* Y = (bf16*)Y1 + ((size_t)b * Cn + f - 384) * Tn;
#pragma unroll
            for (int mb = 0; mb < NMB; ++mb) {
                int t = t0 + mb * 16 + kq * 4;
                bf16 tmp[4];
#pragma unroll
                for (int r = 0; r < 4; ++r) tmp[r] = __float2bfloat16(acc[mb][r] + bs);
                *(uint2*)(Y + t) = *(uint2*)tmp;
            }
        }
    }
}

// ---------------------------------------------------------------------------
// MFMA flash attention, split-K over s, LDS-staged K/V, XCD swizzle (R2),
// T14 async-STAGE split (R2), rel-V via MFMA (R3).
// R5: VALU-chain cuts —
//  * row-sum via ones-MFMA: Osum = mfma(aP, 1.0) replaces the per-chunk
//    16-lane shuffle butterfly (same bf16 P values, fp32 MFMA accumulate).
//  * wave-uniform gating: rel-K band add + pdg capture only on diagonal
//    chunks; -1e4 mask fixup only when okbits says some mask elem is 0.
//  * T5 setprio(1) around QK and PV MFMA clusters.
// FIXED-MAX softmax (scores O(5), exp safe in fp32).
// Writes UNNORMALIZED partials: Op bf16 [sp][rid][96], Lp fp32 [sp][rid].
__global__ __launch_bounds__(256) void attn_mfma(
        const bf16* __restrict__ QK, const bf16* __restrict__ V,
        const float* __restrict__ mask, const bf16* __restrict__ erkb,
        const bf16* __restrict__ ervb, bf16* __restrict__ Op,
        float* __restrict__ Lp, int layer) {
    __shared__ bf16 Ks[64][100];      // K chunk [s][d]
    __shared__ bf16 Vs[96][68];       // V chunk [d][s]
    __shared__ float rq[4][16][17];   // per-wave rel-K band: [m][dd]
    __shared__ bf16 pT[4][16][68];    // per-wave P: [m][s]
    __shared__ bf16 pdg[4][16][16];   // per-wave rel-V band: [m][dd], 9..15 zero
    // LDS total: 40960 B -> 4 blocks/CU exactly

    const int tid = threadIdx.x, wv = tid >> 6, lane = tid & 63;
    const int col = lane & 15, quad = lane >> 4;
    // XCD-bijective swizzle (1024 = 8 XCD x 128; id%8 = XCD round-robin)
    const int w = (blockIdx.x & 7) * 128 + (blockIdx.x >> 3);
    const int t0 = (w & 15) * 64;
    const int yz = w >> 4;
    const int h = yz & 1;
    const int z = yz >> 1;
    const int b = z >> 2, sp = z & 3;
    const int hd = h * DKn;
    const int t0w = t0 + wv * 16;

    // zero per-wave rel-V band (rows not hit by any chunk stay zero)
    *(uint2*)&pdg[wv][col][quad * 4] = (uint2){0, 0};

    // staging geometry (3 short8 per thread for K, 3 for V)
    int rK[3], cK[3], rV[3], cV[3];
#pragma unroll
    for (int i = 0; i < 3; ++i) {
        int s = tid + i * 256;
        rK[i] = s / 12; cK[i] = (s % 12) * 8;   // 64 rows x 96 cols
        rV[i] = s >> 3; cV[i] = (s & 7) * 8;    // 96 rows x 64 cols
    }
    const bf16* kbase = QK + (size_t)b * Tn * QKS + 192 + hd;
    const bf16* vbase = V + ((size_t)b * Cn + hd) * Tn;

    short8 kst[3], vst[3];
    const int sbeg = sp * (Tn / NSPLIT);
    const int send = sbeg + Tn / NSPLIT;

    // issue first chunk's loads immediately (latency hides under Q/rq prep)
#pragma unroll
    for (int i = 0; i < 3; ++i) {
        kst[i] = *(const short8*)(kbase + (size_t)(sbeg + rK[i]) * QKS + cK[i]);
        vst[i] = *(const short8*)(vbase + (size_t)rV[i] * Tn + sbeg + cV[i]);
    }

    // Q A-frags (persist): A[m=col][k=quad*8+j+32*kd]
    short8 aq[3];
    {
        const bf16* qrow = QK + ((size_t)b * Tn + t0w + col) * QKS + hd + quad * 8;
#pragma unroll
        for (int kd = 0; kd < 3; ++kd) aq[kd] = *(const short8*)(qrow + kd * 32);
    }
    // rel-K band via MFMA: R = Q . erk^T  (B rows 9..15 are zero)
    {
        const bf16* erow = erkb + ((size_t)layer * 16 + col) * 96 + quad * 8;
        f32x4 R = {};
#pragma unroll
        for (int kd = 0; kd < 3; ++kd) {
            short8 be = *(const short8*)(erow + kd * 32);
            R = __builtin_amdgcn_mfma_f32_16x16x32_bf16(aq[kd], be, R, 0, 0, 0);
        }
#pragma unroll
        for (int r = 0; r < 4; ++r) rq[wv][quad * 4 + r][col] = R[r];
    }
    float mtv[4];
#pragma unroll
    for (int r = 0; r < 4; ++r) mtv[r] = mask[b * Tn + t0w + quad * 4 + r];
    const bool qok = __all(mtv[0] != 0.f && mtv[1] != 0.f &&
                           mtv[2] != 0.f && mtv[3] != 0.f);
    // wave-uniform per-chunk "all mask nonzero" bits
    int okbits = 0;
    if (qok) {
#pragma unroll
        for (int ch = 0; ch < 4; ++ch) {
            int sc = b * Tn + sbeg + ch * 64 + col;
            float a0 = mask[sc], a1 = mask[sc + 16], a2 = mask[sc + 32], a3 = mask[sc + 48];
            if (__all(a0 != 0.f && a1 != 0.f && a2 != 0.f && a3 != 0.f))
                okbits |= 1 << ch;
        }
    }

    // first chunk into LDS
#pragma unroll
    for (int i = 0; i < 3; ++i) {
        *(short8*)&Ks[rK[i]][cK[i]] = kst[i];
        *(short8*)&Vs[rV[i]][cV[i]] = vst[i];
    }
    __syncthreads();

    f32x4 O[6] = {};
    f32x4 Osum = {};
    short8 ones;
#pragma unroll
    for (int j = 0; j < 8; ++j) ones[j] = (short)0x3F80;   // bf16 1.0

    for (int s0 = sbeg; s0 < send; s0 += 64) {
        const bool nxt = (s0 + 64 < send);
        // T14: issue NEXT chunk's global loads now; ds_write after barrier
        if (nxt) {
#pragma unroll
            for (int i = 0; i < 3; ++i) {
                kst[i] = *(const short8*)(kbase + (size_t)(s0 + 64 + rK[i]) * QKS + cK[i]);
                vst[i] = *(const short8*)(vbase + (size_t)rV[i] * Tn + s0 + 64 + cV[i]);
            }
        }

        // S = Q K^T (B-frags from LDS)
        f32x4 S[4] = {};
        __builtin_amdgcn_s_setprio(1);
#pragma unroll
        for (int nb = 0; nb < 4; ++nb)
#pragma unroll
            for (int kd = 0; kd < 3; ++kd) {
                short8 bkf = *(const short8*)&Ks[16 * nb + col][kd * 32 + quad * 8];
                S[nb] = __builtin_amdgcn_mfma_f32_16x16x32_bf16(aq[kd], bkf, S[nb], 0, 0, 0);
            }
        __builtin_amdgcn_s_setprio(0);

        const bool diag = (s0 <= t0w + 15 + WINn) && (s0 + 63 >= t0w - WINn);
        if (diag) {   // rel-K band add (only diagonal chunks have hits)
#pragma unroll
            for (int nb = 0; nb < 4; ++nb) {
                const int sg = s0 + 16 * nb + col;
#pragma unroll
                for (int r = 0; r < 4; ++r) {
                    int dd = sg - (t0w + quad * 4 + r) + WINn;
                    if ((unsigned)dd <= 2u * WINn) S[nb][r] += rq[wv][quad * 4 + r][dd];
                }
            }
        }
        if (!((okbits >> ((s0 - sbeg) >> 6)) & 1)) {   // rare path: masked elems
#pragma unroll
            for (int nb = 0; nb < 4; ++nb) {
                const float msv = mask[b * Tn + s0 + 16 * nb + col];
#pragma unroll
                for (int r = 0; r < 4; ++r)
                    if (msv * mtv[r] == 0.f) S[nb][r] = -1e4f;
            }
        }

        // P = exp(S) -> pT (pdg band capture only on diagonal chunks)
        if (diag) {
#pragma unroll
            for (int nb = 0; nb < 4; ++nb) {
                const int sg = s0 + 16 * nb + col;
#pragma unroll
                for (int r = 0; r < 4; ++r) {
                    bf16 pb_ = __float2bfloat16(__expf(S[nb][r]));
                    pT[wv][quad * 4 + r][16 * nb + col] = pb_;
                    int dd = sg - (t0w + quad * 4 + r) + WINn;
                    if ((unsigned)dd <= 2u * WINn) pdg[wv][quad * 4 + r][dd] = pb_;
                }
            }
        } else {
#pragma unroll
            for (int nb = 0; nb < 4; ++nb)
#pragma unroll
                for (int r = 0; r < 4; ++r)
                    pT[wv][quad * 4 + r][16 * nb + col] =
                        __float2bfloat16(__expf(S[nb][r]));
        }

        // P A-frags from per-wave LDS; PV + ones-rowsum MFMAs
        short8 aP[2];
#pragma unroll
        for (int kk = 0; kk < 2; ++kk)
            aP[kk] = *(const short8*)&pT[wv][col][kk * 32 + quad * 8];
        __builtin_amdgcn_s_setprio(1);
#pragma unroll
        for (int nd = 0; nd < 6; ++nd)
#pragma unroll
            for (int kk = 0; kk < 2; ++kk) {
                short8 bvf = *(const short8*)&Vs[16 * nd + col][kk * 32 + quad * 8];
                O[nd] = __builtin_amdgcn_mfma_f32_16x16x32_bf16(aP[kk], bvf, O[nd], 0, 0, 0);
            }
#pragma unroll
        for (int kk = 0; kk < 2; ++kk)
            Osum = __builtin_amdgcn_mfma_f32_16x16x32_bf16(aP[kk], ones, Osum, 0, 0, 0);
        __builtin_amdgcn_s_setprio(0);

        __syncthreads();   // all waves done reading Ks/Vs
        if (nxt) {
#pragma unroll
            for (int i = 0; i < 3; ++i) {
                *(short8*)&Ks[rK[i]][cK[i]] = kst[i];
                *(short8*)&Vs[rV[i]][cV[i]] = vst[i];
            }
            __syncthreads();
        }
    }

    // rel-V band contribution: O += pdg(16x16, k 9..15 zero) . ERVB(k x 96)
    {
        short8 ad = {0, 0, 0, 0, 0, 0, 0, 0};
        if (quad < 2) ad = *(const short8*)&pdg[wv][col][quad * 8];
        const bf16* eb = ervb + (size_t)layer * 96 * 32 + (size_t)col * 32 + quad * 8;
#pragma unroll
        for (int nd = 0; nd < 6; ++nd) {
            short8 bd = *(const short8*)(eb + (size_t)nd * 16 * 32);
            O[nd] = __builtin_amdgcn_mfma_f32_16x16x32_bf16(ad, bd, O[nd], 0, 0, 0);
        }
    }

    // epilogue: write unnormalized partials (Lp row-sums come from Osum)
    const int rbase = (b * Hn + h) * Tn + t0w;
#pragma unroll
    for (int r = 0; r < 4; ++r) {
        const int rid = rbase + quad * 4 + r;
        bf16* dst = Op + ((size_t)sp * RN + rid) * 96 + col;
#pragma unroll
        for (int nd = 0; nd < 6; ++nd)
            dst[16 * nd] = __float2bfloat16(O[nd][r]);
        if (col == 0) Lp[sp * RN + rid] = Osum[r];
    }
}

// ---------------------------------------------------------------------------
// Residual add + LayerNorm over channels. X <- LN(X+Y)*g+b (fp32) and
// XT <- bf16 transposed [b][t][C], optionally *mask.
__global__ __launch_bounds__(256) void ln_k(
        float* __restrict__ X, const float* __restrict__ Y,
        const float* __restrict__ G, const float* __restrict__ Bt,
        const float* __restrict__ mask, bf16* __restrict__ XT, int apply_mask) {
    __shared__ float tile[Cn][33];
    __shared__ float r1[8][32];
    __shared__ float r2[8][32];
    const int tid = threadIdx.x;
    const int lane = tid & 31, w = tid >> 5;
    const int b = blockIdx.x >> 5;
    const int t0 = (blockIdx.x & 31) * 32;
    const int t = t0 + lane;

    float s1 = 0.f, s2 = 0.f;
    for (int c = w; c < Cn; c += 8) {
        float v = X[((b * Cn + c) * Tn) + t] + Y[((b * Cn + c) * Tn) + t];
        tile[c][lane] = v;
        s1 += v;
        s2 += v * v;
    }
    r1[w][lane] = s1;
    r2[w][lane] = s2;
    __syncthreads();
    if (w == 0) {
        float a = 0.f, q = 0.f;
        for (int i = 0; i < 8; ++i) { a += r1[i][lane]; q += r2[i][lane]; }
        float m = a / Cn;
        float var = q / Cn - m * m;
        r1[0][lane] = m;
        r2[0][lane] = rsqrtf(var + 1e-5f);
    }
    __syncthreads();
    const float m = r1[0][lane], rs = r2[0][lane];
    for (int c = w; c < Cn; c += 8) {
        float y = (tile[c][lane] - m) * rs * G[c] + Bt[c];
        X[((b * Cn + c) * Tn) + t] = y;
        tile[c][lane] = y;
    }
    __syncthreads();
    for (int idx = tid; idx < 32 * Cn; idx += 256) {
        int tl = idx / Cn, c = idx % Cn;
        float v = tile[c][tl];
        if (apply_mask) v *= mask[b * Tn + t0 + tl];
        XT[((size_t)b * Tn + t0 + tl) * Cn + c] = __float2bfloat16(v);
    }
}

// FFN2-combine + residual + LN2: Y = (P0+P1+bias)*mask; Xn = LN(X+Y)*g+b.
// OUT==null: X <- Xn, XT <- bf16(Xn).  OUT!=null (last layer): OUT <- Xn*mask.
__global__ __launch_bounds__(256) void ln_ffn2(
        float* __restrict__ X, const float* __restrict__ P0,
        const float* __restrict__ P1, const float* __restrict__ bias,
        const float* __restrict__ G, const float* __restrict__ Bt,
        const float* __restrict__ mask, bf16* __restrict__ XT,
        float* __restrict__ OUT) {
    __shared__ float tile[Cn][33];
    __shared__ float r1[8][32];
    __shared__ float r2[8][32];
    const int tid = threadIdx.x;
    const int lane = tid & 31, w = tid >> 5;
    const int b = blockIdx.x >> 5;
    const int t0 = (blockIdx.x & 31) * 32;
    const int t = t0 + lane;
    const float mk = mask[b * Tn + t];

    float s1 = 0.f, s2 = 0.f;
    for (int c = w; c < Cn; c += 8) {
        size_t i = ((size_t)b * Cn + c) * Tn + t;
        float y = (P0[i] + P1[i] + bias[c]) * mk;
        float v = X[i] + y;
        tile[c][lane] = v;
        s1 += v;
        s2 += v * v;
    }
    r1[w][lane] = s1;
    r2[w][lane] = s2;
    __syncthreads();
    if (w == 0) {
        float a = 0.f, q = 0.f;
        for (int i = 0; i < 8; ++i) { a += r1[i][lane]; q += r2[i][lane]; }
        float m = a / Cn;
        float var = q / Cn - m * m;
        r1[0][lane] = m;
        r2[0][lane] = rsqrtf(var + 1e-5f);
    }
    __syncthreads();
    const float m = r1[0][lane], rs = r2[0][lane];
    if (OUT) {   // final layer: write output = LN(...)*mask directly, done
        for (int c = w; c < Cn; c += 8) {
            float y = (tile[c][lane] - m) * rs * G[c] + Bt[c];
            OUT[((b * Cn + c) * Tn) + t] = y * mk;
        }
        return;
    }
    for (int c = w; c < Cn; c += 8) {
        float y = (tile[c][lane] - m) * rs * G[c] + Bt[c];
        X[((b * Cn + c) * Tn) + t] = y;
        tile[c][lane] = y;
    }
    __syncthreads();
    for (int idx = tid; idx < 32 * Cn; idx += 256) {
        int tl = idx / Cn, c = idx % Cn;
        XT[((size_t)b * Tn + t0 + tl) * Cn + c] = __float2bfloat16(tile[c][tl]);
    }
}

// ---------------------------------------------------------------------------
extern "C" void kernel_launch(void* const* d_in, const int* in_sizes, int n_in,
                              void* d_out, int out_size, void* d_ws, size_t ws_size,
                              hipStream_t stream) {
    const float* x    = (const float*)d_in[0];
    const float* mask = (const float*)d_in[1];
    const float* Wq   = (const float*)d_in[2];
    const float* bq   = (const float*)d_in[3];
    const float* Wk   = (const float*)d_in[4];
    const float* bk   = (const float*)d_in[5];
    const float* Wv   = (const float*)d_in[6];
    const float* bv   = (const float*)d_in[7];
    const float* Wo   = (const float*)d_in[8];
    const float* bo   = (const float*)d_in[9];
    const float* erk  = (const float*)d_in[10];
    const float* erv  = (const float*)d_in[11];
    const float* ln1g = (const float*)d_in[12];
    const float* ln1b = (const float*)d_in[13];
    const float* w1   = (const float*)d_in[14];
    const float* b1   = (const float*)d_in[15];
    const float* w2   = (const float*)d_in[16];
    const float* b2   = (const float*)d_in[17];
    const float* ln2g = (const float*)d_in[18];
    const float* ln2b = (const float*)d_in[19];

    const size_t N = (size_t)Bn * Cn * Tn;         // 1,572,864
    const int WC = Ln * Cn * Cn;                   // 221,184
    const size_t WF = (size_t)Ln * 3 * FCn * Cn;   // 2,654,208
    const size_t WQKV = (size_t)Ln * 576 * Cn;     // 663,552
    const size_t NSCR = (size_t)Bn * Tn * FCn;     // 6,291,456 == NSPLIT*RN*96

    float* X    = (float*)d_ws;
    float* Yb   = X + N;                           // conv_o out / FFN2 partial 0
    float* bqkv = Yb + N;                          // L*576 floats
    float* Lp   = bqkv + Ln * 576;                 // NSPLIT*RN floats
    bf16* p16 = (bf16*)(Lp + (size_t)NSPLIT * RN);
    bf16* XT   = p16; p16 += N;
    bf16* QKT  = p16; p16 += (size_t)Bn * Tn * QKS;  // 2N bf16; dead after attn
    bf16* Vb   = p16; p16 += N;
    bf16* AT   = p16; p16 += N;      // (unused since R5; kept for layout)
    bf16* SCR  = p16; p16 += NSCR;   // shared: attn O-partials <-> FFN hidden
    bf16* Wqkv = p16; p16 += WQKV;
    bf16* Wob  = p16; p16 += WC;
    bf16* W1t  = p16; p16 += WF;
    bf16* W2t  = p16; p16 += WF;
    bf16* ERKB = p16; p16 += Ln * 16 * 96;
    bf16* ERVB = p16; p16 += Ln * 96 * 32;
    float* P1  = (float*)QKT;        // FFN2 partial 1 aliases dead QKT (N fp32)
    (void)AT;

    const float qscale = 0.10206207261596575f;  // 1/sqrt(96)

    // one-time transforms
    qkv_prep<<<(int)((WQKV + Ln * 576 + 255) / 256), 256, 0, stream>>>(
        Wq, Wk, Wv, bq, bk, bv, Wqkv, bqkv, qscale);
    cast_bf<<<(WC + 255) / 256, 256, 0, stream>>>(Wo, Wob, WC);
    reorder_w<<<(int)((WF + 255) / 256), 256, 0, stream>>>(w1, W1t, FCn, Cn);
    reorder_w<<<(int)((WF + 255) / 256), 256, 0, stream>>>(w2, W2t, Cn, FCn);
    erk_prep<<<(Ln * 16 * 96 + 255) / 256, 256, 0, stream>>>(erk, ERKB);
    erv_prep<<<(Ln * 96 * 32 + 255) / 256, 256, 0, stream>>>(erv, ERVB);
    cvt_in_k<<<Bn * 32, 256, 0, stream>>>(x, mask, X, XT);

    for (int l = 0; l < Ln; ++l) {
        conv_mfma<1, 128, 4, 1><<<dim3(Tn / 128, 9, Bn), 256, 0, stream>>>(
            XT, Wqkv + (size_t)l * 576 * Cn, bqkv + l * 576, nullptr, QKT, Vb, Cn, 576);
        attn_mfma<<<dim3(Tn / 64 * Hn * Bn * NSPLIT), 256, 0, stream>>>(
            QKT, Vb, mask, ERKB, ERVB, SCR, Lp, l);
        // Wo conv with fused attn split-combine (MODE 6): Xt=Op, mask=Lp
        conv_mfma<1, 64, 6, 1><<<dim3(Tn / 64, 3, Bn), 256, 0, stream>>>(
            SCR, Wob + (size_t)l * Cn * Cn, bo + l * Cn, Lp, Yb, nullptr, Cn, Cn);
        ln_k<<<Bn * 32, 256, 0, stream>>>(X, Yb, ln1g + l * Cn, ln1b + l * Cn, mask, XT, 1);
        conv_mfma<3, 128, 2, 1><<<dim3(Tn / 128, FCn / 64, Bn), 256, 0, stream>>>(
            XT, W1t + (size_t)l * 3 * FCn * Cn, b1 + l * FCn, mask, SCR, nullptr, Cn, FCn);
        conv_mfma<3, 128, 5, 2><<<dim3(Tn / 128, 3, Bn * 2), 256, 0, stream>>>(
            SCR, W2t + (size_t)l * 3 * Cn * FCn, b2 + l * Cn, mask, Yb, P1, FCn, Cn);
        ln_ffn2<<<Bn * 32, 256, 0, stream>>>(X, Yb, P1, b2 + l * Cn,
                                             ln2g + l * Cn, ln2b + l * Cn, mask, XT,
                                             (l == Ln - 1) ? (float*)d_out : nullptr);
    }
}

// Round 6
// 698.384 us; speedup vs baseline: 1.6537x; 1.1484x over previous
//
#include <hip/hip_runtime.h>
#include <hip/hip_bf16.h>

// Problem constants
constexpr int Bn  = 8;
constexpr int Cn  = 192;   // hidden channels
constexpr int Tn  = 1024;  // sequence length
constexpr int Hn  = 2;     // heads
constexpr int DKn = 96;    // head dim
constexpr int FCn = 768;   // filter channels
constexpr int Ln  = 6;     // layers
constexpr int WINn = 4;    // rel-attn window
constexpr int QKS = 384;   // QK transposed row stride (Q|K concat)
constexpr int NSPLIT = 4;  // attention s-split (flash-decoding)
constexpr int RN  = Bn * Hn * Tn;  // 16384 attention rows

typedef __hip_bfloat16 bf16;
typedef __attribute__((ext_vector_type(8))) short short8;
typedef __attribute__((ext_vector_type(4))) float f32x4;

// ---------------------------------------------------------------------------
// R6: ALL one-time weight transforms in a single grid-stride kernel
// (was 5 separate dispatches; saves launch ramps).
__global__ void prep_all(
        const float* __restrict__ Wq, const float* __restrict__ Wk,
        const float* __restrict__ Wv, const float* __restrict__ bq,
        const float* __restrict__ bk, const float* __restrict__ bv,
        const float* __restrict__ Wo, const float* __restrict__ w1,
        const float* __restrict__ w2, const float* __restrict__ erk,
        const float* __restrict__ erv,
        bf16* __restrict__ Wqkv, float* __restrict__ bqkv,
        bf16* __restrict__ Wob, bf16* __restrict__ W1t, bf16* __restrict__ W2t,
        bf16* __restrict__ ERKB, bf16* __restrict__ ERVB, float qscale) {
    size_t i = (size_t)blockIdx.x * 256 + threadIdx.x;
    const size_t nW  = (size_t)Ln * 576 * Cn;     // 663,552
    const size_t nB  = (size_t)Ln * 576;
    const size_t WCn = (size_t)Ln * Cn * Cn;      // 221,184
    const size_t WFn = (size_t)Ln * 3 * FCn * Cn; // 2,654,208
    if (i < nW) {        // fused QKV weight (qscale folded into Q)
        int c = i % Cn, f = (i / Cn) % 576, l = i / (Cn * 576);
        float v;
        if (f < 192)      v = Wq[((size_t)l * Cn + f) * Cn + c] * qscale;
        else if (f < 384) v = Wk[((size_t)l * Cn + f - 192) * Cn + c];
        else              v = Wv[((size_t)l * Cn + f - 384) * Cn + c];
        Wqkv[i] = __float2bfloat16(v);
        return;
    }
    i -= nW;
    if (i < nB) {        // fused QKV bias
        int f = i % 576, l = i / 576;
        float v;
        if (f < 192)      v = bq[l * Cn + f] * qscale;
        else if (f < 384) v = bk[l * Cn + f - 192];
        else              v = bv[l * Cn + f - 384];
        bqkv[i] = v;
        return;
    }
    i -= nB;
    if (i < WCn) {       // Wo cast
        Wob[i] = __float2bfloat16(Wo[i]);
        return;
    }
    i -= WCn;
    if (i < WFn) {       // w1 [L][FC][C][3] -> [L][3][FC][C]
        int c = i % Cn;
        int f = (i / Cn) % FCn;
        int ko = (i / (Cn * FCn)) % 3;
        int l = i / (3 * Cn * FCn);
        W1t[i] = __float2bfloat16(w1[(((size_t)(l * FCn + f)) * Cn + c) * 3 + ko]);
        return;
    }
    i -= WFn;
    if (i < WFn) {       // w2 [L][C][FC][3] -> [L][3][C][FC]
        int c = i % FCn;
        int f = (i / FCn) % Cn;
        int ko = (i / (FCn * Cn)) % 3;
        int l = i / (3 * FCn * Cn);
        W2t[i] = __float2bfloat16(w2[(((size_t)(l * Cn + f)) * FCn + c) * 3 + ko]);
        return;
    }
    i -= WFn;
    if (i < (size_t)Ln * 16 * 96) {   // erk -> [L][16][96], rows 9..15 zero
        int d = i % 96, row = (i / 96) % 16, l = i / (96 * 16);
        float v = (row < 9) ? erk[((size_t)l * 9 + row) * 96 + d] : 0.f;
        ERKB[i] = __float2bfloat16(v);
        return;
    }
    i -= (size_t)Ln * 16 * 96;
    if (i < (size_t)Ln * 96 * 32) {   // erv -> [L][96][32] transposed, k 9..31 zero
        int k = i & 31, d = (i >> 5) % 96, l = i / (96 * 32);
        float v = (k < 9) ? erv[((size_t)l * 9 + k) * 96 + d] : 0.f;
        ERVB[i] = __float2bfloat16(v);
    }
}

// ---------------------------------------------------------------------------
// Input: X = x*mask (fp32, NCT) + XT = bf16 transposed [b][t][c]
__global__ __launch_bounds__(256) void cvt_in_k(
        const float* __restrict__ x, const float* __restrict__ mask,
        float* __restrict__ X, bf16* __restrict__ XT) {
    __shared__ float tile[Cn][33];
    const int tid = threadIdx.x, lane = tid & 31, w = tid >> 5;
    const int b = blockIdx.x >> 5;
    const int t0 = (blockIdx.x & 31) * 32;
    const float mk = mask[b * Tn + t0 + lane];
    for (int c = w; c < Cn; c += 8) {
        float v = x[((b * Cn + c) * Tn) + t0 + lane] * mk;
        X[((b * Cn + c) * Tn) + t0 + lane] = v;
        tile[c][lane] = v;
    }
    __syncthreads();
    for (int idx = tid; idx < 32 * Cn; idx += 256) {
        int tl = idx / Cn, c = idx % Cn;
        XT[((size_t)b * Tn + t0 + tl) * Cn + c] = __float2bfloat16(tile[c][tl]);
    }
}

// ---------------------------------------------------------------------------
// MFMA conv1d, LDS-staged, TT=128 for K-heavy convs, T14 async-STAGE (R4).
// MODE 0: fp32 NCT out (+bias, *mask if mask!=null)
// MODE 2: bf16 transposed [b][t][CO] out relu(+bias)*mask   [FFN1]
// MODE 4: QKV split: f<384 -> bf16 T (stride QKS) into Y0; else bf16 NCT Y1
// MODE 5: fp32 NCT K-split partial, NO bias: ks==0 -> Y0, ks==1 -> Y1 [FFN2]
template <int KS, int TT, int MODE, int NSP>
__global__ __launch_bounds__(256) void conv_mfma(
        const bf16* __restrict__ Xt, const bf16* __restrict__ W,
        const float* __restrict__ bias, const float* __restrict__ mask,
        void* __restrict__ Y0, void* __restrict__ Y1, int CIN, int CO) {
    constexpr int PAD = KS / 2;
    constexpr int NMB = TT / 16;
    constexpr int AR  = TT + KS - 1;        // A rows staged
    constexpr int RS  = 72;                 // padded row stride (bf16 cols)
    constexpr int NA  = (AR * 8 + 255) / 256;  // per-thread A short8 loads
    constexpr int NB  = KS * 2;                // per-thread B short8 loads
    __shared__ bf16 As[AR][RS];
    __shared__ bf16 Bs[KS][64][RS];

    const int tid = threadIdx.x;
    const int wv = tid >> 6, lane = tid & 63;
    const int m = lane & 15, kq = lane >> 4;
    const int b = blockIdx.z / NSP, ks = blockIdx.z % NSP;
    const int t0 = blockIdx.x * TT;
    const int f0 = blockIdx.y * 64;
    const int f = f0 + wv * 16 + m;

    const bf16* xb = Xt + (size_t)b * Tn * CIN;
    const size_t wko = (size_t)CO * CIN;

    // per-thread staging coordinates (fixed across chunks)
    int rA[NA], cA[NA];
    bool vA[NA];
#pragma unroll
    for (int i = 0; i < NA; ++i) {
        int s = tid + i * 256;
        rA[i] = s >> 3; cA[i] = (s & 7) * 8; vA[i] = (s < AR * 8);
    }
    int rB[NB], cB[NB], koB[NB];
#pragma unroll
    for (int i = 0; i < NB; ++i) {
        int s = tid + i * 256;          // always < KS*512
        koB[i] = s >> 9; rB[i] = (s >> 3) & 63; cB[i] = (s & 7) * 8;
    }

    short8 pa[NA], pb[NB];
    const int cbeg = ks * (CIN / NSP);
    const int cend = cbeg + CIN / NSP;

    // issue + commit helpers (T14 split)
    auto issue = [&](int c0) {
#pragma unroll
        for (int i = 0; i < NA; ++i) {
            short8 v = {0, 0, 0, 0, 0, 0, 0, 0};
            if (vA[i]) {
                int gt = t0 + rA[i] - PAD;
                if (PAD == 0 || (unsigned)gt < (unsigned)Tn)
                    v = *(const short8*)(xb + (size_t)gt * CIN + c0 + cA[i]);
            }
            pa[i] = v;
        }
#pragma unroll
        for (int i = 0; i < NB; ++i)
            pb[i] = *(const short8*)(W + (size_t)koB[i] * wko +
                                     (size_t)(f0 + rB[i]) * CIN + c0 + cB[i]);
    };
    auto commit = [&]() {
#pragma unroll
        for (int i = 0; i < NA; ++i)
            if (vA[i]) *(short8*)&As[rA[i]][cA[i]] = pa[i];
#pragma unroll
        for (int i = 0; i < NB; ++i)
            *(short8*)&Bs[koB[i]][rB[i]][cB[i]] = pb[i];
    };

    f32x4 acc[NMB] = {};

    issue(cbeg);
    commit();
    __syncthreads();

    for (int c0 = cbeg; c0 < cend; c0 += 64) {
        const bool nxt = (c0 + 64 < cend);
        if (nxt) issue(c0 + 64);
#pragma unroll
        for (int kk = 0; kk < 2; ++kk)
#pragma unroll
            for (int ko = 0; ko < KS; ++ko) {
                short8 bfr = *(const short8*)&Bs[ko][wv * 16 + m][kk * 32 + kq * 8];
#pragma unroll
                for (int mb = 0; mb < NMB; ++mb) {
                    short8 afr = *(const short8*)&As[mb * 16 + m + ko][kk * 32 + kq * 8];
                    acc[mb] = __builtin_amdgcn_mfma_f32_16x16x32_bf16(afr, bfr, acc[mb], 0, 0, 0);
                }
            }
        if (nxt) {
            __syncthreads();   // all fragment reads of this chunk complete
            commit();
            __syncthreads();   // staged data visible
        }
    }

    if (MODE == 5) {
        float* Y = (float*)(ks ? Y1 : Y0) + ((size_t)b * CO + f) * Tn;
#pragma unroll
        for (int mb = 0; mb < NMB; ++mb) {
            int t = t0 + mb * 16 + kq * 4;
            float4 o;
            o.x = acc[mb][0]; o.y = acc[mb][1]; o.z = acc[mb][2]; o.w = acc[mb][3];
            *(float4*)(Y + t) = o;
        }
        return;
    }
    const float bs = bias[f];
    if (MODE == 0) {
        float* Y = (float*)Y0 + ((size_t)b * CO + f) * Tn;
#pragma unroll
        for (int mb = 0; mb < NMB; ++mb) {
            int t = t0 + mb * 16 + kq * 4;
            float4 o;
            o.x = acc[mb][0] + bs; o.y = acc[mb][1] + bs;
            o.z = acc[mb][2] + bs; o.w = acc[mb][3] + bs;
            if (mask) {
                o.x *= mask[b * Tn + t];     o.y *= mask[b * Tn + t + 1];
                o.z *= mask[b * Tn + t + 2]; o.w *= mask[b * Tn + t + 3];
            }
            *(float4*)(Y + t) = o;
        }
    } else if (MODE == 2) {
        bf16* Y = (bf16*)Y0;
#pragma unroll
        for (int mb = 0; mb < NMB; ++mb)
#pragma unroll
            for (int r = 0; r < 4; ++r) {
                int t = t0 + mb * 16 + kq * 4 + r;
                float v = fmaxf(acc[mb][r] + bs, 0.f) * mask[b * Tn + t];
                Y[((size_t)b * Tn + t) * CO + f] = __float2bfloat16(v);
            }
    } else {  // MODE 4
        if (blockIdx.y < 6) {          // Q|K -> transposed, stride QKS
            bf16* Y = (bf16*)Y0;
#pragma unroll
            for (int mb = 0; mb < NMB; ++mb)
#pragma unroll
                for (int r = 0; r < 4; ++r) {
                    int t = t0 + mb * 16 + kq * 4 + r;
                    Y[((size_t)b * Tn + t) * QKS + f] = __float2bfloat16(acc[mb][r] + bs);
                }
        } else {                        // V -> bf16 NCT
            bf16* Y = (bf16*)Y1 + ((size_t)b * Cn + f - 384) * Tn;
#pragma unroll
            for (int mb = 0; mb < NMB; ++mb) {
                int t = t0 + mb * 16 + kq * 4;
                bf16 tmp[4];
#pragma unroll
                for (int r = 0; r < 4; ++r) tmp[r] = __float2bfloat16(acc[mb][r] + bs);
                *(uint2*)(Y + t) = *(uint2*)tmp;
            }
        }
    }
}

// ---------------------------------------------------------------------------
// R6: fully fused Wo stage: attn split-combine + Wo conv + bias + residual
// + channel-LayerNorm + X/XT write. One block owns a full [32 t x 192 c]
// output tile (all channels -> LN is block-local). Replaces the MODE-6 Wo
// conv AND ln_k (kills 6 dispatches + the 6 MB fp32 Yb round-trip per layer).
// Grid 256 blocks, XCD-affine: b = blockIdx&7 (each XCD's b-panel of Op
// ~1.6 MB -> L2-resident).
__global__ __launch_bounds__(256) void wo_ln_k(
        const bf16* __restrict__ Op, const float* __restrict__ Lp,
        const bf16* __restrict__ W, const float* __restrict__ bias,
        float* __restrict__ X, const float* __restrict__ G,
        const float* __restrict__ Bt, const float* __restrict__ mask,
        bf16* __restrict__ XT) {
    __shared__ bf16 As[32][72];       // combined attn out [t][c-chunk]
    __shared__ bf16 Bs[192][72];      // Wo panel [f][c-chunk]
    __shared__ float sm1[4][32];
    __shared__ float sm2[4][32];

    const int tid = threadIdx.x;
    const int wv = tid >> 6, lane = tid & 63;
    const int m = lane & 15, quad = lane >> 4;
    const int b = blockIdx.x & 7;
    const int t0 = (blockIdx.x >> 3) * 32;

    const int rA = tid >> 3, cA = (tid & 7) * 8;   // A: 32 rows x 8 short8
    short8 pa6[4]; float pl6[4];
    short8 pb[6];                                   // B: 192 rows x 8 short8

    auto issue = [&](int c0) {
        int c = c0 + cA;
        int hh = (c >= 96) ? 1 : 0;
        int rid = (b * Hn + hh) * Tn + t0 + rA;
        int d0 = c - 96 * hh;
#pragma unroll
        for (int sp = 0; sp < 4; ++sp) {
            pa6[sp] = *(const short8*)(Op + ((size_t)sp * RN + rid) * 96 + d0);
            pl6[sp] = Lp[sp * RN + rid];
        }
#pragma unroll
        for (int i = 0; i < 6; ++i) {
            int s = tid + i * 256;
            pb[i] = *(const short8*)(W + (size_t)(s >> 3) * Cn + c0 + (s & 7) * 8);
        }
    };
    auto commit = [&]() {
        float denom = pl6[0] + pl6[1] + pl6[2] + pl6[3];
        float inv = 1.f / fmaxf(denom, 1e-30f);
        bf16 tmp[8];
#pragma unroll
        for (int e = 0; e < 8; ++e) {
            float o = 0.f;
#pragma unroll
            for (int sp = 0; sp < 4; ++sp)
                o += __bfloat162float(((const bf16*)&pa6[sp])[e]);
            tmp[e] = __float2bfloat16(o * inv);
        }
        *(short8*)&As[rA][cA] = *(const short8*)tmp;
#pragma unroll
        for (int i = 0; i < 6; ++i) {
            int s = tid + i * 256;
            *(short8*)&Bs[s >> 3][(s & 7) * 8] = pb[i];
        }
    };

    f32x4 acc[3][2] = {};

    issue(0);
    commit();
    __syncthreads();
    for (int c0 = 0; c0 < Cn; c0 += 64) {
        const bool nxt = (c0 + 64 < Cn);
        if (nxt) issue(c0 + 64);
#pragma unroll
        for (int kk = 0; kk < 2; ++kk)
#pragma unroll
            for (int fb = 0; fb < 3; ++fb) {
                short8 bfr = *(const short8*)&Bs[fb * 64 + wv * 16 + m][kk * 32 + quad * 8];
#pragma unroll
                for (int mb = 0; mb < 2; ++mb) {
                    short8 afr = *(const short8*)&As[mb * 16 + m][kk * 32 + quad * 8];
                    acc[fb][mb] = __builtin_amdgcn_mfma_f32_16x16x32_bf16(afr, bfr, acc[fb][mb], 0, 0, 0);
                }
            }
        if (nxt) {
            __syncthreads();
            commit();
            __syncthreads();
        }
    }

    // bias + residual; accumulate per-t LN stats over this lane's channels
    float s1[2][4] = {{0.f, 0.f, 0.f, 0.f}, {0.f, 0.f, 0.f, 0.f}};
    float s2[2][4] = {{0.f, 0.f, 0.f, 0.f}, {0.f, 0.f, 0.f, 0.f}};
#pragma unroll
    for (int fb = 0; fb < 3; ++fb) {
        const int f = fb * 64 + wv * 16 + m;
        const float bsv = bias[f];
#pragma unroll
        for (int mb = 0; mb < 2; ++mb) {
            const int t = t0 + mb * 16 + quad * 4;
            float4 xv = *(const float4*)(X + ((size_t)(b * Cn + f)) * Tn + t);
            acc[fb][mb][0] += bsv + xv.x;
            acc[fb][mb][1] += bsv + xv.y;
            acc[fb][mb][2] += bsv + xv.z;
            acc[fb][mb][3] += bsv + xv.w;
#pragma unroll
            for (int r = 0; r < 4; ++r) {
                float v = acc[fb][mb][r];
                s1[mb][r] += v;
                s2[mb][r] += v * v;
            }
        }
    }
    // reduce over the 16 m-lanes (same t within each quad group)
#pragma unroll
    for (int mb = 0; mb < 2; ++mb)
#pragma unroll
        for (int r = 0; r < 4; ++r)
#pragma unroll
            for (int mk = 1; mk < 16; mk <<= 1) {
                s1[mb][r] += __shfl_xor(s1[mb][r], mk);
                s2[mb][r] += __shfl_xor(s2[mb][r], mk);
            }
    if (m == 0) {
#pragma unroll
        for (int mb = 0; mb < 2; ++mb)
#pragma unroll
            for (int r = 0; r < 4; ++r) {
                sm1[wv][mb * 16 + quad * 4 + r] = s1[mb][r];
                sm2[wv][mb * 16 + quad * 4 + r] = s2[mb][r];
            }
    }
    __syncthreads();
    float mean[2][4], rs[2][4], mtv[2][4];
#pragma unroll
    for (int mb = 0; mb < 2; ++mb) {
        float4 mk4 = *(const float4*)(mask + b * Tn + t0 + mb * 16 + quad * 4);
        mtv[mb][0] = mk4.x; mtv[mb][1] = mk4.y;
        mtv[mb][2] = mk4.z; mtv[mb][3] = mk4.w;
#pragma unroll
        for (int r = 0; r < 4; ++r) {
            int tt = mb * 16 + quad * 4 + r;
            float a = sm1[0][tt] + sm1[1][tt] + sm1[2][tt] + sm1[3][tt];
            float q = sm2[0][tt] + sm2[1][tt] + sm2[2][tt] + sm2[3][tt];
            float mn = a / Cn;
            mean[mb][r] = mn;
            rs[mb][r] = rsqrtf(q / Cn - mn * mn + 1e-5f);
        }
    }
    // normalize + write X (fp32 NCT) and XT (bf16 T, masked)
#pragma unroll
    for (int fb = 0; fb < 3; ++fb) {
        const int f = fb * 64 + wv * 16 + m;
        const float gv = G[f], bv = Bt[f];
#pragma unroll
        for (int mb = 0; mb < 2; ++mb) {
            const int t = t0 + mb * 16 + quad * 4;
            float y[4];
#pragma unroll
            for (int r = 0; r < 4; ++r)
                y[r] = (acc[fb][mb][r] - mean[mb][r]) * rs[mb][r] * gv + bv;
            float4 xo;
            xo.x = y[0]; xo.y = y[1]; xo.z = y[2]; xo.w = y[3];
            *(float4*)(X + ((size_t)(b * Cn + f)) * Tn + t) = xo;
#pragma unroll
            for (int r = 0; r < 4; ++r)
                XT[((size_t)b * Tn + t + r) * Cn + f] =
                    __float2bfloat16(y[r] * mtv[mb][r]);
        }
    }
}

// ---------------------------------------------------------------------------
// MFMA flash attention, split-K over s, LDS-staged K/V, XCD swizzle (R2),
// T14 async-STAGE split (R2), rel-V via MFMA (R3), VALU cuts + setprio (R5).
// FIXED-MAX softmax (scores O(5), exp safe in fp32).
// Writes UNNORMALIZED partials: Op bf16 [sp][rid][96], Lp fp32 [sp][rid].
__global__ __launch_bounds__(256) void attn_mfma(
        const bf16* __restrict__ QK, const bf16* __restrict__ V,
        const float* __restrict__ mask, const bf16* __restrict__ erkb,
        const bf16* __restrict__ ervb, bf16* __restrict__ Op,
        float* __restrict__ Lp, int layer) {
    __shared__ bf16 Ks[64][100];      // K chunk [s][d]
    __shared__ bf16 Vs[96][68];       // V chunk [d][s]
    __shared__ float rq[4][16][17];   // per-wave rel-K band: [m][dd]
    __shared__ bf16 pT[4][16][68];    // per-wave P: [m][s]
    __shared__ bf16 pdg[4][16][16];   // per-wave rel-V band: [m][dd], 9..15 zero

    const int tid = threadIdx.x, wv = tid >> 6, lane = tid & 63;
    const int col = lane & 15, quad = lane >> 4;
    // XCD-bijective swizzle (1024 = 8 XCD x 128; id%8 = XCD round-robin)
    const int w = (blockIdx.x & 7) * 128 + (blockIdx.x >> 3);
    const int t0 = (w & 15) * 64;
    const int yz = w >> 4;
    const int h = yz & 1;
    const int z = yz >> 1;
    const int b = z >> 2, sp = z & 3;
    const int hd = h * DKn;
    const int t0w = t0 + wv * 16;

    // zero per-wave rel-V band (rows not hit by any chunk stay zero)
    *(uint2*)&pdg[wv][col][quad * 4] = (uint2){0, 0};

    // staging geometry (3 short8 per thread for K, 3 for V)
    int rK[3], cK[3], rV[3], cV[3];
#pragma unroll
    for (int i = 0; i < 3; ++i) {
        int s = tid + i * 256;
        rK[i] = s / 12; cK[i] = (s % 12) * 8;   // 64 rows x 96 cols
        rV[i] = s >> 3; cV[i] = (s & 7) * 8;    // 96 rows x 64 cols
    }
    const bf16* kbase = QK + (size_t)b * Tn * QKS + 192 + hd;
    const bf16* vbase = V + ((size_t)b * Cn + hd) * Tn;

    short8 kst[3], vst[3];
    const int sbeg = sp * (Tn / NSPLIT);
    const int send = sbeg + Tn / NSPLIT;

    // issue first chunk's loads immediately (latency hides under Q/rq prep)
#pragma unroll
    for (int i = 0; i < 3; ++i) {
        kst[i] = *(const short8*)(kbase + (size_t)(sbeg + rK[i]) * QKS + cK[i]);
        vst[i] = *(const short8*)(vbase + (size_t)rV[i] * Tn + sbeg + cV[i]);
    }

    // Q A-frags (persist): A[m=col][k=quad*8+j+32*kd]
    short8 aq[3];
    {
        const bf16* qrow = QK + ((size_t)b * Tn + t0w + col) * QKS + hd + quad * 8;
#pragma unroll
        for (int kd = 0; kd < 3; ++kd) aq[kd] = *(const short8*)(qrow + kd * 32);
    }
    // rel-K band via MFMA: R = Q . erk^T  (B rows 9..15 are zero)
    {
        const bf16* erow = erkb + ((size_t)layer * 16 + col) * 96 + quad * 8;
        f32x4 R = {};
#pragma unroll
        for (int kd = 0; kd < 3; ++kd) {
            short8 be = *(const short8*)(erow + kd * 32);
            R = __builtin_amdgcn_mfma_f32_16x16x32_bf16(aq[kd], be, R, 0, 0, 0);
        }
#pragma unroll
        for (int r = 0; r < 4; ++r) rq[wv][quad * 4 + r][col] = R[r];
    }
    float mtv[4];
#pragma unroll
    for (int r = 0; r < 4; ++r) mtv[r] = mask[b * Tn + t0w + quad * 4 + r];
    const bool qok = __all(mtv[0] != 0.f && mtv[1] != 0.f &&
                           mtv[2] != 0.f && mtv[3] != 0.f);
    int okbits = 0;
    if (qok) {
#pragma unroll
        for (int ch = 0; ch < 4; ++ch) {
            int sc = b * Tn + sbeg + ch * 64 + col;
            float a0 = mask[sc], a1 = mask[sc + 16], a2 = mask[sc + 32], a3 = mask[sc + 48];
            if (__all(a0 != 0.f && a1 != 0.f && a2 != 0.f && a3 != 0.f))
                okbits |= 1 << ch;
        }
    }

    // first chunk into LDS
#pragma unroll
    for (int i = 0; i < 3; ++i) {
        *(short8*)&Ks[rK[i]][cK[i]] = kst[i];
        *(short8*)&Vs[rV[i]][cV[i]] = vst[i];
    }
    __syncthreads();

    f32x4 O[6] = {};
    f32x4 Osum = {};
    short8 ones;
#pragma unroll
    for (int j = 0; j < 8; ++j) ones[j] = (short)0x3F80;   // bf16 1.0

    for (int s0 = sbeg; s0 < send; s0 += 64) {
        const bool nxt = (s0 + 64 < send);
        if (nxt) {
#pragma unroll
            for (int i = 0; i < 3; ++i) {
                kst[i] = *(const short8*)(kbase + (size_t)(s0 + 64 + rK[i]) * QKS + cK[i]);
                vst[i] = *(const short8*)(vbase + (size_t)rV[i] * Tn + s0 + 64 + cV[i]);
            }
        }

        // S = Q K^T (B-frags from LDS)
        f32x4 S[4] = {};
        __builtin_amdgcn_s_setprio(1);
#pragma unroll
        for (int nb = 0; nb < 4; ++nb)
#pragma unroll
            for (int kd = 0; kd < 3; ++kd) {
                short8 bkf = *(const short8*)&Ks[16 * nb + col][kd * 32 + quad * 8];
                S[nb] = __builtin_amdgcn_mfma_f32_16x16x32_bf16(aq[kd], bkf, S[nb], 0, 0, 0);
            }
        __builtin_amdgcn_s_setprio(0);

        const bool diag = (s0 <= t0w + 15 + WINn) && (s0 + 63 >= t0w - WINn);
        if (diag) {
#pragma unroll
            for (int nb = 0; nb < 4; ++nb) {
                const int sg = s0 + 16 * nb + col;
#pragma unroll
                for (int r = 0; r < 4; ++r) {
                    int dd = sg - (t0w + quad * 4 + r) + WINn;
                    if ((unsigned)dd <= 2u * WINn) S[nb][r] += rq[wv][quad * 4 + r][dd];
                }
            }
        }
        if (!((okbits >> ((s0 - sbeg) >> 6)) & 1)) {
#pragma unroll
            for (int nb = 0; nb < 4; ++nb) {
                const float msv = mask[b * Tn + s0 + 16 * nb + col];
#pragma unroll
                for (int r = 0; r < 4; ++r)
                    if (msv * mtv[r] == 0.f) S[nb][r] = -1e4f;
            }
        }

        // P = exp(S) -> pT (pdg band capture only on diagonal chunks)
        if (diag) {
#pragma unroll
            for (int nb = 0; nb < 4; ++nb) {
                const int sg = s0 + 16 * nb + col;
#pragma unroll
                for (int r = 0; r < 4; ++r) {
                    bf16 pb_ = __float2bfloat16(__expf(S[nb][r]));
                    pT[wv][quad * 4 + r][16 * nb + col] = pb_;
                    int dd = sg - (t0w + quad * 4 + r) + WINn;
                    if ((unsigned)dd <= 2u * WINn) pdg[wv][quad * 4 + r][dd] = pb_;
                }
            }
        } else {
#pragma unroll
            for (int nb = 0; nb < 4; ++nb)
#pragma unroll
                for (int r = 0; r < 4; ++r)
                    pT[wv][quad * 4 + r][16 * nb + col] =
                        __float2bfloat16(__expf(S[nb][r]));
        }

        // P A-frags from per-wave LDS; PV + ones-rowsum MFMAs
        short8 aP[2];
#pragma unroll
        for (int kk = 0; kk < 2; ++kk)
            aP[kk] = *(const short8*)&pT[wv][col][kk * 32 + quad * 8];
        __builtin_amdgcn_s_setprio(1);
#pragma unroll
        for (int nd = 0; nd < 6; ++nd)
#pragma unroll
            for (int kk = 0; kk < 2; ++kk) {
                short8 bvf = *(const short8*)&Vs[16 * nd + col][kk * 32 + quad * 8];
                O[nd] = __builtin_amdgcn_mfma_f32_16x16x32_bf16(aP[kk], bvf, O[nd], 0, 0, 0);
            }
#pragma unroll
        for (int kk = 0; kk < 2; ++kk)
            Osum = __builtin_amdgcn_mfma_f32_16x16x32_bf16(aP[kk], ones, Osum, 0, 0, 0);
        __builtin_amdgcn_s_setprio(0);

        __syncthreads();
        if (nxt) {
#pragma unroll
            for (int i = 0; i < 3; ++i) {
                *(short8*)&Ks[rK[i]][cK[i]] = kst[i];
                *(short8*)&Vs[rV[i]][cV[i]] = vst[i];
            }
            __syncthreads();
        }
    }

    // rel-V band contribution: O += pdg(16x16, k 9..15 zero) . ERVB(k x 96)
    {
        short8 ad = {0, 0, 0, 0, 0, 0, 0, 0};
        if (quad < 2) ad = *(const short8*)&pdg[wv][col][quad * 8];
        const bf16* eb = ervb + (size_t)layer * 96 * 32 + (size_t)col * 32 + quad * 8;
#pragma unroll
        for (int nd = 0; nd < 6; ++nd) {
            short8 bd = *(const short8*)(eb + (size_t)nd * 16 * 32);
            O[nd] = __builtin_amdgcn_mfma_f32_16x16x32_bf16(ad, bd, O[nd], 0, 0, 0);
        }
    }

    // epilogue: write unnormalized partials (Lp row-sums come from Osum)
    const int rbase = (b * Hn + h) * Tn + t0w;
#pragma unroll
    for (int r = 0; r < 4; ++r) {
        const int rid = rbase + quad * 4 + r;
        bf16* dst = Op + ((size_t)sp * RN + rid) * 96 + col;
#pragma unroll
        for (int nd = 0; nd < 6; ++nd)
            dst[16 * nd] = __float2bfloat16(O[nd][r]);
        if (col == 0) Lp[sp * RN + rid] = Osum[r];
    }
}

// ---------------------------------------------------------------------------
// FFN2-combine + residual + LN2: Y = (P0+P1+bias)*mask; Xn = LN(X+Y)*g+b.
// OUT==null: X <- Xn, XT <- bf16(Xn).  OUT!=null (last layer): OUT <- Xn*mask.
__global__ __launch_bounds__(256) void ln_ffn2(
        float* __restrict__ X, const float* __restrict__ P0,
        const float* __restrict__ P1, const float* __restrict__ bias,
        const float* __restrict__ G, const float* __restrict__ Bt,
        const float* __restrict__ mask, bf16* __restrict__ XT,
        float* __restrict__ OUT) {
    __shared__ float tile[Cn][33];
    __shared__ float r1[8][32];
    __shared__ float r2[8][32];
    const int tid = threadIdx.x;
    const int lane = tid & 31, w = tid >> 5;
    const int b = blockIdx.x >> 5;
    const int t0 = (blockIdx.x & 31) * 32;
    const int t = t0 + lane;
    const float mk = mask[b * Tn + t];

    float s1 = 0.f, s2 = 0.f;
    for (int c = w; c < Cn; c += 8) {
        size_t i = ((size_t)b * Cn + c) * Tn + t;
        float y = (P0[i] + P1[i] + bias[c]) * mk;
        float v = X[i] + y;
        tile[c][lane] = v;
        s1 += v;
        s2 += v * v;
    }
    r1[w][lane] = s1;
    r2[w][lane] = s2;
    __syncthreads();
    if (w == 0) {
        float a = 0.f, q = 0.f;
        for (int i = 0; i < 8; ++i) { a += r1[i][lane]; q += r2[i][lane]; }
        float m = a / Cn;
        float var = q / Cn - m * m;
        r1[0][lane] = m;
        r2[0][lane] = rsqrtf(var + 1e-5f);
    }
    __syncthreads();
    const float m = r1[0][lane], rs = r2[0][lane];
    if (OUT) {   // final layer: write output = LN(...)*mask directly, done
        for (int c = w; c < Cn; c += 8) {
            float y = (tile[c][lane] - m) * rs * G[c] + Bt[c];
            OUT[((b * Cn + c) * Tn) + t] = y * mk;
        }
        return;
    }
    for (int c = w; c < Cn; c += 8) {
        float y = (tile[c][lane] - m) * rs * G[c] + Bt[c];
        X[((b * Cn + c) * Tn) + t] = y;
        tile[c][lane] = y;
    }
    __syncthreads();
    for (int idx = tid; idx < 32 * Cn; idx += 256) {
        int tl = idx / Cn, c = idx % Cn;
        XT[((size_t)b * Tn + t0 + tl) * Cn + c] = __float2bfloat16(tile[c][tl]);
    }
}

// ---------------------------------------------------------------------------
extern "C" void kernel_launch(void* const* d_in, const int* in_sizes, int n_in,
                              void* d_out, int out_size, void* d_ws, size_t ws_size,
                              hipStream_t stream) {
    const float* x    = (const float*)d_in[0];
    const float* mask = (const float*)d_in[1];
    const float* Wq   = (const float*)d_in[2];
    const float* bq   = (const float*)d_in[3];
    const float* Wk   = (const float*)d_in[4];
    const float* bk   = (const float*)d_in[5];
    const float* Wv   = (const float*)d_in[6];
    const float* bv   = (const float*)d_in[7];
    const float* Wo   = (const float*)d_in[8];
    const float* bo   = (const float*)d_in[9];
    const float* erk  = (const float*)d_in[10];
    const float* erv  = (const float*)d_in[11];
    const float* ln1g = (const float*)d_in[12];
    const float* ln1b = (const float*)d_in[13];
    const float* w1   = (const float*)d_in[14];
    const float* b1   = (const float*)d_in[15];
    const float* w2   = (const float*)d_in[16];
    const float* b2   = (const float*)d_in[17];
    const float* ln2g = (const float*)d_in[18];
    const float* ln2b = (const float*)d_in[19];

    const size_t N = (size_t)Bn * Cn * Tn;         // 1,572,864
    const int WC = Ln * Cn * Cn;                   // 221,184
    const size_t WF = (size_t)Ln * 3 * FCn * Cn;   // 2,654,208
    const size_t WQKV = (size_t)Ln * 576 * Cn;     // 663,552
    const size_t NSCR = (size_t)Bn * Tn * FCn;     // 6,291,456 == NSPLIT*RN*96

    float* X    = (float*)d_ws;
    float* Yb   = X + N;                           // FFN2 partial 0
    float* bqkv = Yb + N;                          // L*576 floats
    float* Lp   = bqkv + Ln * 576;                 // NSPLIT*RN floats
    bf16* p16 = (bf16*)(Lp + (size_t)NSPLIT * RN);
    bf16* XT   = p16; p16 += N;
    bf16* QKT  = p16; p16 += (size_t)Bn * Tn * QKS;  // 2N bf16; dead after attn
    bf16* Vb   = p16; p16 += N;
    bf16* AT   = p16; p16 += N;      // (unused since R5; kept for layout)
    bf16* SCR  = p16; p16 += NSCR;   // shared: attn O-partials <-> FFN hidden
    bf16* Wqkv = p16; p16 += WQKV;
    bf16* Wob  = p16; p16 += WC;
    bf16* W1t  = p16; p16 += WF;
    bf16* W2t  = p16; p16 += WF;
    bf16* ERKB = p16; p16 += Ln * 16 * 96;
    bf16* ERVB = p16; p16 += Ln * 96 * 32;
    float* P1  = (float*)QKT;        // FFN2 partial 1 aliases dead QKT (N fp32)
    (void)AT;

    const float qscale = 0.10206207261596575f;  // 1/sqrt(96)

    // one-time transforms: single fused dispatch
    const size_t nprep = WQKV + Ln * 576 + WC + 2 * WF +
                         (size_t)Ln * 16 * 96 + (size_t)Ln * 96 * 32;
    prep_all<<<(int)((nprep + 255) / 256), 256, 0, stream>>>(
        Wq, Wk, Wv, bq, bk, bv, Wo, w1, w2, erk, erv,
        Wqkv, bqkv, Wob, W1t, W2t, ERKB, ERVB, qscale);
    cvt_in_k<<<Bn * 32, 256, 0, stream>>>(x, mask, X, XT);

    for (int l = 0; l < Ln; ++l) {
        conv_mfma<1, 128, 4, 1><<<dim3(Tn / 128, 9, Bn), 256, 0, stream>>>(
            XT, Wqkv + (size_t)l * 576 * Cn, bqkv + l * 576, nullptr, QKT, Vb, Cn, 576);
        attn_mfma<<<dim3(Tn / 64 * Hn * Bn * NSPLIT), 256, 0, stream>>>(
            QKT, Vb, mask, ERKB, ERVB, SCR, Lp, l);
        // fused: split-combine + Wo conv + residual + LN1 + X/XT write
        wo_ln_k<<<256, 256, 0, stream>>>(
            SCR, Lp, Wob + (size_t)l * Cn * Cn, bo + l * Cn,
            X, ln1g + l * Cn, ln1b + l * Cn, mask, XT);
        conv_mfma<3, 128, 2, 1><<<dim3(Tn / 128, FCn / 64, Bn), 256, 0, stream>>>(
            XT, W1t + (size_t)l * 3 * FCn * Cn, b1 + l * FCn, mask, SCR, nullptr, Cn, FCn);
        conv_mfma<3, 128, 5, 2><<<dim3(Tn / 128, 3, Bn * 2), 256, 0, stream>>>(
            SCR, W2t + (size_t)l * 3 * Cn * FCn, b2 + l * Cn, mask, Yb, P1, FCn, Cn);
        ln_ffn2<<<Bn * 32, 256, 0, stream>>>(X, Yb, P1, b2 + l * Cn,
                                             ln2g + l * Cn, ln2b + l * Cn, mask, XT,
                                             (l == Ln - 1) ? (float*)d_out : nullptr);
    }
}

// Round 7
// 666.994 us; speedup vs baseline: 1.7315x; 1.0471x over previous
//
#include <hip/hip_runtime.h>
#include <hip/hip_bf16.h>

// Problem constants
constexpr int Bn  = 8;
constexpr int Cn  = 192;   // hidden channels
constexpr int Tn  = 1024;  // sequence length
constexpr int Hn  = 2;     // heads
constexpr int DKn = 96;    // head dim
constexpr int FCn = 768;   // filter channels
constexpr int Ln  = 6;     // layers
constexpr int WINn = 4;    // rel-attn window
constexpr int QKS = 384;   // QK transposed row stride (Q|K concat)
constexpr int NSPLIT = 4;  // attention s-split (flash-decoding)
constexpr int RN  = Bn * Hn * Tn;  // 16384 attention rows

typedef __hip_bfloat16 bf16;
typedef __attribute__((ext_vector_type(8))) short short8;
typedef __attribute__((ext_vector_type(4))) float f32x4;

// ---------------------------------------------------------------------------
// One-time weight transforms in a single grid-stride kernel (R6).
__global__ void prep_all(
        const float* __restrict__ Wq, const float* __restrict__ Wk,
        const float* __restrict__ Wv, const float* __restrict__ bq,
        const float* __restrict__ bk, const float* __restrict__ bv,
        const float* __restrict__ Wo, const float* __restrict__ w1,
        const float* __restrict__ w2, const float* __restrict__ erk,
        const float* __restrict__ erv,
        bf16* __restrict__ Wqkv, float* __restrict__ bqkv,
        bf16* __restrict__ Wob, bf16* __restrict__ W1t, bf16* __restrict__ W2t,
        bf16* __restrict__ ERKB, bf16* __restrict__ ERVB, float qscale) {
    size_t i = (size_t)blockIdx.x * 256 + threadIdx.x;
    const size_t nW  = (size_t)Ln * 576 * Cn;     // 663,552
    const size_t nB  = (size_t)Ln * 576;
    const size_t WCn = (size_t)Ln * Cn * Cn;      // 221,184
    const size_t WFn = (size_t)Ln * 3 * FCn * Cn; // 2,654,208
    if (i < nW) {        // fused QKV weight (qscale folded into Q)
        int c = i % Cn, f = (i / Cn) % 576, l = i / (Cn * 576);
        float v;
        if (f < 192)      v = Wq[((size_t)l * Cn + f) * Cn + c] * qscale;
        else if (f < 384) v = Wk[((size_t)l * Cn + f - 192) * Cn + c];
        else              v = Wv[((size_t)l * Cn + f - 384) * Cn + c];
        Wqkv[i] = __float2bfloat16(v);
        return;
    }
    i -= nW;
    if (i < nB) {        // fused QKV bias
        int f = i % 576, l = i / 576;
        float v;
        if (f < 192)      v = bq[l * Cn + f] * qscale;
        else if (f < 384) v = bk[l * Cn + f - 192];
        else              v = bv[l * Cn + f - 384];
        bqkv[i] = v;
        return;
    }
    i -= nB;
    if (i < WCn) {       // Wo cast
        Wob[i] = __float2bfloat16(Wo[i]);
        return;
    }
    i -= WCn;
    if (i < WFn) {       // w1 [L][FC][C][3] -> [L][3][FC][C]
        int c = i % Cn;
        int f = (i / Cn) % FCn;
        int ko = (i / (Cn * FCn)) % 3;
        int l = i / (3 * Cn * FCn);
        W1t[i] = __float2bfloat16(w1[(((size_t)(l * FCn + f)) * Cn + c) * 3 + ko]);
        return;
    }
    i -= WFn;
    if (i < WFn) {       // w2 [L][C][FC][3] -> [L][3][C][FC]
        int c = i % FCn;
        int f = (i / FCn) % Cn;
        int ko = (i / (FCn * Cn)) % 3;
        int l = i / (3 * FCn * Cn);
        W2t[i] = __float2bfloat16(w2[(((size_t)(l * Cn + f)) * FCn + c) * 3 + ko]);
        return;
    }
    i -= WFn;
    if (i < (size_t)Ln * 16 * 96) {   // erk -> [L][16][96], rows 9..15 zero
        int d = i % 96, row = (i / 96) % 16, l = i / (96 * 16);
        float v = (row < 9) ? erk[((size_t)l * 9 + row) * 96 + d] : 0.f;
        ERKB[i] = __float2bfloat16(v);
        return;
    }
    i -= (size_t)Ln * 16 * 96;
    if (i < (size_t)Ln * 96 * 32) {   // erv -> [L][96][32] transposed, k 9..31 zero
        int k = i & 31, d = (i >> 5) % 96, l = i / (96 * 32);
        float v = (k < 9) ? erv[((size_t)l * 9 + k) * 96 + d] : 0.f;
        ERVB[i] = __float2bfloat16(v);
    }
}

// ---------------------------------------------------------------------------
// Input: X = x*mask (fp32, NCT) + XT = bf16 transposed [b][t][c]
__global__ __launch_bounds__(256) void cvt_in_k(
        const float* __restrict__ x, const float* __restrict__ mask,
        float* __restrict__ X, bf16* __restrict__ XT) {
    __shared__ float tile[Cn][33];
    const int tid = threadIdx.x, lane = tid & 31, w = tid >> 5;
    const int b = blockIdx.x >> 5;
    const int t0 = (blockIdx.x & 31) * 32;
    const float mk = mask[b * Tn + t0 + lane];
    for (int c = w; c < Cn; c += 8) {
        float v = x[((b * Cn + c) * Tn) + t0 + lane] * mk;
        X[((b * Cn + c) * Tn) + t0 + lane] = v;
        tile[c][lane] = v;
    }
    __syncthreads();
    for (int idx = tid; idx < 32 * Cn; idx += 256) {
        int tl = idx / Cn, c = idx % Cn;
        XT[((size_t)b * Tn + t0 + tl) * Cn + c] = __float2bfloat16(tile[c][tl]);
    }
}

// ---------------------------------------------------------------------------
// MFMA conv1d, LDS-staged, TT=128 for K-heavy convs, T14 async-STAGE (R4).
// MODE 2: bf16 transposed [b][t][CO] out relu(+bias)*mask   [FFN1]
// MODE 4: QKV split: f<384 -> bf16 T (stride QKS) into Y0; else bf16 NCT Y1
template <int KS, int TT, int MODE, int NSP>
__global__ __launch_bounds__(256) void conv_mfma(
        const bf16* __restrict__ Xt, const bf16* __restrict__ W,
        const float* __restrict__ bias, const float* __restrict__ mask,
        void* __restrict__ Y0, void* __restrict__ Y1, int CIN, int CO) {
    constexpr int PAD = KS / 2;
    constexpr int NMB = TT / 16;
    constexpr int AR  = TT + KS - 1;        // A rows staged
    constexpr int RS  = 72;                 // padded row stride (bf16 cols)
    constexpr int NA  = (AR * 8 + 255) / 256;  // per-thread A short8 loads
    constexpr int NB  = KS * 2;                // per-thread B short8 loads
    __shared__ bf16 As[AR][RS];
    __shared__ bf16 Bs[KS][64][RS];

    const int tid = threadIdx.x;
    const int wv = tid >> 6, lane = tid & 63;
    const int m = lane & 15, kq = lane >> 4;
    const int b = blockIdx.z / NSP, ks = blockIdx.z % NSP;
    const int t0 = blockIdx.x * TT;
    const int f0 = blockIdx.y * 64;
    const int f = f0 + wv * 16 + m;

    const bf16* xb = Xt + (size_t)b * Tn * CIN;
    const size_t wko = (size_t)CO * CIN;

    int rA[NA], cA[NA];
    bool vA[NA];
#pragma unroll
    for (int i = 0; i < NA; ++i) {
        int s = tid + i * 256;
        rA[i] = s >> 3; cA[i] = (s & 7) * 8; vA[i] = (s < AR * 8);
    }
    int rB[NB], cB[NB], koB[NB];
#pragma unroll
    for (int i = 0; i < NB; ++i) {
        int s = tid + i * 256;          // always < KS*512
        koB[i] = s >> 9; rB[i] = (s >> 3) & 63; cB[i] = (s & 7) * 8;
    }

    short8 pa[NA], pb[NB];
    const int cbeg = ks * (CIN / NSP);
    const int cend = cbeg + CIN / NSP;

    auto issue = [&](int c0) {
#pragma unroll
        for (int i = 0; i < NA; ++i) {
            short8 v = {0, 0, 0, 0, 0, 0, 0, 0};
            if (vA[i]) {
                int gt = t0 + rA[i] - PAD;
                if (PAD == 0 || (unsigned)gt < (unsigned)Tn)
                    v = *(const short8*)(xb + (size_t)gt * CIN + c0 + cA[i]);
            }
            pa[i] = v;
        }
#pragma unroll
        for (int i = 0; i < NB; ++i)
            pb[i] = *(const short8*)(W + (size_t)koB[i] * wko +
                                     (size_t)(f0 + rB[i]) * CIN + c0 + cB[i]);
    };
    auto commit = [&]() {
#pragma unroll
        for (int i = 0; i < NA; ++i)
            if (vA[i]) *(short8*)&As[rA[i]][cA[i]] = pa[i];
#pragma unroll
        for (int i = 0; i < NB; ++i)
            *(short8*)&Bs[koB[i]][rB[i]][cB[i]] = pb[i];
    };

    f32x4 acc[NMB] = {};

    issue(cbeg);
    commit();
    __syncthreads();

    for (int c0 = cbeg; c0 < cend; c0 += 64) {
        const bool nxt = (c0 + 64 < cend);
        if (nxt) issue(c0 + 64);
#pragma unroll
        for (int kk = 0; kk < 2; ++kk)
#pragma unroll
            for (int ko = 0; ko < KS; ++ko) {
                short8 bfr = *(const short8*)&Bs[ko][wv * 16 + m][kk * 32 + kq * 8];
#pragma unroll
                for (int mb = 0; mb < NMB; ++mb) {
                    short8 afr = *(const short8*)&As[mb * 16 + m + ko][kk * 32 + kq * 8];
                    acc[mb] = __builtin_amdgcn_mfma_f32_16x16x32_bf16(afr, bfr, acc[mb], 0, 0, 0);
                }
            }
        if (nxt) {
            __syncthreads();   // all fragment reads of this chunk complete
            commit();
            __syncthreads();   // staged data visible
        }
    }

    const float bs = bias[f];
    if (MODE == 2) {
        bf16* Y = (bf16*)Y0;
#pragma unroll
        for (int mb = 0; mb < NMB; ++mb)
#pragma unroll
            for (int r = 0; r < 4; ++r) {
                int t = t0 + mb * 16 + kq * 4 + r;
                float v = fmaxf(acc[mb][r] + bs, 0.f) * mask[b * Tn + t];
                Y[((size_t)b * Tn + t) * CO + f] = __float2bfloat16(v);
            }
    } else {  // MODE 4
        if (blockIdx.y < 6) {          // Q|K -> transposed, stride QKS
            bf16* Y = (bf16*)Y0;
#pragma unroll
            for (int mb = 0; mb < NMB; ++mb)
#pragma unroll
                for (int r = 0; r < 4; ++r) {
                    int t = t0 + mb * 16 + kq * 4 + r;
                    Y[((size_t)b * Tn + t) * QKS + f] = __float2bfloat16(acc[mb][r] + bs);
                }
        } else {                        // V -> bf16 NCT
            bf16* Y = (bf16*)Y1 + ((size_t)b * Cn + f - 384) * Tn;
#pragma unroll
            for (int mb = 0; mb < NMB; ++mb) {
                int t = t0 + mb * 16 + kq * 4;
                bf16 tmp[4];
#pragma unroll
                for (int r = 0; r < 4; ++r) tmp[r] = __float2bfloat16(acc[mb][r] + bs);
                *(uint2*)(Y + t) = *(uint2*)tmp;
            }
        }
    }
}

// ---------------------------------------------------------------------------
// R6: fused Wo stage: attn split-combine + Wo conv + bias + residual
// + channel-LayerNorm + X/XT write. One block owns [32 t x 192 c].
__global__ __launch_bounds__(256) void wo_ln_k(
        const bf16* __restrict__ Op, const float* __restrict__ Lp,
        const bf16* __restrict__ W, const float* __restrict__ bias,
        float* __restrict__ X, const float* __restrict__ G,
        const float* __restrict__ Bt, const float* __restrict__ mask,
        bf16* __restrict__ XT) {
    __shared__ bf16 As[32][72];       // combined attn out [t][c-chunk]
    __shared__ bf16 Bs[192][72];      // Wo panel [f][c-chunk]
    __shared__ float sm1[4][32];
    __shared__ float sm2[4][32];

    const int tid = threadIdx.x;
    const int wv = tid >> 6, lane = tid & 63;
    const int m = lane & 15, quad = lane >> 4;
    const int b = blockIdx.x & 7;
    const int t0 = (blockIdx.x >> 3) * 32;

    const int rA = tid >> 3, cA = (tid & 7) * 8;   // A: 32 rows x 8 short8
    short8 pa6[4]; float pl6[4];
    short8 pb[6];                                   // B: 192 rows x 8 short8

    auto issue = [&](int c0) {
        int c = c0 + cA;
        int hh = (c >= 96) ? 1 : 0;
        int rid = (b * Hn + hh) * Tn + t0 + rA;
        int d0 = c - 96 * hh;
#pragma unroll
        for (int sp = 0; sp < 4; ++sp) {
            pa6[sp] = *(const short8*)(Op + ((size_t)sp * RN + rid) * 96 + d0);
            pl6[sp] = Lp[sp * RN + rid];
        }
#pragma unroll
        for (int i = 0; i < 6; ++i) {
            int s = tid + i * 256;
            pb[i] = *(const short8*)(W + (size_t)(s >> 3) * Cn + c0 + (s & 7) * 8);
        }
    };
    auto commit = [&]() {
        float denom = pl6[0] + pl6[1] + pl6[2] + pl6[3];
        float inv = 1.f / fmaxf(denom, 1e-30f);
        bf16 tmp[8];
#pragma unroll
        for (int e = 0; e < 8; ++e) {
            float o = 0.f;
#pragma unroll
            for (int sp = 0; sp < 4; ++sp)
                o += __bfloat162float(((const bf16*)&pa6[sp])[e]);
            tmp[e] = __float2bfloat16(o * inv);
        }
        *(short8*)&As[rA][cA] = *(const short8*)tmp;
#pragma unroll
        for (int i = 0; i < 6; ++i) {
            int s = tid + i * 256;
            *(short8*)&Bs[s >> 3][(s & 7) * 8] = pb[i];
        }
    };

    f32x4 acc[3][2] = {};

    issue(0);
    commit();
    __syncthreads();
    for (int c0 = 0; c0 < Cn; c0 += 64) {
        const bool nxt = (c0 + 64 < Cn);
        if (nxt) issue(c0 + 64);
#pragma unroll
        for (int kk = 0; kk < 2; ++kk)
#pragma unroll
            for (int fb = 0; fb < 3; ++fb) {
                short8 bfr = *(const short8*)&Bs[fb * 64 + wv * 16 + m][kk * 32 + quad * 8];
#pragma unroll
                for (int mb = 0; mb < 2; ++mb) {
                    short8 afr = *(const short8*)&As[mb * 16 + m][kk * 32 + quad * 8];
                    acc[fb][mb] = __builtin_amdgcn_mfma_f32_16x16x32_bf16(afr, bfr, acc[fb][mb], 0, 0, 0);
                }
            }
        if (nxt) {
            __syncthreads();
            commit();
            __syncthreads();
        }
    }

    // bias + residual; accumulate per-t LN stats over this lane's channels
    float s1[2][4] = {{0.f, 0.f, 0.f, 0.f}, {0.f, 0.f, 0.f, 0.f}};
    float s2[2][4] = {{0.f, 0.f, 0.f, 0.f}, {0.f, 0.f, 0.f, 0.f}};
#pragma unroll
    for (int fb = 0; fb < 3; ++fb) {
        const int f = fb * 64 + wv * 16 + m;
        const float bsv = bias[f];
#pragma unroll
        for (int mb = 0; mb < 2; ++mb) {
            const int t = t0 + mb * 16 + quad * 4;
            float4 xv = *(const float4*)(X + ((size_t)(b * Cn + f)) * Tn + t);
            acc[fb][mb][0] += bsv + xv.x;
            acc[fb][mb][1] += bsv + xv.y;
            acc[fb][mb][2] += bsv + xv.z;
            acc[fb][mb][3] += bsv + xv.w;
#pragma unroll
            for (int r = 0; r < 4; ++r) {
                float v = acc[fb][mb][r];
                s1[mb][r] += v;
                s2[mb][r] += v * v;
            }
        }
    }
#pragma unroll
    for (int mb = 0; mb < 2; ++mb)
#pragma unroll
        for (int r = 0; r < 4; ++r)
#pragma unroll
            for (int mk = 1; mk < 16; mk <<= 1) {
                s1[mb][r] += __shfl_xor(s1[mb][r], mk);
                s2[mb][r] += __shfl_xor(s2[mb][r], mk);
            }
    if (m == 0) {
#pragma unroll
        for (int mb = 0; mb < 2; ++mb)
#pragma unroll
            for (int r = 0; r < 4; ++r) {
                sm1[wv][mb * 16 + quad * 4 + r] = s1[mb][r];
                sm2[wv][mb * 16 + quad * 4 + r] = s2[mb][r];
            }
    }
    __syncthreads();
    float mean[2][4], rs[2][4], mtv[2][4];
#pragma unroll
    for (int mb = 0; mb < 2; ++mb) {
        float4 mk4 = *(const float4*)(mask + b * Tn + t0 + mb * 16 + quad * 4);
        mtv[mb][0] = mk4.x; mtv[mb][1] = mk4.y;
        mtv[mb][2] = mk4.z; mtv[mb][3] = mk4.w;
#pragma unroll
        for (int r = 0; r < 4; ++r) {
            int tt = mb * 16 + quad * 4 + r;
            float a = sm1[0][tt] + sm1[1][tt] + sm1[2][tt] + sm1[3][tt];
            float q = sm2[0][tt] + sm2[1][tt] + sm2[2][tt] + sm2[3][tt];
            float mn = a / Cn;
            mean[mb][r] = mn;
            rs[mb][r] = rsqrtf(q / Cn - mn * mn + 1e-5f);
        }
    }
#pragma unroll
    for (int fb = 0; fb < 3; ++fb) {
        const int f = fb * 64 + wv * 16 + m;
        const float gv = G[f], bv = Bt[f];
#pragma unroll
        for (int mb = 0; mb < 2; ++mb) {
            const int t = t0 + mb * 16 + quad * 4;
            float y[4];
#pragma unroll
            for (int r = 0; r < 4; ++r)
                y[r] = (acc[fb][mb][r] - mean[mb][r]) * rs[mb][r] * gv + bv;
            float4 xo;
            xo.x = y[0]; xo.y = y[1]; xo.z = y[2]; xo.w = y[3];
            *(float4*)(X + ((size_t)(b * Cn + f)) * Tn + t) = xo;
#pragma unroll
            for (int r = 0; r < 4; ++r)
                XT[((size_t)b * Tn + t + r) * Cn + f] =
                    __float2bfloat16(y[r] * mtv[mb][r]);
        }
    }
}

// ---------------------------------------------------------------------------
// R7: fused FFN2 stage: conv2 (K=768x3) + bias + *mask + residual +
// channel-LayerNorm + X/XT write (or OUT on last layer). One block owns
// [32 t x 192 c]; replaces the split FFN2 (2 fp32 partials) AND ln_ffn2 —
// kills 6 dispatches + 24 MB/layer partial round-trip.
// Hc: bf16 [b][t][FCn] masked relu hidden (FFN1 MODE-2 output).
// W: W2t layer [3][Cn][FCn].
__global__ __launch_bounds__(256) void ffn2_ln(
        const bf16* __restrict__ Hc, const bf16* __restrict__ W,
        const float* __restrict__ bias, float* __restrict__ X,
        const float* __restrict__ G, const float* __restrict__ Bt,
        const float* __restrict__ mask, bf16* __restrict__ XT,
        float* __restrict__ OUT) {
    __shared__ bf16 As[34][72];        // hidden rows t0-1..t0+32, c-chunk
    __shared__ bf16 Bs[3][192][72];    // W2 panel [ko][f][c-chunk]  (~83 KB)
    __shared__ float sm1[4][32];
    __shared__ float sm2[4][32];

    const int tid = threadIdx.x;
    const int wv = tid >> 6, lane = tid & 63;
    const int m = lane & 15, quad = lane >> 4;
    const int b = blockIdx.x & 7;
    const int t0 = (blockIdx.x >> 3) * 32;

    const bf16* hb = Hc + (size_t)b * Tn * FCn;

    short8 pa[2], pb[18];
    auto issue = [&](int c0) {
#pragma unroll
        for (int i = 0; i < 2; ++i) {
            int s = tid + i * 256;
            short8 v = {0, 0, 0, 0, 0, 0, 0, 0};
            if (s < 272) {
                int gt = t0 + (s >> 3) - 1;
                if ((unsigned)gt < (unsigned)Tn)
                    v = *(const short8*)(hb + (size_t)gt * FCn + c0 + (s & 7) * 8);
            }
            pa[i] = v;
        }
#pragma unroll
        for (int i = 0; i < 18; ++i) {
            int s = tid + i * 256;           // < 4608 = 3*192*8
            int ko = s / 1536, rem = s - ko * 1536;
            pb[i] = *(const short8*)(W + (size_t)ko * Cn * FCn +
                                     (size_t)(rem >> 3) * FCn + c0 + (rem & 7) * 8);
        }
    };
    auto commit = [&]() {
#pragma unroll
        for (int i = 0; i < 2; ++i) {
            int s = tid + i * 256;
            if (s < 272) *(short8*)&As[s >> 3][(s & 7) * 8] = pa[i];
        }
#pragma unroll
        for (int i = 0; i < 18; ++i) {
            int s = tid + i * 256;
            int ko = s / 1536, rem = s - ko * 1536;
            *(short8*)&Bs[ko][rem >> 3][(rem & 7) * 8] = pb[i];
        }
    };

    f32x4 acc[3][2] = {};

    issue(0);
    commit();
    __syncthreads();
    for (int c0 = 0; c0 < FCn; c0 += 64) {
        const bool nxt = (c0 + 64 < FCn);
        if (nxt) issue(c0 + 64);
#pragma unroll
        for (int kk = 0; kk < 2; ++kk)
#pragma unroll
            for (int ko = 0; ko < 3; ++ko)
#pragma unroll
                for (int fb = 0; fb < 3; ++fb) {
                    short8 bfr = *(const short8*)&Bs[ko][fb * 64 + wv * 16 + m][kk * 32 + quad * 8];
#pragma unroll
                    for (int mb = 0; mb < 2; ++mb) {
                        short8 afr = *(const short8*)&As[mb * 16 + m + ko][kk * 32 + quad * 8];
                        acc[fb][mb] = __builtin_amdgcn_mfma_f32_16x16x32_bf16(afr, bfr, acc[fb][mb], 0, 0, 0);
                    }
                }
        if (nxt) {
            __syncthreads();
            commit();
            __syncthreads();
        }
    }

    // y = (conv + bias)*mask; v = X + y; LN stats over channels
    float mtv[2][4];
#pragma unroll
    for (int mb = 0; mb < 2; ++mb) {
        float4 mk4 = *(const float4*)(mask + b * Tn + t0 + mb * 16 + quad * 4);
        mtv[mb][0] = mk4.x; mtv[mb][1] = mk4.y;
        mtv[mb][2] = mk4.z; mtv[mb][3] = mk4.w;
    }
    float s1[2][4] = {{0.f, 0.f, 0.f, 0.f}, {0.f, 0.f, 0.f, 0.f}};
    float s2[2][4] = {{0.f, 0.f, 0.f, 0.f}, {0.f, 0.f, 0.f, 0.f}};
#pragma unroll
    for (int fb = 0; fb < 3; ++fb) {
        const int f = fb * 64 + wv * 16 + m;
        const float bsv = bias[f];
#pragma unroll
        for (int mb = 0; mb < 2; ++mb) {
            const int t = t0 + mb * 16 + quad * 4;
            float4 xv = *(const float4*)(X + ((size_t)(b * Cn + f)) * Tn + t);
            acc[fb][mb][0] = xv.x + (acc[fb][mb][0] + bsv) * mtv[mb][0];
            acc[fb][mb][1] = xv.y + (acc[fb][mb][1] + bsv) * mtv[mb][1];
            acc[fb][mb][2] = xv.z + (acc[fb][mb][2] + bsv) * mtv[mb][2];
            acc[fb][mb][3] = xv.w + (acc[fb][mb][3] + bsv) * mtv[mb][3];
#pragma unroll
            for (int r = 0; r < 4; ++r) {
                float v = acc[fb][mb][r];
                s1[mb][r] += v;
                s2[mb][r] += v * v;
            }
        }
    }
#pragma unroll
    for (int mb = 0; mb < 2; ++mb)
#pragma unroll
        for (int r = 0; r < 4; ++r)
#pragma unroll
            for (int mk = 1; mk < 16; mk <<= 1) {
                s1[mb][r] += __shfl_xor(s1[mb][r], mk);
                s2[mb][r] += __shfl_xor(s2[mb][r], mk);
            }
    if (m == 0) {
#pragma unroll
        for (int mb = 0; mb < 2; ++mb)
#pragma unroll
            for (int r = 0; r < 4; ++r) {
                sm1[wv][mb * 16 + quad * 4 + r] = s1[mb][r];
                sm2[wv][mb * 16 + quad * 4 + r] = s2[mb][r];
            }
    }
    __syncthreads();
    float mean[2][4], rs[2][4];
#pragma unroll
    for (int mb = 0; mb < 2; ++mb)
#pragma unroll
        for (int r = 0; r < 4; ++r) {
            int tt = mb * 16 + quad * 4 + r;
            float a = sm1[0][tt] + sm1[1][tt] + sm1[2][tt] + sm1[3][tt];
            float q = sm2[0][tt] + sm2[1][tt] + sm2[2][tt] + sm2[3][tt];
            float mn = a / Cn;
            mean[mb][r] = mn;
            rs[mb][r] = rsqrtf(q / Cn - mn * mn + 1e-5f);
        }
#pragma unroll
    for (int fb = 0; fb < 3; ++fb) {
        const int f = fb * 64 + wv * 16 + m;
        const float gv = G[f], bv = Bt[f];
#pragma unroll
        for (int mb = 0; mb < 2; ++mb) {
            const int t = t0 + mb * 16 + quad * 4;
            float y[4];
#pragma unroll
            for (int r = 0; r < 4; ++r)
                y[r] = (acc[fb][mb][r] - mean[mb][r]) * rs[mb][r] * gv + bv;
            if (OUT) {      // final layer: OUT = LN(...)*mask, NCT fp32
                float4 xo;
                xo.x = y[0] * mtv[mb][0]; xo.y = y[1] * mtv[mb][1];
                xo.z = y[2] * mtv[mb][2]; xo.w = y[3] * mtv[mb][3];
                *(float4*)(OUT + ((size_t)(b * Cn + f)) * Tn + t) = xo;
            } else {
                float4 xo;
                xo.x = y[0]; xo.y = y[1]; xo.z = y[2]; xo.w = y[3];
                *(float4*)(X + ((size_t)(b * Cn + f)) * Tn + t) = xo;
#pragma unroll
                for (int r = 0; r < 4; ++r)
                    XT[((size_t)b * Tn + t + r) * Cn + f] = __float2bfloat16(y[r]);
            }
        }
    }
}

// ---------------------------------------------------------------------------
// MFMA flash attention, split-K over s, LDS-staged K/V, XCD swizzle (R2),
// T14 async-STAGE split (R2), rel-V via MFMA (R3), VALU cuts + setprio (R5).
// FIXED-MAX softmax (scores O(5), exp safe in fp32).
// Writes UNNORMALIZED partials: Op bf16 [sp][rid][96], Lp fp32 [sp][rid].
__global__ __launch_bounds__(256) void attn_mfma(
        const bf16* __restrict__ QK, const bf16* __restrict__ V,
        const float* __restrict__ mask, const bf16* __restrict__ erkb,
        const bf16* __restrict__ ervb, bf16* __restrict__ Op,
        float* __restrict__ Lp, int layer) {
    __shared__ bf16 Ks[64][100];      // K chunk [s][d]
    __shared__ bf16 Vs[96][68];       // V chunk [d][s]
    __shared__ float rq[4][16][17];   // per-wave rel-K band: [m][dd]
    __shared__ bf16 pT[4][16][68];    // per-wave P: [m][s]
    __shared__ bf16 pdg[4][16][16];   // per-wave rel-V band: [m][dd], 9..15 zero

    const int tid = threadIdx.x, wv = tid >> 6, lane = tid & 63;
    const int col = lane & 15, quad = lane >> 4;
    const int w = (blockIdx.x & 7) * 128 + (blockIdx.x >> 3);
    const int t0 = (w & 15) * 64;
    const int yz = w >> 4;
    const int h = yz & 1;
    const int z = yz >> 1;
    const int b = z >> 2, sp = z & 3;
    const int hd = h * DKn;
    const int t0w = t0 + wv * 16;

    *(uint2*)&pdg[wv][col][quad * 4] = (uint2){0, 0};

    int rK[3], cK[3], rV[3], cV[3];
#pragma unroll
    for (int i = 0; i < 3; ++i) {
        int s = tid + i * 256;
        rK[i] = s / 12; cK[i] = (s % 12) * 8;   // 64 rows x 96 cols
        rV[i] = s >> 3; cV[i] = (s & 7) * 8;    // 96 rows x 64 cols
    }
    const bf16* kbase = QK + (size_t)b * Tn * QKS + 192 + hd;
    const bf16* vbase = V + ((size_t)b * Cn + hd) * Tn;

    short8 kst[3], vst[3];
    const int sbeg = sp * (Tn / NSPLIT);
    const int send = sbeg + Tn / NSPLIT;

#pragma unroll
    for (int i = 0; i < 3; ++i) {
        kst[i] = *(const short8*)(kbase + (size_t)(sbeg + rK[i]) * QKS + cK[i]);
        vst[i] = *(const short8*)(vbase + (size_t)rV[i] * Tn + sbeg + cV[i]);
    }

    short8 aq[3];
    {
        const bf16* qrow = QK + ((size_t)b * Tn + t0w + col) * QKS + hd + quad * 8;
#pragma unroll
        for (int kd = 0; kd < 3; ++kd) aq[kd] = *(const short8*)(qrow + kd * 32);
    }
    {
        const bf16* erow = erkb + ((size_t)layer * 16 + col) * 96 + quad * 8;
        f32x4 R = {};
#pragma unroll
        for (int kd = 0; kd < 3; ++kd) {
            short8 be = *(const short8*)(erow + kd * 32);
            R = __builtin_amdgcn_mfma_f32_16x16x32_bf16(aq[kd], be, R, 0, 0, 0);
        }
#pragma unroll
        for (int r = 0; r < 4; ++r) rq[wv][quad * 4 + r][col] = R[r];
    }
    float mtv[4];
#pragma unroll
    for (int r = 0; r < 4; ++r) mtv[r] = mask[b * Tn + t0w + quad * 4 + r];
    const bool qok = __all(mtv[0] != 0.f && mtv[1] != 0.f &&
                           mtv[2] != 0.f && mtv[3] != 0.f);
    int okbits = 0;
    if (qok) {
#pragma unroll
        for (int ch = 0; ch < 4; ++ch) {
            int sc = b * Tn + sbeg + ch * 64 + col;
            float a0 = mask[sc], a1 = mask[sc + 16], a2 = mask[sc + 32], a3 = mask[sc + 48];
            if (__all(a0 != 0.f && a1 != 0.f && a2 != 0.f && a3 != 0.f))
                okbits |= 1 << ch;
        }
    }

#pragma unroll
    for (int i = 0; i < 3; ++i) {
        *(short8*)&Ks[rK[i]][cK[i]] = kst[i];
        *(short8*)&Vs[rV[i]][cV[i]] = vst[i];
    }
    __syncthreads();

    f32x4 O[6] = {};
    f32x4 Osum = {};
    short8 ones;
#pragma unroll
    for (int j = 0; j < 8; ++j) ones[j] = (short)0x3F80;   // bf16 1.0

    for (int s0 = sbeg; s0 < send; s0 += 64) {
        const bool nxt = (s0 + 64 < send);
        if (nxt) {
#pragma unroll
            for (int i = 0; i < 3; ++i) {
                kst[i] = *(const short8*)(kbase + (size_t)(s0 + 64 + rK[i]) * QKS + cK[i]);
                vst[i] = *(const short8*)(vbase + (size_t)rV[i] * Tn + s0 + 64 + cV[i]);
            }
        }

        f32x4 S[4] = {};
        __builtin_amdgcn_s_setprio(1);
#pragma unroll
        for (int nb = 0; nb < 4; ++nb)
#pragma unroll
            for (int kd = 0; kd < 3; ++kd) {
                short8 bkf = *(const short8*)&Ks[16 * nb + col][kd * 32 + quad * 8];
                S[nb] = __builtin_amdgcn_mfma_f32_16x16x32_bf16(aq[kd], bkf, S[nb], 0, 0, 0);
            }
        __builtin_amdgcn_s_setprio(0);

        const bool diag = (s0 <= t0w + 15 + WINn) && (s0 + 63 >= t0w - WINn);
        if (diag) {
#pragma unroll
            for (int nb = 0; nb < 4; ++nb) {
                const int sg = s0 + 16 * nb + col;
#pragma unroll
                for (int r = 0; r < 4; ++r) {
                    int dd = sg - (t0w + quad * 4 + r) + WINn;
                    if ((unsigned)dd <= 2u * WINn) S[nb][r] += rq[wv][quad * 4 + r][dd];
                }
            }
        }
        if (!((okbits >> ((s0 - sbeg) >> 6)) & 1)) {
#pragma unroll
            for (int nb = 0; nb < 4; ++nb) {
                const float msv = mask[b * Tn + s0 + 16 * nb + col];
#pragma unroll
                for (int r = 0; r < 4; ++r)
                    if (msv * mtv[r] == 0.f) S[nb][r] = -1e4f;
            }
        }

        if (diag) {
#pragma unroll
            for (int nb = 0; nb < 4; ++nb) {
                const int sg = s0 + 16 * nb + col;
#pragma unroll
                for (int r = 0; r < 4; ++r) {
                    bf16 pb_ = __float2bfloat16(__expf(S[nb][r]));
                    pT[wv][quad * 4 + r][16 * nb + col] = pb_;
                    int dd = sg - (t0w + quad * 4 + r) + WINn;
                    if ((unsigned)dd <= 2u * WINn) pdg[wv][quad * 4 + r][dd] = pb_;
                }
            }
        } else {
#pragma unroll
            for (int nb = 0; nb < 4; ++nb)
#pragma unroll
                for (int r = 0; r < 4; ++r)
                    pT[wv][quad * 4 + r][16 * nb + col] =
                        __float2bfloat16(__expf(S[nb][r]));
        }

        short8 aP[2];
#pragma unroll
        for (int kk = 0; kk < 2; ++kk)
            aP[kk] = *(const short8*)&pT[wv][col][kk * 32 + quad * 8];
        __builtin_amdgcn_s_setprio(1);
#pragma unroll
        for (int nd = 0; nd < 6; ++nd)
#pragma unroll
            for (int kk = 0; kk < 2; ++kk) {
                short8 bvf = *(const short8*)&Vs[16 * nd + col][kk * 32 + quad * 8];
                O[nd] = __builtin_amdgcn_mfma_f32_16x16x32_bf16(aP[kk], bvf, O[nd], 0, 0, 0);
            }
#pragma unroll
        for (int kk = 0; kk < 2; ++kk)
            Osum = __builtin_amdgcn_mfma_f32_16x16x32_bf16(aP[kk], ones, Osum, 0, 0, 0);
        __builtin_amdgcn_s_setprio(0);

        __syncthreads();
        if (nxt) {
#pragma unroll
            for (int i = 0; i < 3; ++i) {
                *(short8*)&Ks[rK[i]][cK[i]] = kst[i];
                *(short8*)&Vs[rV[i]][cV[i]] = vst[i];
            }
            __syncthreads();
        }
    }

    {
        short8 ad = {0, 0, 0, 0, 0, 0, 0, 0};
        if (quad < 2) ad = *(const short8*)&pdg[wv][col][quad * 8];
        const bf16* eb = ervb + (size_t)layer * 96 * 32 + (size_t)col * 32 + quad * 8;
#pragma unroll
        for (int nd = 0; nd < 6; ++nd) {
            short8 bd = *(const short8*)(eb + (size_t)nd * 16 * 32);
            O[nd] = __builtin_amdgcn_mfma_f32_16x16x32_bf16(ad, bd, O[nd], 0, 0, 0);
        }
    }

    const int rbase = (b * Hn + h) * Tn + t0w;
#pragma unroll
    for (int r = 0; r < 4; ++r) {
        const int rid = rbase + quad * 4 + r;
        bf16* dst = Op + ((size_t)sp * RN + rid) * 96 + col;
#pragma unroll
        for (int nd = 0; nd < 6; ++nd)
            dst[16 * nd] = __float2bfloat16(O[nd][r]);
        if (col == 0) Lp[sp * RN + rid] = Osum[r];
    }
}

// ---------------------------------------------------------------------------
extern "C" void kernel_launch(void* const* d_in, const int* in_sizes, int n_in,
                              void* d_out, int out_size, void* d_ws, size_t ws_size,
                              hipStream_t stream) {
    const float* x    = (const float*)d_in[0];
    const float* mask = (const float*)d_in[1];
    const float* Wq   = (const float*)d_in[2];
    const float* bq   = (const float*)d_in[3];
    const float* Wk   = (const float*)d_in[4];
    const float* bk   = (const float*)d_in[5];
    const float* Wv   = (const float*)d_in[6];
    const float* bv   = (const float*)d_in[7];
    const float* Wo   = (const float*)d_in[8];
    const float* bo   = (const float*)d_in[9];
    const float* erk  = (const float*)d_in[10];
    const float* erv  = (const float*)d_in[11];
    const float* ln1g = (const float*)d_in[12];
    const float* ln1b = (const float*)d_in[13];
    const float* w1   = (const float*)d_in[14];
    const float* b1   = (const float*)d_in[15];
    const float* w2   = (const float*)d_in[16];
    const float* b2   = (const float*)d_in[17];
    const float* ln2g = (const float*)d_in[18];
    const float* ln2b = (const float*)d_in[19];

    const size_t N = (size_t)Bn * Cn * Tn;         // 1,572,864
    const int WC = Ln * Cn * Cn;                   // 221,184
    const size_t WF = (size_t)Ln * 3 * FCn * Cn;   // 2,654,208
    const size_t WQKV = (size_t)Ln * 576 * Cn;     // 663,552
    const size_t NSCR = (size_t)Bn * Tn * FCn;     // 6,291,456 == NSPLIT*RN*96

    float* X    = (float*)d_ws;
    float* Yb   = X + N;                           // (unused since R7)
    float* bqkv = Yb + N;                          // L*576 floats
    float* Lp   = bqkv + Ln * 576;                 // NSPLIT*RN floats
    bf16* p16 = (bf16*)(Lp + (size_t)NSPLIT * RN);
    bf16* XT   = p16; p16 += N;
    bf16* QKT  = p16; p16 += (size_t)Bn * Tn * QKS;  // 2N bf16; dead after attn
    bf16* Vb   = p16; p16 += N;
    bf16* AT   = p16; p16 += N;      // (unused; kept for layout)
    bf16* SCR  = p16; p16 += NSCR;   // shared: attn O-partials <-> FFN hidden
    bf16* Wqkv = p16; p16 += WQKV;
    bf16* Wob  = p16; p16 += WC;
    bf16* W1t  = p16; p16 += WF;
    bf16* W2t  = p16; p16 += WF;
    bf16* ERKB = p16; p16 += Ln * 16 * 96;
    bf16* ERVB = p16; p16 += Ln * 96 * 32;
    (void)AT; (void)Yb;

    const float qscale = 0.10206207261596575f;  // 1/sqrt(96)

    // one-time transforms: single fused dispatch
    const size_t nprep = WQKV + Ln * 576 + WC + 2 * WF +
                         (size_t)Ln * 16 * 96 + (size_t)Ln * 96 * 32;
    prep_all<<<(int)((nprep + 255) / 256), 256, 0, stream>>>(
        Wq, Wk, Wv, bq, bk, bv, Wo, w1, w2, erk, erv,
        Wqkv, bqkv, Wob, W1t, W2t, ERKB, ERVB, qscale);
    cvt_in_k<<<Bn * 32, 256, 0, stream>>>(x, mask, X, XT);

    for (int l = 0; l < Ln; ++l) {
        conv_mfma<1, 128, 4, 1><<<dim3(Tn / 128, 9, Bn), 256, 0, stream>>>(
            XT, Wqkv + (size_t)l * 576 * Cn, bqkv + l * 576, nullptr, QKT, Vb, Cn, 576);
        attn_mfma<<<dim3(Tn / 64 * Hn * Bn * NSPLIT), 256, 0, stream>>>(
            QKT, Vb, mask, ERKB, ERVB, SCR, Lp, l);
        // fused: split-combine + Wo conv + residual + LN1 + X/XT write
        wo_ln_k<<<256, 256, 0, stream>>>(
            SCR, Lp, Wob + (size_t)l * Cn * Cn, bo + l * Cn,
            X, ln1g + l * Cn, ln1b + l * Cn, mask, XT);
        conv_mfma<3, 128, 2, 1><<<dim3(Tn / 128, FCn / 64, Bn), 256, 0, stream>>>(
            XT, W1t + (size_t)l * 3 * FCn * Cn, b1 + l * FCn, mask, SCR, nullptr, Cn, FCn);
        // fused: FFN2 conv + mask + residual + LN2 + X/XT (or OUT) write
        ffn2_ln<<<256, 256, 0, stream>>>(
            SCR, W2t + (size_t)l * 3 * Cn * FCn, b2 + l * Cn,
            X, ln2g + l * Cn, ln2b + l * Cn, mask, XT,
            (l == Ln - 1) ? (float*)d_out : nullptr);
    }
}

// Round 8
// 613.077 us; speedup vs baseline: 1.8838x; 1.0879x over previous
//
#include <hip/hip_runtime.h>
#include <hip/hip_bf16.h>

// Problem constants
constexpr int Bn  = 8;
constexpr int Cn  = 192;   // hidden channels
constexpr int Tn  = 1024;  // sequence length
constexpr int Hn  = 2;     // heads
constexpr int DKn = 96;    // head dim
constexpr int FCn = 768;   // filter channels
constexpr int Ln  = 6;     // layers
constexpr int WINn = 4;    // rel-attn window
constexpr int QKS = 384;   // QK transposed row stride (Q|K concat)
constexpr int NSPLIT = 4;  // attention s-split (flash-decoding)
constexpr int RN  = Bn * Hn * Tn;  // 16384 attention rows

typedef __hip_bfloat16 bf16;
typedef __attribute__((ext_vector_type(8))) short short8;
typedef __attribute__((ext_vector_type(4))) float f32x4;

// ---------------------------------------------------------------------------
// One-time weight transforms in a single grid-stride kernel (R6).
__global__ void prep_all(
        const float* __restrict__ Wq, const float* __restrict__ Wk,
        const float* __restrict__ Wv, const float* __restrict__ bq,
        const float* __restrict__ bk, const float* __restrict__ bv,
        const float* __restrict__ Wo, const float* __restrict__ w1,
        const float* __restrict__ w2, const float* __restrict__ erk,
        const float* __restrict__ erv,
        bf16* __restrict__ Wqkv, float* __restrict__ bqkv,
        bf16* __restrict__ Wob, bf16* __restrict__ W1t, bf16* __restrict__ W2t,
        bf16* __restrict__ ERKB, bf16* __restrict__ ERVB, float qscale) {
    size_t i = (size_t)blockIdx.x * 256 + threadIdx.x;
    const size_t nW  = (size_t)Ln * 576 * Cn;     // 663,552
    const size_t nB  = (size_t)Ln * 576;
    const size_t WCn = (size_t)Ln * Cn * Cn;      // 221,184
    const size_t WFn = (size_t)Ln * 3 * FCn * Cn; // 2,654,208
    if (i < nW) {        // fused QKV weight (qscale folded into Q)
        int c = i % Cn, f = (i / Cn) % 576, l = i / (Cn * 576);
        float v;
        if (f < 192)      v = Wq[((size_t)l * Cn + f) * Cn + c] * qscale;
        else if (f < 384) v = Wk[((size_t)l * Cn + f - 192) * Cn + c];
        else              v = Wv[((size_t)l * Cn + f - 384) * Cn + c];
        Wqkv[i] = __float2bfloat16(v);
        return;
    }
    i -= nW;
    if (i < nB) {        // fused QKV bias
        int f = i % 576, l = i / 576;
        float v;
        if (f < 192)      v = bq[l * Cn + f] * qscale;
        else if (f < 384) v = bk[l * Cn + f - 192];
        else              v = bv[l * Cn + f - 384];
        bqkv[i] = v;
        return;
    }
    i -= nB;
    if (i < WCn) {       // Wo cast
        Wob[i] = __float2bfloat16(Wo[i]);
        return;
    }
    i -= WCn;
    if (i < WFn) {       // w1 [L][FC][C][3] -> [L][3][FC][C]
        int c = i % Cn;
        int f = (i / Cn) % FCn;
        int ko = (i / (Cn * FCn)) % 3;
        int l = i / (3 * Cn * FCn);
        W1t[i] = __float2bfloat16(w1[(((size_t)(l * FCn + f)) * Cn + c) * 3 + ko]);
        return;
    }
    i -= WFn;
    if (i < WFn) {       // w2 [L][C][FC][3] -> [L][3][C][FC]
        int c = i % FCn;
        int f = (i / FCn) % Cn;
        int ko = (i / (FCn * Cn)) % 3;
        int l = i / (3 * FCn * Cn);
        W2t[i] = __float2bfloat16(w2[(((size_t)(l * Cn + f)) * FCn + c) * 3 + ko]);
        return;
    }
    i -= WFn;
    if (i < (size_t)Ln * 16 * 96) {   // erk -> [L][16][96], rows 9..15 zero
        int d = i % 96, row = (i / 96) % 16, l = i / (96 * 16);
        float v = (row < 9) ? erk[((size_t)l * 9 + row) * 96 + d] : 0.f;
        ERKB[i] = __float2bfloat16(v);
        return;
    }
    i -= (size_t)Ln * 16 * 96;
    if (i < (size_t)Ln * 96 * 32) {   // erv -> [L][96][32] transposed, k 9..31 zero
        int k = i & 31, d = (i >> 5) % 96, l = i / (96 * 32);
        float v = (k < 9) ? erv[((size_t)l * 9 + k) * 96 + d] : 0.f;
        ERVB[i] = __float2bfloat16(v);
    }
}

// ---------------------------------------------------------------------------
// Input: X = x*mask (fp32, NCT) + XT = bf16 transposed [b][t][c]
__global__ __launch_bounds__(256) void cvt_in_k(
        const float* __restrict__ x, const float* __restrict__ mask,
        float* __restrict__ X, bf16* __restrict__ XT) {
    __shared__ float tile[Cn][33];
    const int tid = threadIdx.x, lane = tid & 31, w = tid >> 5;
    const int b = blockIdx.x >> 5;
    const int t0 = (blockIdx.x & 31) * 32;
    const float mk = mask[b * Tn + t0 + lane];
    for (int c = w; c < Cn; c += 8) {
        float v = x[((b * Cn + c) * Tn) + t0 + lane] * mk;
        X[((b * Cn + c) * Tn) + t0 + lane] = v;
        tile[c][lane] = v;
    }
    __syncthreads();
    for (int idx = tid; idx < 32 * Cn; idx += 256) {
        int tl = idx / Cn, c = idx % Cn;
        XT[((size_t)b * Tn + t0 + tl) * Cn + c] = __float2bfloat16(tile[c][tl]);
    }
}

// ---------------------------------------------------------------------------
// MFMA conv1d, LDS-staged, TT=128 for K-heavy convs, T14 async-STAGE (R4).
// MODE 2: bf16 transposed [b][t][CO] out relu(+bias)*mask   [FFN1]
// MODE 4: QKV split: f<384 -> bf16 T (stride QKS) into Y0; else bf16 NCT Y1
template <int KS, int TT, int MODE, int NSP>
__global__ __launch_bounds__(256) void conv_mfma(
        const bf16* __restrict__ Xt, const bf16* __restrict__ W,
        const float* __restrict__ bias, const float* __restrict__ mask,
        void* __restrict__ Y0, void* __restrict__ Y1, int CIN, int CO) {
    constexpr int PAD = KS / 2;
    constexpr int NMB = TT / 16;
    constexpr int AR  = TT + KS - 1;        // A rows staged
    constexpr int RS  = 72;                 // padded row stride (bf16 cols)
    constexpr int NA  = (AR * 8 + 255) / 256;  // per-thread A short8 loads
    constexpr int NB  = KS * 2;                // per-thread B short8 loads
    __shared__ bf16 As[AR][RS];
    __shared__ bf16 Bs[KS][64][RS];

    const int tid = threadIdx.x;
    const int wv = tid >> 6, lane = tid & 63;
    const int m = lane & 15, kq = lane >> 4;
    const int b = blockIdx.z / NSP, ks = blockIdx.z % NSP;
    const int t0 = blockIdx.x * TT;
    const int f0 = blockIdx.y * 64;
    const int f = f0 + wv * 16 + m;

    const bf16* xb = Xt + (size_t)b * Tn * CIN;
    const size_t wko = (size_t)CO * CIN;

    int rA[NA], cA[NA];
    bool vA[NA];
#pragma unroll
    for (int i = 0; i < NA; ++i) {
        int s = tid + i * 256;
        rA[i] = s >> 3; cA[i] = (s & 7) * 8; vA[i] = (s < AR * 8);
    }
    int rB[NB], cB[NB], koB[NB];
#pragma unroll
    for (int i = 0; i < NB; ++i) {
        int s = tid + i * 256;          // always < KS*512
        koB[i] = s >> 9; rB[i] = (s >> 3) & 63; cB[i] = (s & 7) * 8;
    }

    short8 pa[NA], pb[NB];
    const int cbeg = ks * (CIN / NSP);
    const int cend = cbeg + CIN / NSP;

    auto issue = [&](int c0) {
#pragma unroll
        for (int i = 0; i < NA; ++i) {
            short8 v = {0, 0, 0, 0, 0, 0, 0, 0};
            if (vA[i]) {
                int gt = t0 + rA[i] - PAD;
                if (PAD == 0 || (unsigned)gt < (unsigned)Tn)
                    v = *(const short8*)(xb + (size_t)gt * CIN + c0 + cA[i]);
            }
            pa[i] = v;
        }
#pragma unroll
        for (int i = 0; i < NB; ++i)
            pb[i] = *(const short8*)(W + (size_t)koB[i] * wko +
                                     (size_t)(f0 + rB[i]) * CIN + c0 + cB[i]);
    };
    auto commit = [&]() {
#pragma unroll
        for (int i = 0; i < NA; ++i)
            if (vA[i]) *(short8*)&As[rA[i]][cA[i]] = pa[i];
#pragma unroll
        for (int i = 0; i < NB; ++i)
            *(short8*)&Bs[koB[i]][rB[i]][cB[i]] = pb[i];
    };

    f32x4 acc[NMB] = {};

    issue(cbeg);
    commit();
    __syncthreads();

    for (int c0 = cbeg; c0 < cend; c0 += 64) {
        const bool nxt = (c0 + 64 < cend);
        if (nxt) issue(c0 + 64);
#pragma unroll
        for (int kk = 0; kk < 2; ++kk)
#pragma unroll
            for (int ko = 0; ko < KS; ++ko) {
                short8 bfr = *(const short8*)&Bs[ko][wv * 16 + m][kk * 32 + kq * 8];
#pragma unroll
                for (int mb = 0; mb < NMB; ++mb) {
                    short8 afr = *(const short8*)&As[mb * 16 + m + ko][kk * 32 + kq * 8];
                    acc[mb] = __builtin_amdgcn_mfma_f32_16x16x32_bf16(afr, bfr, acc[mb], 0, 0, 0);
                }
            }
        if (nxt) {
            __syncthreads();   // all fragment reads of this chunk complete
            commit();
            __syncthreads();   // staged data visible
        }
    }

    const float bs = bias[f];
    if (MODE == 2) {
        bf16* Y = (bf16*)Y0;
#pragma unroll
        for (int mb = 0; mb < NMB; ++mb)
#pragma unroll
            for (int r = 0; r < 4; ++r) {
                int t = t0 + mb * 16 + kq * 4 + r;
                float v = fmaxf(acc[mb][r] + bs, 0.f) * mask[b * Tn + t];
                Y[((size_t)b * Tn + t) * CO + f] = __float2bfloat16(v);
            }
    } else {  // MODE 4
        if (blockIdx.y < 6) {          // Q|K -> transposed, stride QKS
            bf16* Y = (bf16*)Y0;
#pragma unroll
            for (int mb = 0; mb < NMB; ++mb)
#pragma unroll
                for (int r = 0; r < 4; ++r) {
                    int t = t0 + mb * 16 + kq * 4 + r;
                    Y[((size_t)b * Tn + t) * QKS + f] = __float2bfloat16(acc[mb][r] + bs);
                }
        } else {                        // V -> bf16 NCT
            bf16* Y = (bf16*)Y1 + ((size_t)b * Cn + f - 384) * Tn;
#pragma unroll
            for (int mb = 0; mb < NMB; ++mb) {
                int t = t0 + mb * 16 + kq * 4;
                bf16 tmp[4];
#pragma unroll
                for (int r = 0; r < 4; ++r) tmp[r] = __float2bfloat16(acc[mb][r] + bs);
                *(uint2*)(Y + t) = *(uint2*)tmp;
            }
        }
    }
}

// ---------------------------------------------------------------------------
// R8: wo_ln_k at 512 threads / 8 waves (2 waves/SIMD, was 1). Waves map as
// 4 f-groups (48 ch) x 2 t-groups (16 rows); per-wave acc[3]; B prefetch
// 6->3 regs. Same math as R6 version.
__global__ __launch_bounds__(512) void wo_ln_k(
        const bf16* __restrict__ Op, const float* __restrict__ Lp,
        const bf16* __restrict__ W, const float* __restrict__ bias,
        float* __restrict__ X, const float* __restrict__ G,
        const float* __restrict__ Bt, const float* __restrict__ mask,
        bf16* __restrict__ XT) {
    __shared__ bf16 As[32][72];       // combined attn out [t][c-chunk]
    __shared__ bf16 Bs[192][72];      // Wo panel [f][c-chunk]
    __shared__ float sm1[8][16];
    __shared__ float sm2[8][16];

    const int tid = threadIdx.x;
    const int wv = tid >> 6, lane = tid & 63;
    const int m = lane & 15, quad = lane >> 4;
    const int fg = wv & 3, tg = wv >> 2;
    const int b = blockIdx.x & 7;
    const int t0 = (blockIdx.x >> 3) * 32;

    const bool vA = (tid < 256);
    const int rA = tid >> 3, cA = (tid & 7) * 8;   // A: 32 rows x 8 short8
    short8 pa6[4]; float pl6[4];
    short8 pb[3];                                   // B: 1536 short8 / 512

    auto issue = [&](int c0) {
        if (vA) {
            int c = c0 + cA;
            int hh = (c >= 96) ? 1 : 0;
            int rid = (b * Hn + hh) * Tn + t0 + rA;
            int d0 = c - 96 * hh;
#pragma unroll
            for (int sp = 0; sp < 4; ++sp) {
                pa6[sp] = *(const short8*)(Op + ((size_t)sp * RN + rid) * 96 + d0);
                pl6[sp] = Lp[sp * RN + rid];
            }
        }
#pragma unroll
        for (int i = 0; i < 3; ++i) {
            int s = tid + i * 512;
            pb[i] = *(const short8*)(W + (size_t)(s >> 3) * Cn + c0 + (s & 7) * 8);
        }
    };
    auto commit = [&]() {
        if (vA) {
            float denom = pl6[0] + pl6[1] + pl6[2] + pl6[3];
            float inv = 1.f / fmaxf(denom, 1e-30f);
            bf16 tmp[8];
#pragma unroll
            for (int e = 0; e < 8; ++e) {
                float o = 0.f;
#pragma unroll
                for (int sp = 0; sp < 4; ++sp)
                    o += __bfloat162float(((const bf16*)&pa6[sp])[e]);
                tmp[e] = __float2bfloat16(o * inv);
            }
            *(short8*)&As[rA][cA] = *(const short8*)tmp;
        }
#pragma unroll
        for (int i = 0; i < 3; ++i) {
            int s = tid + i * 512;
            *(short8*)&Bs[s >> 3][(s & 7) * 8] = pb[i];
        }
    };

    f32x4 acc[3] = {};

    issue(0);
    commit();
    __syncthreads();
    for (int c0 = 0; c0 < Cn; c0 += 64) {
        const bool nxt = (c0 + 64 < Cn);
        if (nxt) issue(c0 + 64);
#pragma unroll
        for (int kk = 0; kk < 2; ++kk) {
            short8 afr = *(const short8*)&As[tg * 16 + m][kk * 32 + quad * 8];
#pragma unroll
            for (int fb = 0; fb < 3; ++fb) {
                short8 bfr = *(const short8*)&Bs[fg * 48 + fb * 16 + m][kk * 32 + quad * 8];
                acc[fb] = __builtin_amdgcn_mfma_f32_16x16x32_bf16(afr, bfr, acc[fb], 0, 0, 0);
            }
        }
        if (nxt) {
            __syncthreads();
            commit();
            __syncthreads();
        }
    }

    // bias + residual; per-t LN stats over this lane's 3 channels
    const int tq = t0 + tg * 16 + quad * 4;
    float s1[4] = {}, s2[4] = {};
#pragma unroll
    for (int fb = 0; fb < 3; ++fb) {
        const int f = fg * 48 + fb * 16 + m;
        const float bsv = bias[f];
        float4 xv = *(const float4*)(X + ((size_t)(b * Cn + f)) * Tn + tq);
        acc[fb][0] += bsv + xv.x;
        acc[fb][1] += bsv + xv.y;
        acc[fb][2] += bsv + xv.z;
        acc[fb][3] += bsv + xv.w;
#pragma unroll
        for (int r = 0; r < 4; ++r) {
            float v = acc[fb][r];
            s1[r] += v;
            s2[r] += v * v;
        }
    }
#pragma unroll
    for (int r = 0; r < 4; ++r)
#pragma unroll
        for (int mk = 1; mk < 16; mk <<= 1) {
            s1[r] += __shfl_xor(s1[r], mk);
            s2[r] += __shfl_xor(s2[r], mk);
        }
    if (m == 0) {
#pragma unroll
        for (int r = 0; r < 4; ++r) {
            sm1[wv][quad * 4 + r] = s1[r];
            sm2[wv][quad * 4 + r] = s2[r];
        }
    }
    __syncthreads();
    float mean[4], rsv[4];
    float4 mk4 = *(const float4*)(mask + b * Tn + tq);
    float mtv[4] = {mk4.x, mk4.y, mk4.z, mk4.w};
#pragma unroll
    for (int r = 0; r < 4; ++r) {
        int tt = quad * 4 + r;
        float a = sm1[tg * 4 + 0][tt] + sm1[tg * 4 + 1][tt] +
                  sm1[tg * 4 + 2][tt] + sm1[tg * 4 + 3][tt];
        float q = sm2[tg * 4 + 0][tt] + sm2[tg * 4 + 1][tt] +
                  sm2[tg * 4 + 2][tt] + sm2[tg * 4 + 3][tt];
        float mn = a / Cn;
        mean[r] = mn;
        rsv[r] = rsqrtf(q / Cn - mn * mn + 1e-5f);
    }
#pragma unroll
    for (int fb = 0; fb < 3; ++fb) {
        const int f = fg * 48 + fb * 16 + m;
        const float gv = G[f], bv = Bt[f];
        float y[4];
#pragma unroll
        for (int r = 0; r < 4; ++r)
            y[r] = (acc[fb][r] - mean[r]) * rsv[r] * gv + bv;
        float4 xo;
        xo.x = y[0]; xo.y = y[1]; xo.z = y[2]; xo.w = y[3];
        *(float4*)(X + ((size_t)(b * Cn + f)) * Tn + tq) = xo;
#pragma unroll
        for (int r = 0; r < 4; ++r)
            XT[((size_t)b * Tn + tq + r) * Cn + f] =
                __float2bfloat16(y[r] * mtv[r]);
    }
}

// ---------------------------------------------------------------------------
// R8: ffn2_ln at 512 threads / 8 waves (2 waves/SIMD, was 1; B prefetch
// 18->9 regs, kills the near-spill). Waves = 4 f-groups x 2 t-groups.
// conv2 (K=768x3) + bias + *mask + residual + channel-LN + X/XT (or OUT).
__global__ __launch_bounds__(512) void ffn2_ln(
        const bf16* __restrict__ Hc, const bf16* __restrict__ W,
        const float* __restrict__ bias, float* __restrict__ X,
        const float* __restrict__ G, const float* __restrict__ Bt,
        const float* __restrict__ mask, bf16* __restrict__ XT,
        float* __restrict__ OUT) {
    __shared__ bf16 As[34][72];        // hidden rows t0-1..t0+32, c-chunk
    __shared__ bf16 Bs[3][192][72];    // W2 panel [ko][f][c-chunk]  (~83 KB)
    __shared__ float sm1[8][16];
    __shared__ float sm2[8][16];

    const int tid = threadIdx.x;
    const int wv = tid >> 6, lane = tid & 63;
    const int m = lane & 15, quad = lane >> 4;
    const int fg = wv & 3, tg = wv >> 2;
    const int b = blockIdx.x & 7;
    const int t0 = (blockIdx.x >> 3) * 32;

    const bf16* hb = Hc + (size_t)b * Tn * FCn;

    const bool vA = (tid < 272);
    short8 pa, pb[9];
    auto issue = [&](int c0) {
        short8 v = {0, 0, 0, 0, 0, 0, 0, 0};
        if (vA) {
            int gt = t0 + (tid >> 3) - 1;
            if ((unsigned)gt < (unsigned)Tn)
                v = *(const short8*)(hb + (size_t)gt * FCn + c0 + (tid & 7) * 8);
        }
        pa = v;
#pragma unroll
        for (int i = 0; i < 9; ++i) {
            int s = tid + i * 512;           // < 4608 = 3*192*8
            int ko = s / 1536, rem = s - ko * 1536;
            pb[i] = *(const short8*)(W + (size_t)ko * Cn * FCn +
                                     (size_t)(rem >> 3) * FCn + c0 + (rem & 7) * 8);
        }
    };
    auto commit = [&]() {
        if (vA) *(short8*)&As[tid >> 3][(tid & 7) * 8] = pa;
#pragma unroll
        for (int i = 0; i < 9; ++i) {
            int s = tid + i * 512;
            int ko = s / 1536, rem = s - ko * 1536;
            *(short8*)&Bs[ko][rem >> 3][(rem & 7) * 8] = pb[i];
        }
    };

    f32x4 acc[3] = {};

    issue(0);
    commit();
    __syncthreads();
    for (int c0 = 0; c0 < FCn; c0 += 64) {
        const bool nxt = (c0 + 64 < FCn);
        if (nxt) issue(c0 + 64);
#pragma unroll
        for (int kk = 0; kk < 2; ++kk)
#pragma unroll
            for (int ko = 0; ko < 3; ++ko) {
                short8 afr = *(const short8*)&As[tg * 16 + m + ko][kk * 32 + quad * 8];
#pragma unroll
                for (int fb = 0; fb < 3; ++fb) {
                    short8 bfr = *(const short8*)&Bs[ko][fg * 48 + fb * 16 + m][kk * 32 + quad * 8];
                    acc[fb] = __builtin_amdgcn_mfma_f32_16x16x32_bf16(afr, bfr, acc[fb], 0, 0, 0);
                }
            }
        if (nxt) {
            __syncthreads();
            commit();
            __syncthreads();
        }
    }

    // y = (conv + bias)*mask; v = X + y; LN stats over channels
    const int tq = t0 + tg * 16 + quad * 4;
    float4 mk4 = *(const float4*)(mask + b * Tn + tq);
    float mtv[4] = {mk4.x, mk4.y, mk4.z, mk4.w};
    float s1[4] = {}, s2[4] = {};
#pragma unroll
    for (int fb = 0; fb < 3; ++fb) {
        const int f = fg * 48 + fb * 16 + m;
        const float bsv = bias[f];
        float4 xv = *(const float4*)(X + ((size_t)(b * Cn + f)) * Tn + tq);
        acc[fb][0] = xv.x + (acc[fb][0] + bsv) * mtv[0];
        acc[fb][1] = xv.y + (acc[fb][1] + bsv) * mtv[1];
        acc[fb][2] = xv.z + (acc[fb][2] + bsv) * mtv[2];
        acc[fb][3] = xv.w + (acc[fb][3] + bsv) * mtv[3];
#pragma unroll
        for (int r = 0; r < 4; ++r) {
            float v = acc[fb][r];
            s1[r] += v;
            s2[r] += v * v;
        }
    }
#pragma unroll
    for (int r = 0; r < 4; ++r)
#pragma unroll
        for (int mk = 1; mk < 16; mk <<= 1) {
            s1[r] += __shfl_xor(s1[r], mk);
            s2[r] += __shfl_xor(s2[r], mk);
        }
    if (m == 0) {
#pragma unroll
        for (int r = 0; r < 4; ++r) {
            sm1[wv][quad * 4 + r] = s1[r];
            sm2[wv][quad * 4 + r] = s2[r];
        }
    }
    __syncthreads();
    float mean[4], rsv[4];
#pragma unroll
    for (int r = 0; r < 4; ++r) {
        int tt = quad * 4 + r;
        float a = sm1[tg * 4 + 0][tt] + sm1[tg * 4 + 1][tt] +
                  sm1[tg * 4 + 2][tt] + sm1[tg * 4 + 3][tt];
        float q = sm2[tg * 4 + 0][tt] + sm2[tg * 4 + 1][tt] +
                  sm2[tg * 4 + 2][tt] + sm2[tg * 4 + 3][tt];
        float mn = a / Cn;
        mean[r] = mn;
        rsv[r] = rsqrtf(q / Cn - mn * mn + 1e-5f);
    }
#pragma unroll
    for (int fb = 0; fb < 3; ++fb) {
        const int f = fg * 48 + fb * 16 + m;
        const float gv = G[f], bv = Bt[f];
        float y[4];
#pragma unroll
        for (int r = 0; r < 4; ++r)
            y[r] = (acc[fb][r] - mean[r]) * rsv[r] * gv + bv;
        if (OUT) {      // final layer: OUT = LN(...)*mask, NCT fp32
            float4 xo;
            xo.x = y[0] * mtv[0]; xo.y = y[1] * mtv[1];
            xo.z = y[2] * mtv[2]; xo.w = y[3] * mtv[3];
            *(float4*)(OUT + ((size_t)(b * Cn + f)) * Tn + tq) = xo;
        } else {
            float4 xo;
            xo.x = y[0]; xo.y = y[1]; xo.z = y[2]; xo.w = y[3];
            *(float4*)(X + ((size_t)(b * Cn + f)) * Tn + tq) = xo;
#pragma unroll
            for (int r = 0; r < 4; ++r)
                XT[((size_t)b * Tn + tq + r) * Cn + f] = __float2bfloat16(y[r]);
        }
    }
}

// ---------------------------------------------------------------------------
// MFMA flash attention. R8: 8 waves / QBLK=128 per block (512 threads,
// grid 512): per-wave code unchanged (each wave owns 16 q-rows), but
// per-phase MFMA doubles and K/V panel re-reads halve. LDS 56 KB ->
// 2 blocks/CU = 16 waves/CU = 4 waves/SIMD (same as before).
// Retains: XCD swizzle (R2), T14 async-STAGE (R2), rel-V via MFMA (R3),
// ones-MFMA rowsum + gating + setprio (R5). FIXED-MAX softmax.
// Writes UNNORMALIZED partials: Op bf16 [sp][rid][96], Lp fp32 [sp][rid].
__global__ __launch_bounds__(512) void attn_mfma(
        const bf16* __restrict__ QK, const bf16* __restrict__ V,
        const float* __restrict__ mask, const bf16* __restrict__ erkb,
        const bf16* __restrict__ ervb, bf16* __restrict__ Op,
        float* __restrict__ Lp, int layer) {
    __shared__ bf16 Ks[64][100];      // K chunk [s][d]
    __shared__ bf16 Vs[96][68];       // V chunk [d][s]
    __shared__ float rq[8][16][17];   // per-wave rel-K band: [m][dd]
    __shared__ bf16 pT[8][16][68];    // per-wave P: [m][s]
    __shared__ bf16 pdg[8][16][16];   // per-wave rel-V band: [m][dd], 9..15 zero
    // LDS total: 12800+13056+8704+17408+4096 = 56064 B -> 2 blocks/CU

    const int tid = threadIdx.x, wv = tid >> 6, lane = tid & 63;
    const int col = lane & 15, quad = lane >> 4;
    // XCD-bijective swizzle (512 = 8 XCD x 64)
    const int w = (blockIdx.x & 7) * 64 + (blockIdx.x >> 3);
    const int t0 = (w & 7) * 128;
    const int yz = w >> 3;
    const int h = yz & 1;
    const int z = yz >> 1;
    const int b = z >> 2, sp = z & 3;
    const int hd = h * DKn;
    const int t0w = t0 + wv * 16;

    *(uint2*)&pdg[wv][col][quad * 4] = (uint2){0, 0};

    // staging geometry: 768 short8 each for K and V; 512 threads ->
    // one each + threads<256 take a second
    const bool g2 = (tid < 256);
    int rK[2], cK[2], rV[2], cV[2];
    {
        int s = tid;
        rK[0] = s / 12; cK[0] = (s % 12) * 8;   // 64 rows x 96 cols
        rV[0] = s >> 3; cV[0] = (s & 7) * 8;    // 96 rows x 64 cols
        s = tid + 512;
        rK[1] = s / 12; cK[1] = (s % 12) * 8;   // valid only if g2
        rV[1] = s >> 3; cV[1] = (s & 7) * 8;
    }
    const bf16* kbase = QK + (size_t)b * Tn * QKS + 192 + hd;
    const bf16* vbase = V + ((size_t)b * Cn + hd) * Tn;

    short8 kst[2], vst[2];
    const int sbeg = sp * (Tn / NSPLIT);
    const int send = sbeg + Tn / NSPLIT;

    kst[0] = *(const short8*)(kbase + (size_t)(sbeg + rK[0]) * QKS + cK[0]);
    vst[0] = *(const short8*)(vbase + (size_t)rV[0] * Tn + sbeg + cV[0]);
    if (g2) {
        kst[1] = *(const short8*)(kbase + (size_t)(sbeg + rK[1]) * QKS + cK[1]);
        vst[1] = *(const short8*)(vbase + (size_t)rV[1] * Tn + sbeg + cV[1]);
    }

    // Q A-frags (persist): A[m=col][k=quad*8+j+32*kd]
    short8 aq[3];
    {
        const bf16* qrow = QK + ((size_t)b * Tn + t0w + col) * QKS + hd + quad * 8;
#pragma unroll
        for (int kd = 0; kd < 3; ++kd) aq[kd] = *(const short8*)(qrow + kd * 32);
    }
    // rel-K band via MFMA: R = Q . erk^T  (B rows 9..15 are zero)
    {
        const bf16* erow = erkb + ((size_t)layer * 16 + col) * 96 + quad * 8;
        f32x4 R = {};
#pragma unroll
        for (int kd = 0; kd < 3; ++kd) {
            short8 be = *(const short8*)(erow + kd * 32);
            R = __builtin_amdgcn_mfma_f32_16x16x32_bf16(aq[kd], be, R, 0, 0, 0);
        }
#pragma unroll
        for (int r = 0; r < 4; ++r) rq[wv][quad * 4 + r][col] = R[r];
    }
    float mtv[4];
#pragma unroll
    for (int r = 0; r < 4; ++r) mtv[r] = mask[b * Tn + t0w + quad * 4 + r];
    const bool qok = __all(mtv[0] != 0.f && mtv[1] != 0.f &&
                           mtv[2] != 0.f && mtv[3] != 0.f);
    int okbits = 0;
    if (qok) {
#pragma unroll
        for (int ch = 0; ch < 4; ++ch) {
            int sc = b * Tn + sbeg + ch * 64 + col;
            float a0 = mask[sc], a1 = mask[sc + 16], a2 = mask[sc + 32], a3 = mask[sc + 48];
            if (__all(a0 != 0.f && a1 != 0.f && a2 != 0.f && a3 != 0.f))
                okbits |= 1 << ch;
        }
    }

    *(short8*)&Ks[rK[0]][cK[0]] = kst[0];
    *(short8*)&Vs[rV[0]][cV[0]] = vst[0];
    if (g2) {
        *(short8*)&Ks[rK[1]][cK[1]] = kst[1];
        *(short8*)&Vs[rV[1]][cV[1]] = vst[1];
    }
    __syncthreads();

    f32x4 O[6] = {};
    f32x4 Osum = {};
    short8 ones;
#pragma unroll
    for (int j = 0; j < 8; ++j) ones[j] = (short)0x3F80;   // bf16 1.0

    for (int s0 = sbeg; s0 < send; s0 += 64) {
        const bool nxt = (s0 + 64 < send);
        if (nxt) {
            kst[0] = *(const short8*)(kbase + (size_t)(s0 + 64 + rK[0]) * QKS + cK[0]);
            vst[0] = *(const short8*)(vbase + (size_t)rV[0] * Tn + s0 + 64 + cV[0]);
            if (g2) {
                kst[1] = *(const short8*)(kbase + (size_t)(s0 + 64 + rK[1]) * QKS + cK[1]);
                vst[1] = *(const short8*)(vbase + (size_t)rV[1] * Tn + s0 + 64 + cV[1]);
            }
        }

        f32x4 S[4] = {};
        __builtin_amdgcn_s_setprio(1);
#pragma unroll
        for (int nb = 0; nb < 4; ++nb)
#pragma unroll
            for (int kd = 0; kd < 3; ++kd) {
                short8 bkf = *(const short8*)&Ks[16 * nb + col][kd * 32 + quad * 8];
                S[nb] = __builtin_amdgcn_mfma_f32_16x16x32_bf16(aq[kd], bkf, S[nb], 0, 0, 0);
            }
        __builtin_amdgcn_s_setprio(0);

        const bool diag = (s0 <= t0w + 15 + WINn) && (s0 + 63 >= t0w - WINn);
        if (diag) {
#pragma unroll
            for (int nb = 0; nb < 4; ++nb) {
                const int sg = s0 + 16 * nb + col;
#pragma unroll
                for (int r = 0; r < 4; ++r) {
                    int dd = sg - (t0w + quad * 4 + r) + WINn;
                    if ((unsigned)dd <= 2u * WINn) S[nb][r] += rq[wv][quad * 4 + r][dd];
                }
            }
        }
        if (!((okbits >> ((s0 - sbeg) >> 6)) & 1)) {
#pragma unroll
            for (int nb = 0; nb < 4; ++nb) {
                const float msv = mask[b * Tn + s0 + 16 * nb + col];
#pragma unroll
                for (int r = 0; r < 4; ++r)
                    if (msv * mtv[r] == 0.f) S[nb][r] = -1e4f;
            }
        }

        if (diag) {
#pragma unroll
            for (int nb = 0; nb < 4; ++nb) {
                const int sg = s0 + 16 * nb + col;
#pragma unroll
                for (int r = 0; r < 4; ++r) {
                    bf16 pb_ = __float2bfloat16(__expf(S[nb][r]));
                    pT[wv][quad * 4 + r][16 * nb + col] = pb_;
                    int dd = sg - (t0w + quad * 4 + r) + WINn;
                    if ((unsigned)dd <= 2u * WINn) pdg[wv][quad * 4 + r][dd] = pb_;
                }
            }
        } else {
#pragma unroll
            for (int nb = 0; nb < 4; ++nb)
#pragma unroll
                for (int r = 0; r < 4; ++r)
                    pT[wv][quad * 4 + r][16 * nb + col] =
                        __float2bfloat16(__expf(S[nb][r]));
        }

        short8 aP[2];
#pragma unroll
        for (int kk = 0; kk < 2; ++kk)
            aP[kk] = *(const short8*)&pT[wv][col][kk * 32 + quad * 8];
        __builtin_amdgcn_s_setprio(1);
#pragma unroll
        for (int nd = 0; nd < 6; ++nd)
#pragma unroll
            for (int kk = 0; kk < 2; ++kk) {
                short8 bvf = *(const short8*)&Vs[16 * nd + col][kk * 32 + quad * 8];
                O[nd] = __builtin_amdgcn_mfma_f32_16x16x32_bf16(aP[kk], bvf, O[nd], 0, 0, 0);
            }
#pragma unroll
        for (int kk = 0; kk < 2; ++kk)
            Osum = __builtin_amdgcn_mfma_f32_16x16x32_bf16(aP[kk], ones, Osum, 0, 0, 0);
        __builtin_amdgcn_s_setprio(0);

        __syncthreads();
        if (nxt) {
            *(short8*)&Ks[rK[0]][cK[0]] = kst[0];
            *(short8*)&Vs[rV[0]][cV[0]] = vst[0];
            if (g2) {
                *(short8*)&Ks[rK[1]][cK[1]] = kst[1];
                *(short8*)&Vs[rV[1]][cV[1]] = vst[1];
            }
            __syncthreads();
        }
    }

    // rel-V band contribution: O += pdg(16x16, k 9..15 zero) . ERVB(k x 96)
    {
        short8 ad = {0, 0, 0, 0, 0, 0, 0, 0};
        if (quad < 2) ad = *(const short8*)&pdg[wv][col][quad * 8];
        const bf16* eb = ervb + (size_t)layer * 96 * 32 + (size_t)col * 32 + quad * 8;
#pragma unroll
        for (int nd = 0; nd < 6; ++nd) {
            short8 bd = *(const short8*)(eb + (size_t)nd * 16 * 32);
            O[nd] = __builtin_amdgcn_mfma_f32_16x16x32_bf16(ad, bd, O[nd], 0, 0, 0);
        }
    }

    // epilogue: write unnormalized partials (Lp row-sums come from Osum)
    const int rbase = (b * Hn + h) * Tn + t0w;
#pragma unroll
    for (int r = 0; r < 4; ++r) {
        const int rid = rbase + quad * 4 + r;
        bf16* dst = Op + ((size_t)sp * RN + rid) * 96 + col;
#pragma unroll
        for (int nd = 0; nd < 6; ++nd)
            dst[16 * nd] = __float2bfloat16(O[nd][r]);
        if (col == 0) Lp[sp * RN + rid] = Osum[r];
    }
}

// ---------------------------------------------------------------------------
extern "C" void kernel_launch(void* const* d_in, const int* in_sizes, int n_in,
                              void* d_out, int out_size, void* d_ws, size_t ws_size,
                              hipStream_t stream) {
    const float* x    = (const float*)d_in[0];
    const float* mask = (const float*)d_in[1];
    const float* Wq   = (const float*)d_in[2];
    const float* bq   = (const float*)d_in[3];
    const float* Wk   = (const float*)d_in[4];
    const float* bk   = (const float*)d_in[5];
    const float* Wv   = (const float*)d_in[6];
    const float* bv   = (const float*)d_in[7];
    const float* Wo   = (const float*)d_in[8];
    const float* bo   = (const float*)d_in[9];
    const float* erk  = (const float*)d_in[10];
    const float* erv  = (const float*)d_in[11];
    const float* ln1g = (const float*)d_in[12];
    const float* ln1b = (const float*)d_in[13];
    const float* w1   = (const float*)d_in[14];
    const float* b1   = (const float*)d_in[15];
    const float* w2   = (const float*)d_in[16];
    const float* b2   = (const float*)d_in[17];
    const float* ln2g = (const float*)d_in[18];
    const float* ln2b = (const float*)d_in[19];

    const size_t N = (size_t)Bn * Cn * Tn;         // 1,572,864
    const int WC = Ln * Cn * Cn;                   // 221,184
    const size_t WF = (size_t)Ln * 3 * FCn * Cn;   // 2,654,208
    const size_t WQKV = (size_t)Ln * 576 * Cn;     // 663,552
    const size_t NSCR = (size_t)Bn * Tn * FCn;     // 6,291,456 == NSPLIT*RN*96

    float* X    = (float*)d_ws;
    float* Yb   = X + N;                           // (unused since R7)
    float* bqkv = Yb + N;                          // L*576 floats
    float* Lp   = bqkv + Ln * 576;                 // NSPLIT*RN floats
    bf16* p16 = (bf16*)(Lp + (size_t)NSPLIT * RN);
    bf16* XT   = p16; p16 += N;
    bf16* QKT  = p16; p16 += (size_t)Bn * Tn * QKS;  // 2N bf16; dead after attn
    bf16* Vb   = p16; p16 += N;
    bf16* AT   = p16; p16 += N;      // (unused; kept for layout)
    bf16* SCR  = p16; p16 += NSCR;   // shared: attn O-partials <-> FFN hidden
    bf16* Wqkv = p16; p16 += WQKV;
    bf16* Wob  = p16; p16 += WC;
    bf16* W1t  = p16; p16 += WF;
    bf16* W2t  = p16; p16 += WF;
    bf16* ERKB = p16; p16 += Ln * 16 * 96;
    bf16* ERVB = p16; p16 += Ln * 96 * 32;
    (void)AT; (void)Yb;

    const float qscale = 0.10206207261596575f;  // 1/sqrt(96)

    // one-time transforms: single fused dispatch
    const size_t nprep = WQKV + Ln * 576 + WC + 2 * WF +
                         (size_t)Ln * 16 * 96 + (size_t)Ln * 96 * 32;
    prep_all<<<(int)((nprep + 255) / 256), 256, 0, stream>>>(
        Wq, Wk, Wv, bq, bk, bv, Wo, w1, w2, erk, erv,
        Wqkv, bqkv, Wob, W1t, W2t, ERKB, ERVB, qscale);
    cvt_in_k<<<Bn * 32, 256, 0, stream>>>(x, mask, X, XT);

    for (int l = 0; l < Ln; ++l) {
        conv_mfma<1, 128, 4, 1><<<dim3(Tn / 128, 9, Bn), 256, 0, stream>>>(
            XT, Wqkv + (size_t)l * 576 * Cn, bqkv + l * 576, nullptr, QKT, Vb, Cn, 576);
        attn_mfma<<<dim3(512), 512, 0, stream>>>(
            QKT, Vb, mask, ERKB, ERVB, SCR, Lp, l);
        // fused: split-combine + Wo conv + residual + LN1 + X/XT write
        wo_ln_k<<<256, 512, 0, stream>>>(
            SCR, Lp, Wob + (size_t)l * Cn * Cn, bo + l * Cn,
            X, ln1g + l * Cn, ln1b + l * Cn, mask, XT);
        conv_mfma<3, 128, 2, 1><<<dim3(Tn / 128, FCn / 64, Bn), 256, 0, stream>>>(
            XT, W1t + (size_t)l * 3 * FCn * Cn, b1 + l * FCn, mask, SCR, nullptr, Cn, FCn);
        // fused: FFN2 conv + mask + residual + LN2 + X/XT (or OUT) write
        ffn2_ln<<<256, 512, 0, stream>>>(
            SCR, W2t + (size_t)l * 3 * Cn * FCn, b2 + l * Cn,
            X, ln2g + l * Cn, ln2b + l * Cn, mask, XT,
            (l == Ln - 1) ? (float*)d_out : nullptr);
    }
}

// Round 9
// 601.756 us; speedup vs baseline: 1.9193x; 1.0188x over previous
//
#include <hip/hip_runtime.h>
#include <hip/hip_bf16.h>

// Problem constants
constexpr int Bn  = 8;
constexpr int Cn  = 192;   // hidden channels
constexpr int Tn  = 1024;  // sequence length
constexpr int Hn  = 2;     // heads
constexpr int DKn = 96;    // head dim
constexpr int FCn = 768;   // filter channels
constexpr int Ln  = 6;     // layers
constexpr int WINn = 4;    // rel-attn window
constexpr int QKS = 384;   // QK transposed row stride (Q|K concat)
constexpr int NSPLIT = 4;  // attention s-split (flash-decoding)
constexpr int RN  = Bn * Hn * Tn;  // 16384 attention rows

typedef __hip_bfloat16 bf16;
typedef __attribute__((ext_vector_type(8))) short short8;
typedef __attribute__((ext_vector_type(4))) float f32x4;

// ---------------------------------------------------------------------------
// One-time weight transforms in a single grid-stride kernel (R6).
__global__ void prep_all(
        const float* __restrict__ Wq, const float* __restrict__ Wk,
        const float* __restrict__ Wv, const float* __restrict__ bq,
        const float* __restrict__ bk, const float* __restrict__ bv,
        const float* __restrict__ Wo, const float* __restrict__ w1,
        const float* __restrict__ w2, const float* __restrict__ erk,
        const float* __restrict__ erv,
        bf16* __restrict__ Wqkv, float* __restrict__ bqkv,
        bf16* __restrict__ Wob, bf16* __restrict__ W1t, bf16* __restrict__ W2t,
        bf16* __restrict__ ERKB, bf16* __restrict__ ERVB, float qscale) {
    size_t i = (size_t)blockIdx.x * 256 + threadIdx.x;
    const size_t nW  = (size_t)Ln * 576 * Cn;     // 663,552
    const size_t nB  = (size_t)Ln * 576;
    const size_t WCn = (size_t)Ln * Cn * Cn;      // 221,184
    const size_t WFn = (size_t)Ln * 3 * FCn * Cn; // 2,654,208
    if (i < nW) {        // fused QKV weight (qscale folded into Q)
        int c = i % Cn, f = (i / Cn) % 576, l = i / (Cn * 576);
        float v;
        if (f < 192)      v = Wq[((size_t)l * Cn + f) * Cn + c] * qscale;
        else if (f < 384) v = Wk[((size_t)l * Cn + f - 192) * Cn + c];
        else              v = Wv[((size_t)l * Cn + f - 384) * Cn + c];
        Wqkv[i] = __float2bfloat16(v);
        return;
    }
    i -= nW;
    if (i < nB) {        // fused QKV bias
        int f = i % 576, l = i / 576;
        float v;
        if (f < 192)      v = bq[l * Cn + f] * qscale;
        else if (f < 384) v = bk[l * Cn + f - 192];
        else              v = bv[l * Cn + f - 384];
        bqkv[i] = v;
        return;
    }
    i -= nB;
    if (i < WCn) {       // Wo cast
        Wob[i] = __float2bfloat16(Wo[i]);
        return;
    }
    i -= WCn;
    if (i < WFn) {       // w1 [L][FC][C][3] -> [L][3][FC][C]
        int c = i % Cn;
        int f = (i / Cn) % FCn;
        int ko = (i / (Cn * FCn)) % 3;
        int l = i / (3 * Cn * FCn);
        W1t[i] = __float2bfloat16(w1[(((size_t)(l * FCn + f)) * Cn + c) * 3 + ko]);
        return;
    }
    i -= WFn;
    if (i < WFn) {       // w2 [L][C][FC][3] -> [L][3][C][FC]
        int c = i % FCn;
        int f = (i / FCn) % Cn;
        int ko = (i / (FCn * Cn)) % 3;
        int l = i / (3 * FCn * Cn);
        W2t[i] = __float2bfloat16(w2[(((size_t)(l * Cn + f)) * FCn + c) * 3 + ko]);
        return;
    }
    i -= WFn;
    if (i < (size_t)Ln * 16 * 96) {   // erk -> [L][16][96], rows 9..15 zero
        int d = i % 96, row = (i / 96) % 16, l = i / (96 * 16);
        float v = (row < 9) ? erk[((size_t)l * 9 + row) * 96 + d] : 0.f;
        ERKB[i] = __float2bfloat16(v);
        return;
    }
    i -= (size_t)Ln * 16 * 96;
    if (i < (size_t)Ln * 96 * 32) {   // erv -> [L][96][32] transposed, k 9..31 zero
        int k = i & 31, d = (i >> 5) % 96, l = i / (96 * 32);
        float v = (k < 9) ? erv[((size_t)l * 9 + k) * 96 + d] : 0.f;
        ERVB[i] = __float2bfloat16(v);
    }
}

// ---------------------------------------------------------------------------
// Input: X = x*mask (fp32, NCT) + XT = bf16 transposed [b][t][c]
__global__ __launch_bounds__(256) void cvt_in_k(
        const float* __restrict__ x, const float* __restrict__ mask,
        float* __restrict__ X, bf16* __restrict__ XT) {
    __shared__ float tile[Cn][33];
    const int tid = threadIdx.x, lane = tid & 31, w = tid >> 5;
    const int b = blockIdx.x >> 5;
    const int t0 = (blockIdx.x & 31) * 32;
    const float mk = mask[b * Tn + t0 + lane];
    for (int c = w; c < Cn; c += 8) {
        float v = x[((b * Cn + c) * Tn) + t0 + lane] * mk;
        X[((b * Cn + c) * Tn) + t0 + lane] = v;
        tile[c][lane] = v;
    }
    __syncthreads();
    for (int idx = tid; idx < 32 * Cn; idx += 256) {
        int tl = idx / Cn, c = idx % Cn;
        XT[((size_t)b * Tn + t0 + tl) * Cn + c] = __float2bfloat16(tile[c][tl]);
    }
}

// ---------------------------------------------------------------------------
// MFMA conv1d, LDS-staged, TT=128 for K-heavy convs, T14 async-STAGE (R4).
// MODE 2: bf16 transposed [b][t][CO] out relu(+bias)*mask   [FFN1]
// MODE 4: QKV split: f<384 -> bf16 T (stride QKS) into Y0; else bf16 NCT Y1
//         (used only for layer 0; layers 1..5 get QKV from ffn2_ln_qkv)
template <int KS, int TT, int MODE, int NSP>
__global__ __launch_bounds__(256) void conv_mfma(
        const bf16* __restrict__ Xt, const bf16* __restrict__ W,
        const float* __restrict__ bias, const float* __restrict__ mask,
        void* __restrict__ Y0, void* __restrict__ Y1, int CIN, int CO) {
    constexpr int PAD = KS / 2;
    constexpr int NMB = TT / 16;
    constexpr int AR  = TT + KS - 1;        // A rows staged
    constexpr int RS  = 72;                 // padded row stride (bf16 cols)
    constexpr int NA  = (AR * 8 + 255) / 256;  // per-thread A short8 loads
    constexpr int NB  = KS * 2;                // per-thread B short8 loads
    __shared__ bf16 As[AR][RS];
    __shared__ bf16 Bs[KS][64][RS];

    const int tid = threadIdx.x;
    const int wv = tid >> 6, lane = tid & 63;
    const int m = lane & 15, kq = lane >> 4;
    const int b = blockIdx.z / NSP, ks = blockIdx.z % NSP;
    const int t0 = blockIdx.x * TT;
    const int f0 = blockIdx.y * 64;
    const int f = f0 + wv * 16 + m;

    const bf16* xb = Xt + (size_t)b * Tn * CIN;
    const size_t wko = (size_t)CO * CIN;

    int rA[NA], cA[NA];
    bool vA[NA];
#pragma unroll
    for (int i = 0; i < NA; ++i) {
        int s = tid + i * 256;
        rA[i] = s >> 3; cA[i] = (s & 7) * 8; vA[i] = (s < AR * 8);
    }
    int rB[NB], cB[NB], koB[NB];
#pragma unroll
    for (int i = 0; i < NB; ++i) {
        int s = tid + i * 256;          // always < KS*512
        koB[i] = s >> 9; rB[i] = (s >> 3) & 63; cB[i] = (s & 7) * 8;
    }

    short8 pa[NA], pb[NB];
    const int cbeg = ks * (CIN / NSP);
    const int cend = cbeg + CIN / NSP;

    auto issue = [&](int c0) {
#pragma unroll
        for (int i = 0; i < NA; ++i) {
            short8 v = {0, 0, 0, 0, 0, 0, 0, 0};
            if (vA[i]) {
                int gt = t0 + rA[i] - PAD;
                if (PAD == 0 || (unsigned)gt < (unsigned)Tn)
                    v = *(const short8*)(xb + (size_t)gt * CIN + c0 + cA[i]);
            }
            pa[i] = v;
        }
#pragma unroll
        for (int i = 0; i < NB; ++i)
            pb[i] = *(const short8*)(W + (size_t)koB[i] * wko +
                                     (size_t)(f0 + rB[i]) * CIN + c0 + cB[i]);
    };
    auto commit = [&]() {
#pragma unroll
        for (int i = 0; i < NA; ++i)
            if (vA[i]) *(short8*)&As[rA[i]][cA[i]] = pa[i];
#pragma unroll
        for (int i = 0; i < NB; ++i)
            *(short8*)&Bs[koB[i]][rB[i]][cB[i]] = pb[i];
    };

    f32x4 acc[NMB] = {};

    issue(cbeg);
    commit();
    __syncthreads();

    for (int c0 = cbeg; c0 < cend; c0 += 64) {
        const bool nxt = (c0 + 64 < cend);
        if (nxt) issue(c0 + 64);
#pragma unroll
        for (int kk = 0; kk < 2; ++kk)
#pragma unroll
            for (int ko = 0; ko < KS; ++ko) {
                short8 bfr = *(const short8*)&Bs[ko][wv * 16 + m][kk * 32 + kq * 8];
#pragma unroll
                for (int mb = 0; mb < NMB; ++mb) {
                    short8 afr = *(const short8*)&As[mb * 16 + m + ko][kk * 32 + kq * 8];
                    acc[mb] = __builtin_amdgcn_mfma_f32_16x16x32_bf16(afr, bfr, acc[mb], 0, 0, 0);
                }
            }
        if (nxt) {
            __syncthreads();   // all fragment reads of this chunk complete
            commit();
            __syncthreads();   // staged data visible
        }
    }

    const float bs = bias[f];
    if (MODE == 2) {
        bf16* Y = (bf16*)Y0;
#pragma unroll
        for (int mb = 0; mb < NMB; ++mb)
#pragma unroll
            for (int r = 0; r < 4; ++r) {
                int t = t0 + mb * 16 + kq * 4 + r;
                float v = fmaxf(acc[mb][r] + bs, 0.f) * mask[b * Tn + t];
                Y[((size_t)b * Tn + t) * CO + f] = __float2bfloat16(v);
            }
    } else {  // MODE 4
        if (blockIdx.y < 6) {          // Q|K -> transposed, stride QKS
            bf16* Y = (bf16*)Y0;
#pragma unroll
            for (int mb = 0; mb < NMB; ++mb)
#pragma unroll
                for (int r = 0; r < 4; ++r) {
                    int t = t0 + mb * 16 + kq * 4 + r;
                    Y[((size_t)b * Tn + t) * QKS + f] = __float2bfloat16(acc[mb][r] + bs);
                }
        } else {                        // V -> bf16 NCT
            bf16* Y = (bf16*)Y1 + ((size_t)b * Cn + f - 384) * Tn;
#pragma unroll
            for (int mb = 0; mb < NMB; ++mb) {
                int t = t0 + mb * 16 + kq * 4;
                bf16 tmp[4];
#pragma unroll
                for (int r = 0; r < 4; ++r) tmp[r] = __float2bfloat16(acc[mb][r] + bs);
                *(uint2*)(Y + t) = *(uint2*)tmp;
            }
        }
    }
}

// ---------------------------------------------------------------------------
// R8: wo_ln_k at 512 threads / 8 waves (2 waves/SIMD). Waves map as
// 4 f-groups (48 ch) x 2 t-groups (16 rows); per-wave acc[3].
__global__ __launch_bounds__(512) void wo_ln_k(
        const bf16* __restrict__ Op, const float* __restrict__ Lp,
        const bf16* __restrict__ W, const float* __restrict__ bias,
        float* __restrict__ X, const float* __restrict__ G,
        const float* __restrict__ Bt, const float* __restrict__ mask,
        bf16* __restrict__ XT) {
    __shared__ bf16 As[32][72];       // combined attn out [t][c-chunk]
    __shared__ bf16 Bs[192][72];      // Wo panel [f][c-chunk]
    __shared__ float sm1[8][16];
    __shared__ float sm2[8][16];

    const int tid = threadIdx.x;
    const int wv = tid >> 6, lane = tid & 63;
    const int m = lane & 15, quad = lane >> 4;
    const int fg = wv & 3, tg = wv >> 2;
    const int b = blockIdx.x & 7;
    const int t0 = (blockIdx.x >> 3) * 32;

    const bool vA = (tid < 256);
    const int rA = tid >> 3, cA = (tid & 7) * 8;   // A: 32 rows x 8 short8
    short8 pa6[4]; float pl6[4];
    short8 pb[3];                                   // B: 1536 short8 / 512

    auto issue = [&](int c0) {
        if (vA) {
            int c = c0 + cA;
            int hh = (c >= 96) ? 1 : 0;
            int rid = (b * Hn + hh) * Tn + t0 + rA;
            int d0 = c - 96 * hh;
#pragma unroll
            for (int sp = 0; sp < 4; ++sp) {
                pa6[sp] = *(const short8*)(Op + ((size_t)sp * RN + rid) * 96 + d0);
                pl6[sp] = Lp[sp * RN + rid];
            }
        }
#pragma unroll
        for (int i = 0; i < 3; ++i) {
            int s = tid + i * 512;
            pb[i] = *(const short8*)(W + (size_t)(s >> 3) * Cn + c0 + (s & 7) * 8);
        }
    };
    auto commit = [&]() {
        if (vA) {
            float denom = pl6[0] + pl6[1] + pl6[2] + pl6[3];
            float inv = 1.f / fmaxf(denom, 1e-30f);
            bf16 tmp[8];
#pragma unroll
            for (int e = 0; e < 8; ++e) {
                float o = 0.f;
#pragma unroll
                for (int sp = 0; sp < 4; ++sp)
                    o += __bfloat162float(((const bf16*)&pa6[sp])[e]);
                tmp[e] = __float2bfloat16(o * inv);
            }
            *(short8*)&As[rA][cA] = *(const short8*)tmp;
        }
#pragma unroll
        for (int i = 0; i < 3; ++i) {
            int s = tid + i * 512;
            *(short8*)&Bs[s >> 3][(s & 7) * 8] = pb[i];
        }
    };

    f32x4 acc[3] = {};

    issue(0);
    commit();
    __syncthreads();
    for (int c0 = 0; c0 < Cn; c0 += 64) {
        const bool nxt = (c0 + 64 < Cn);
        if (nxt) issue(c0 + 64);
#pragma unroll
        for (int kk = 0; kk < 2; ++kk) {
            short8 afr = *(const short8*)&As[tg * 16 + m][kk * 32 + quad * 8];
#pragma unroll
            for (int fb = 0; fb < 3; ++fb) {
                short8 bfr = *(const short8*)&Bs[fg * 48 + fb * 16 + m][kk * 32 + quad * 8];
                acc[fb] = __builtin_amdgcn_mfma_f32_16x16x32_bf16(afr, bfr, acc[fb], 0, 0, 0);
            }
        }
        if (nxt) {
            __syncthreads();
            commit();
            __syncthreads();
        }
    }

    // bias + residual; per-t LN stats over this lane's 3 channels
    const int tq = t0 + tg * 16 + quad * 4;
    float s1[4] = {}, s2[4] = {};
#pragma unroll
    for (int fb = 0; fb < 3; ++fb) {
        const int f = fg * 48 + fb * 16 + m;
        const float bsv = bias[f];
        float4 xv = *(const float4*)(X + ((size_t)(b * Cn + f)) * Tn + tq);
        acc[fb][0] += bsv + xv.x;
        acc[fb][1] += bsv + xv.y;
        acc[fb][2] += bsv + xv.z;
        acc[fb][3] += bsv + xv.w;
#pragma unroll
        for (int r = 0; r < 4; ++r) {
            float v = acc[fb][r];
            s1[r] += v;
            s2[r] += v * v;
        }
    }
#pragma unroll
    for (int r = 0; r < 4; ++r)
#pragma unroll
        for (int mk = 1; mk < 16; mk <<= 1) {
            s1[r] += __shfl_xor(s1[r], mk);
            s2[r] += __shfl_xor(s2[r], mk);
        }
    if (m == 0) {
#pragma unroll
        for (int r = 0; r < 4; ++r) {
            sm1[wv][quad * 4 + r] = s1[r];
            sm2[wv][quad * 4 + r] = s2[r];
        }
    }
    __syncthreads();
    float mean[4], rsv[4];
    float4 mk4 = *(const float4*)(mask + b * Tn + tq);
    float mtv[4] = {mk4.x, mk4.y, mk4.z, mk4.w};
#pragma unroll
    for (int r = 0; r < 4; ++r) {
        int tt = quad * 4 + r;
        float a = sm1[tg * 4 + 0][tt] + sm1[tg * 4 + 1][tt] +
                  sm1[tg * 4 + 2][tt] + sm1[tg * 4 + 3][tt];
        float q = sm2[tg * 4 + 0][tt] + sm2[tg * 4 + 1][tt] +
                  sm2[tg * 4 + 2][tt] + sm2[tg * 4 + 3][tt];
        float mn = a / Cn;
        mean[r] = mn;
        rsv[r] = rsqrtf(q / Cn - mn * mn + 1e-5f);
    }
#pragma unroll
    for (int fb = 0; fb < 3; ++fb) {
        const int f = fg * 48 + fb * 16 + m;
        const float gv = G[f], bv = Bt[f];
        float y[4];
#pragma unroll
        for (int r = 0; r < 4; ++r)
            y[r] = (acc[fb][r] - mean[r]) * rsv[r] * gv + bv;
        float4 xo;
        xo.x = y[0]; xo.y = y[1]; xo.z = y[2]; xo.w = y[3];
        *(float4*)(X + ((size_t)(b * Cn + f)) * Tn + tq) = xo;
#pragma unroll
        for (int r = 0; r < 4; ++r)
            XT[((size_t)b * Tn + tq + r) * Cn + f] =
                __float2bfloat16(y[r] * mtv[r]);
    }
}

// ---------------------------------------------------------------------------
// R9: ffn2_ln_qkv — FFN2 conv + mask + residual + LN2, then (fused) the
// NEXT layer's QKV 1x1 conv straight from the in-register LN2 output:
// y -> Ys LDS tile [32][192], Bs reused as the Wqkv panel (identical 83 KB
// footprint; safe after the LN barrier), 32x576x192 MFMA, writes QKT/Vb
// exactly as conv MODE 4 did. Kills the standalone QKV dispatch and the
// XT round-trip (XT-from-ffn2's only consumer was QKV).
// Last layer (OUT != null): write OUT and exit before phase 2.
__global__ __launch_bounds__(512) void ffn2_ln_qkv(
        const bf16* __restrict__ Hc, const bf16* __restrict__ W,
        const float* __restrict__ bias, float* __restrict__ X,
        const float* __restrict__ G, const float* __restrict__ Bt,
        const float* __restrict__ mask,
        const bf16* __restrict__ Wqn, const float* __restrict__ bqn,
        bf16* __restrict__ QKT, bf16* __restrict__ Vb,
        float* __restrict__ OUT) {
    __shared__ bf16 As[34][72];        // hidden rows t0-1..t0+32, c-chunk
    __shared__ bf16 Bs[3][192][72];    // W2 panel [ko][f][c-chunk] (~83 KB)
    __shared__ float sm1[8][16];
    __shared__ float sm2[8][16];
    __shared__ bf16 Ys[32][200];       // LN2 output tile [t][c] (phase 2 A)

    const int tid = threadIdx.x;
    const int wv = tid >> 6, lane = tid & 63;
    const int m = lane & 15, quad = lane >> 4;
    const int fg = wv & 3, tg = wv >> 2;
    const int b = blockIdx.x & 7;
    const int t0 = (blockIdx.x >> 3) * 32;

    const bf16* hb = Hc + (size_t)b * Tn * FCn;

    const bool vA = (tid < 272);
    short8 pa, pb[9];
    auto issue = [&](int c0) {
        short8 v = {0, 0, 0, 0, 0, 0, 0, 0};
        if (vA) {
            int gt = t0 + (tid >> 3) - 1;
            if ((unsigned)gt < (unsigned)Tn)
                v = *(const short8*)(hb + (size_t)gt * FCn + c0 + (tid & 7) * 8);
        }
        pa = v;
#pragma unroll
        for (int i = 0; i < 9; ++i) {
            int s = tid + i * 512;           // < 4608 = 3*192*8
            int ko = s / 1536, rem = s - ko * 1536;
            pb[i] = *(const short8*)(W + (size_t)ko * Cn * FCn +
                                     (size_t)(rem >> 3) * FCn + c0 + (rem & 7) * 8);
        }
    };
    auto commit = [&]() {
        if (vA) *(short8*)&As[tid >> 3][(tid & 7) * 8] = pa;
#pragma unroll
        for (int i = 0; i < 9; ++i) {
            int s = tid + i * 512;
            int ko = s / 1536, rem = s - ko * 1536;
            *(short8*)&Bs[ko][rem >> 3][(rem & 7) * 8] = pb[i];
        }
    };

    f32x4 acc[3] = {};

    issue(0);
    commit();
    __syncthreads();
    for (int c0 = 0; c0 < FCn; c0 += 64) {
        const bool nxt = (c0 + 64 < FCn);
        if (nxt) issue(c0 + 64);
#pragma unroll
        for (int kk = 0; kk < 2; ++kk)
#pragma unroll
            for (int ko = 0; ko < 3; ++ko) {
                short8 afr = *(const short8*)&As[tg * 16 + m + ko][kk * 32 + quad * 8];
#pragma unroll
                for (int fb = 0; fb < 3; ++fb) {
                    short8 bfr = *(const short8*)&Bs[ko][fg * 48 + fb * 16 + m][kk * 32 + quad * 8];
                    acc[fb] = __builtin_amdgcn_mfma_f32_16x16x32_bf16(afr, bfr, acc[fb], 0, 0, 0);
                }
            }
        if (nxt) {
            __syncthreads();
            commit();
            __syncthreads();
        }
    }

    // y = (conv + bias)*mask; v = X + y; LN stats over channels
    const int tq = t0 + tg * 16 + quad * 4;
    float4 mk4 = *(const float4*)(mask + b * Tn + tq);
    float mtv[4] = {mk4.x, mk4.y, mk4.z, mk4.w};
    float s1[4] = {}, s2[4] = {};
#pragma unroll
    for (int fb = 0; fb < 3; ++fb) {
        const int f = fg * 48 + fb * 16 + m;
        const float bsv = bias[f];
        float4 xv = *(const float4*)(X + ((size_t)(b * Cn + f)) * Tn + tq);
        acc[fb][0] = xv.x + (acc[fb][0] + bsv) * mtv[0];
        acc[fb][1] = xv.y + (acc[fb][1] + bsv) * mtv[1];
        acc[fb][2] = xv.z + (acc[fb][2] + bsv) * mtv[2];
        acc[fb][3] = xv.w + (acc[fb][3] + bsv) * mtv[3];
#pragma unroll
        for (int r = 0; r < 4; ++r) {
            float v = acc[fb][r];
            s1[r] += v;
            s2[r] += v * v;
        }
    }
#pragma unroll
    for (int r = 0; r < 4; ++r)
#pragma unroll
        for (int mk = 1; mk < 16; mk <<= 1) {
            s1[r] += __shfl_xor(s1[r], mk);
            s2[r] += __shfl_xor(s2[r], mk);
        }
    if (m == 0) {
#pragma unroll
        for (int r = 0; r < 4; ++r) {
            sm1[wv][quad * 4 + r] = s1[r];
            sm2[wv][quad * 4 + r] = s2[r];
        }
    }
    __syncthreads();   // [E1] also: all Bs/As MFMA reads are now complete
    float mean[4], rsv[4];
#pragma unroll
    for (int r = 0; r < 4; ++r) {
        int tt = quad * 4 + r;
        float a = sm1[tg * 4 + 0][tt] + sm1[tg * 4 + 1][tt] +
                  sm1[tg * 4 + 2][tt] + sm1[tg * 4 + 3][tt];
        float q = sm2[tg * 4 + 0][tt] + sm2[tg * 4 + 1][tt] +
                  sm2[tg * 4 + 2][tt] + sm2[tg * 4 + 3][tt];
        float mn = a / Cn;
        mean[r] = mn;
        rsv[r] = rsqrtf(q / Cn - mn * mn + 1e-5f);
    }

    float y3[3][4];
#pragma unroll
    for (int fb = 0; fb < 3; ++fb) {
        const int f = fg * 48 + fb * 16 + m;
        const float gv = G[f], bv = Bt[f];
#pragma unroll
        for (int r = 0; r < 4; ++r)
            y3[fb][r] = (acc[fb][r] - mean[r]) * rsv[r] * gv + bv;
    }

    if (OUT) {      // final layer: OUT = LN(...)*mask, NCT fp32; no QKV
#pragma unroll
        for (int fb = 0; fb < 3; ++fb) {
            const int f = fg * 48 + fb * 16 + m;
            float4 xo;
            xo.x = y3[fb][0] * mtv[0]; xo.y = y3[fb][1] * mtv[1];
            xo.z = y3[fb][2] * mtv[2]; xo.w = y3[fb][3] * mtv[3];
            *(float4*)(OUT + ((size_t)(b * Cn + f)) * Tn + tq) = xo;
        }
        return;
    }

    // write X (residual stream for next layer's wo_ln_k)
#pragma unroll
    for (int fb = 0; fb < 3; ++fb) {
        const int f = fg * 48 + fb * 16 + m;
        float4 xo;
        xo.x = y3[fb][0]; xo.y = y3[fb][1]; xo.z = y3[fb][2]; xo.w = y3[fb][3];
        *(float4*)(X + ((size_t)(b * Cn + f)) * Tn + tq) = xo;
    }

    // ---- phase 2: QKV 1x1 conv for the NEXT layer ----
    bf16 (*Bq)[72] = (bf16 (*)[72])Bs;   // 576 rows x 72 — same footprint

    short8 pbq[9];
    auto issueQ = [&](int c0) {
#pragma unroll
        for (int i = 0; i < 9; ++i) {
            int s = tid + i * 512;           // < 4608 = 576*8
            pbq[i] = *(const short8*)(Wqn + (size_t)(s >> 3) * Cn + c0 + (s & 7) * 8);
        }
    };
    auto commitQ = [&]() {
#pragma unroll
        for (int i = 0; i < 9; ++i) {
            int s = tid + i * 512;
            *(short8*)&Bq[s >> 3][(s & 7) * 8] = pbq[i];
        }
    };

    issueQ(0);
    // drop y (unmasked, matching old XT semantics) into the LDS A-tile
#pragma unroll
    for (int fb = 0; fb < 3; ++fb) {
        const int f = fg * 48 + fb * 16 + m;
#pragma unroll
        for (int r = 0; r < 4; ++r)
            Ys[tg * 16 + quad * 4 + r][f] = __float2bfloat16(y3[fb][r]);
    }
    commitQ();           // safe: all Bs reads precede [E1]
    __syncthreads();     // Ys + Bq chunk 0 visible

    f32x4 acc2[9] = {};
    for (int c0 = 0; c0 < Cn; c0 += 64) {
        const bool nxt = (c0 + 64 < Cn);
        if (nxt) issueQ(c0 + 64);
#pragma unroll
        for (int kk = 0; kk < 2; ++kk) {
            short8 afr = *(const short8*)&Ys[tg * 16 + m][c0 + kk * 32 + quad * 8];
#pragma unroll
            for (int fb = 0; fb < 9; ++fb) {
                short8 bfr = *(const short8*)&Bq[fg * 144 + fb * 16 + m][kk * 32 + quad * 8];
                acc2[fb] = __builtin_amdgcn_mfma_f32_16x16x32_bf16(afr, bfr, acc2[fb], 0, 0, 0);
            }
        }
        if (nxt) {
            __syncthreads();
            commitQ();
            __syncthreads();
        }
    }

    // epilogue: QKT transposed (f<384) / Vb NCT (f>=384), bias added
#pragma unroll
    for (int fb = 0; fb < 9; ++fb) {
        const int f = fg * 144 + fb * 16 + m;
        const float bsv = bqn[f];
        if (f < 384) {
#pragma unroll
            for (int r = 0; r < 4; ++r)
                QKT[((size_t)b * Tn + tq + r) * QKS + f] =
                    __float2bfloat16(acc2[fb][r] + bsv);
        } else {
            bf16 tmp[4];
#pragma unroll
            for (int r = 0; r < 4; ++r) tmp[r] = __float2bfloat16(acc2[fb][r] + bsv);
            *(uint2*)(Vb + ((size_t)b * Cn + f - 384) * Tn + tq) = *(uint2*)tmp;
        }
    }
}

// ---------------------------------------------------------------------------
// MFMA flash attention. R8: 8 waves / QBLK=128 per block (512 threads,
// grid 512). XCD swizzle (R2), T14 async-STAGE (R2), rel-V via MFMA (R3),
// ones-MFMA rowsum + gating + setprio (R5). FIXED-MAX softmax.
// Writes UNNORMALIZED partials: Op bf16 [sp][rid][96], Lp fp32 [sp][rid].
__global__ __launch_bounds__(512) void attn_mfma(
        const bf16* __restrict__ QK, const bf16* __restrict__ V,
        const float* __restrict__ mask, const bf16* __restrict__ erkb,
        const bf16* __restrict__ ervb, bf16* __restrict__ Op,
        float* __restrict__ Lp, int layer) {
    __shared__ bf16 Ks[64][100];      // K chunk [s][d]
    __shared__ bf16 Vs[96][68];       // V chunk [d][s]
    __shared__ float rq[8][16][17];   // per-wave rel-K band: [m][dd]
    __shared__ bf16 pT[8][16][68];    // per-wave P: [m][s]
    __shared__ bf16 pdg[8][16][16];   // per-wave rel-V band: [m][dd], 9..15 zero
    // LDS total: 56064 B -> 2 blocks/CU

    const int tid = threadIdx.x, wv = tid >> 6, lane = tid & 63;
    const int col = lane & 15, quad = lane >> 4;
    // XCD-bijective swizzle (512 = 8 XCD x 64)
    const int w = (blockIdx.x & 7) * 64 + (blockIdx.x >> 3);
    const int t0 = (w & 7) * 128;
    const int yz = w >> 3;
    const int h = yz & 1;
    const int z = yz >> 1;
    const int b = z >> 2, sp = z & 3;
    const int hd = h * DKn;
    const int t0w = t0 + wv * 16;

    *(uint2*)&pdg[wv][col][quad * 4] = (uint2){0, 0};

    const bool g2 = (tid < 256);
    int rK[2], cK[2], rV[2], cV[2];
    {
        int s = tid;
        rK[0] = s / 12; cK[0] = (s % 12) * 8;   // 64 rows x 96 cols
        rV[0] = s >> 3; cV[0] = (s & 7) * 8;    // 96 rows x 64 cols
        s = tid + 512;
        rK[1] = s / 12; cK[1] = (s % 12) * 8;   // valid only if g2
        rV[1] = s >> 3; cV[1] = (s & 7) * 8;
    }
    const bf16* kbase = QK + (size_t)b * Tn * QKS + 192 + hd;
    const bf16* vbase = V + ((size_t)b * Cn + hd) * Tn;

    short8 kst[2], vst[2];
    const int sbeg = sp * (Tn / NSPLIT);
    const int send = sbeg + Tn / NSPLIT;

    kst[0] = *(const short8*)(kbase + (size_t)(sbeg + rK[0]) * QKS + cK[0]);
    vst[0] = *(const short8*)(vbase + (size_t)rV[0] * Tn + sbeg + cV[0]);
    if (g2) {
        kst[1] = *(const short8*)(kbase + (size_t)(sbeg + rK[1]) * QKS + cK[1]);
        vst[1] = *(const short8*)(vbase + (size_t)rV[1] * Tn + sbeg + cV[1]);
    }

    short8 aq[3];
    {
        const bf16* qrow = QK + ((size_t)b * Tn + t0w + col) * QKS + hd + quad * 8;
#pragma unroll
        for (int kd = 0; kd < 3; ++kd) aq[kd] = *(const short8*)(qrow + kd * 32);
    }
    {
        const bf16* erow = erkb + ((size_t)layer * 16 + col) * 96 + quad * 8;
        f32x4 R = {};
#pragma unroll
        for (int kd = 0; kd < 3; ++kd) {
            short8 be = *(const short8*)(erow + kd * 32);
            R = __builtin_amdgcn_mfma_f32_16x16x32_bf16(aq[kd], be, R, 0, 0, 0);
        }
#pragma unroll
        for (int r = 0; r < 4; ++r) rq[wv][quad * 4 + r][col] = R[r];
    }
    float mtv[4];
#pragma unroll
    for (int r = 0; r < 4; ++r) mtv[r] = mask[b * Tn + t0w + quad * 4 + r];
    const bool qok = __all(mtv[0] != 0.f && mtv[1] != 0.f &&
                           mtv[2] != 0.f && mtv[3] != 0.f);
    int okbits = 0;
    if (qok) {
#pragma unroll
        for (int ch = 0; ch < 4; ++ch) {
            int sc = b * Tn + sbeg + ch * 64 + col;
            float a0 = mask[sc], a1 = mask[sc + 16], a2 = mask[sc + 32], a3 = mask[sc + 48];
            if (__all(a0 != 0.f && a1 != 0.f && a2 != 0.f && a3 != 0.f))
                okbits |= 1 << ch;
        }
    }

    *(short8*)&Ks[rK[0]][cK[0]] = kst[0];
    *(short8*)&Vs[rV[0]][cV[0]] = vst[0];
    if (g2) {
        *(short8*)&Ks[rK[1]][cK[1]] = kst[1];
        *(short8*)&Vs[rV[1]][cV[1]] = vst[1];
    }
    __syncthreads();

    f32x4 O[6] = {};
    f32x4 Osum = {};
    short8 ones;
#pragma unroll
    for (int j = 0; j < 8; ++j) ones[j] = (short)0x3F80;   // bf16 1.0

    for (int s0 = sbeg; s0 < send; s0 += 64) {
        const bool nxt = (s0 + 64 < send);
        if (nxt) {
            kst[0] = *(const short8*)(kbase + (size_t)(s0 + 64 + rK[0]) * QKS + cK[0]);
            vst[0] = *(const short8*)(vbase + (size_t)rV[0] * Tn + s0 + 64 + cV[0]);
            if (g2) {
                kst[1] = *(const short8*)(kbase + (size_t)(s0 + 64 + rK[1]) * QKS + cK[1]);
                vst[1] = *(const short8*)(vbase + (size_t)rV[1] * Tn + s0 + 64 + cV[1]);
            }
        }

        f32x4 S[4] = {};
        __builtin_amdgcn_s_setprio(1);
#pragma unroll
        for (int nb = 0; nb < 4; ++nb)
#pragma unroll
            for (int kd = 0; kd < 3; ++kd) {
                short8 bkf = *(const short8*)&Ks[16 * nb + col][kd * 32 + quad * 8];
                S[nb] = __builtin_amdgcn_mfma_f32_16x16x32_bf16(aq[kd], bkf, S[nb], 0, 0, 0);
            }
        __builtin_amdgcn_s_setprio(0);

        const bool diag = (s0 <= t0w + 15 + WINn) && (s0 + 63 >= t0w - WINn);
        if (diag) {
#pragma unroll
            for (int nb = 0; nb < 4; ++nb) {
                const int sg = s0 + 16 * nb + col;
#pragma unroll
                for (int r = 0; r < 4; ++r) {
                    int dd = sg - (t0w + quad * 4 + r) + WINn;
                    if ((unsigned)dd <= 2u * WINn) S[nb][r] += rq[wv][quad * 4 + r][dd];
                }
            }
        }
        if (!((okbits >> ((s0 - sbeg) >> 6)) & 1)) {
#pragma unroll
            for (int nb = 0; nb < 4; ++nb) {
                const float msv = mask[b * Tn + s0 + 16 * nb + col];
#pragma unroll
                for (int r = 0; r < 4; ++r)
                    if (msv * mtv[r] == 0.f) S[nb][r] = -1e4f;
            }
        }

        if (diag) {
#pragma unroll
            for (int nb = 0; nb < 4; ++nb) {
                const int sg = s0 + 16 * nb + col;
#pragma unroll
                for (int r = 0; r < 4; ++r) {
                    bf16 pb_ = __float2bfloat16(__expf(S[nb][r]));
                    pT[wv][quad * 4 + r][16 * nb + col] = pb_;
                    int dd = sg - (t0w + quad * 4 + r) + WINn;
                    if ((unsigned)dd <= 2u * WINn) pdg[wv][quad * 4 + r][dd] = pb_;
                }
            }
        } else {
#pragma unroll
            for (int nb = 0; nb < 4; ++nb)
#pragma unroll
                for (int r = 0; r < 4; ++r)
                    pT[wv][quad * 4 + r][16 * nb + col] =
                        __float2bfloat16(__expf(S[nb][r]));
        }

        short8 aP[2];
#pragma unroll
        for (int kk = 0; kk < 2; ++kk)
            aP[kk] = *(const short8*)&pT[wv][col][kk * 32 + quad * 8];
        __builtin_amdgcn_s_setprio(1);
#pragma unroll
        for (int nd = 0; nd < 6; ++nd)
#pragma unroll
            for (int kk = 0; kk < 2; ++kk) {
                short8 bvf = *(const short8*)&Vs[16 * nd + col][kk * 32 + quad * 8];
                O[nd] = __builtin_amdgcn_mfma_f32_16x16x32_bf16(aP[kk], bvf, O[nd], 0, 0, 0);
            }
#pragma unroll
        for (int kk = 0; kk < 2; ++kk)
            Osum = __builtin_amdgcn_mfma_f32_16x16x32_bf16(aP[kk], ones, Osum, 0, 0, 0);
        __builtin_amdgcn_s_setprio(0);

        __syncthreads();
        if (nxt) {
            *(short8*)&Ks[rK[0]][cK[0]] = kst[0];
            *(short8*)&Vs[rV[0]][cV[0]] = vst[0];
            if (g2) {
                *(short8*)&Ks[rK[1]][cK[1]] = kst[1];
                *(short8*)&Vs[rV[1]][cV[1]] = vst[1];
            }
            __syncthreads();
        }
    }

    // rel-V band contribution: O += pdg(16x16, k 9..15 zero) . ERVB(k x 96)
    {
        short8 ad = {0, 0, 0, 0, 0, 0, 0, 0};
        if (quad < 2) ad = *(const short8*)&pdg[wv][col][quad * 8];
        const bf16* eb = ervb + (size_t)layer * 96 * 32 + (size_t)col * 32 + quad * 8;
#pragma unroll
        for (int nd = 0; nd < 6; ++nd) {
            short8 bd = *(const short8*)(eb + (size_t)nd * 16 * 32);
            O[nd] = __builtin_amdgcn_mfma_f32_16x16x32_bf16(ad, bd, O[nd], 0, 0, 0);
        }
    }

    // epilogue: write unnormalized partials (Lp row-sums come from Osum)
    const int rbase = (b * Hn + h) * Tn + t0w;
#pragma unroll
    for (int r = 0; r < 4; ++r) {
        const int rid = rbase + quad * 4 + r;
        bf16* dst = Op + ((size_t)sp * RN + rid) * 96 + col;
#pragma unroll
        for (int nd = 0; nd < 6; ++nd)
            dst[16 * nd] = __float2bfloat16(O[nd][r]);
        if (col == 0) Lp[sp * RN + rid] = Osum[r];
    }
}

// ---------------------------------------------------------------------------
extern "C" void kernel_launch(void* const* d_in, const int* in_sizes, int n_in,
                              void* d_out, int out_size, void* d_ws, size_t ws_size,
                              hipStream_t stream) {
    const float* x    = (const float*)d_in[0];
    const float* mask = (const float*)d_in[1];
    const float* Wq   = (const float*)d_in[2];
    const float* bq   = (const float*)d_in[3];
    const float* Wk   = (const float*)d_in[4];
    const float* bk   = (const float*)d_in[5];
    const float* Wv   = (const float*)d_in[6];
    const float* bv   = (const float*)d_in[7];
    const float* Wo   = (const float*)d_in[8];
    const float* bo   = (const float*)d_in[9];
    const float* erk  = (const float*)d_in[10];
    const float* erv  = (const float*)d_in[11];
    const float* ln1g = (const float*)d_in[12];
    const float* ln1b = (const float*)d_in[13];
    const float* w1   = (const float*)d_in[14];
    const float* b1   = (const float*)d_in[15];
    const float* w2   = (const float*)d_in[16];
    const float* b2   = (const float*)d_in[17];
    const float* ln2g = (const float*)d_in[18];
    const float* ln2b = (const float*)d_in[19];

    const size_t N = (size_t)Bn * Cn * Tn;         // 1,572,864
    const int WC = Ln * Cn * Cn;                   // 221,184
    const size_t WF = (size_t)Ln * 3 * FCn * Cn;   // 2,654,208
    const size_t WQKV = (size_t)Ln * 576 * Cn;     // 663,552
    const size_t NSCR = (size_t)Bn * Tn * FCn;     // 6,291,456 == NSPLIT*RN*96

    float* X    = (float*)d_ws;
    float* Yb   = X + N;                           // (unused since R7)
    float* bqkv = Yb + N;                          // L*576 floats
    float* Lp   = bqkv + Ln * 576;                 // NSPLIT*RN floats
    bf16* p16 = (bf16*)(Lp + (size_t)NSPLIT * RN);
    bf16* XT   = p16; p16 += N;
    bf16* QKT  = p16; p16 += (size_t)Bn * Tn * QKS;  // 2N bf16
    bf16* Vb   = p16; p16 += N;
    bf16* AT   = p16; p16 += N;      // (unused; kept for layout)
    bf16* SCR  = p16; p16 += NSCR;   // shared: attn O-partials <-> FFN hidden
    bf16* Wqkv = p16; p16 += WQKV;
    bf16* Wob  = p16; p16 += WC;
    bf16* W1t  = p16; p16 += WF;
    bf16* W2t  = p16; p16 += WF;
    bf16* ERKB = p16; p16 += Ln * 16 * 96;
    bf16* ERVB = p16; p16 += Ln * 96 * 32;
    (void)AT; (void)Yb;

    const float qscale = 0.10206207261596575f;  // 1/sqrt(96)

    // one-time transforms: single fused dispatch
    const size_t nprep = WQKV + Ln * 576 + WC + 2 * WF +
                         (size_t)Ln * 16 * 96 + (size_t)Ln * 96 * 32;
    prep_all<<<(int)((nprep + 255) / 256), 256, 0, stream>>>(
        Wq, Wk, Wv, bq, bk, bv, Wo, w1, w2, erk, erv,
        Wqkv, bqkv, Wob, W1t, W2t, ERKB, ERVB, qscale);
    cvt_in_k<<<Bn * 32, 256, 0, stream>>>(x, mask, X, XT);

    // layer 0's QKV from XT (standalone conv); layers 1..5 get QKV fused
    // into the previous layer's ffn2_ln_qkv.
    conv_mfma<1, 128, 4, 1><<<dim3(Tn / 128, 9, Bn), 256, 0, stream>>>(
        XT, Wqkv, bqkv, nullptr, QKT, Vb, Cn, 576);

    for (int l = 0; l < Ln; ++l) {
        attn_mfma<<<dim3(512), 512, 0, stream>>>(
            QKT, Vb, mask, ERKB, ERVB, SCR, Lp, l);
        // fused: split-combine + Wo conv + residual + LN1 + X/XT write
        wo_ln_k<<<256, 512, 0, stream>>>(
            SCR, Lp, Wob + (size_t)l * Cn * Cn, bo + l * Cn,
            X, ln1g + l * Cn, ln1b + l * Cn, mask, XT);
        conv_mfma<3, 128, 2, 1><<<dim3(Tn / 128, FCn / 64, Bn), 256, 0, stream>>>(
            XT, W1t + (size_t)l * 3 * FCn * Cn, b1 + l * FCn, mask, SCR, nullptr, Cn, FCn);
        // fused: FFN2 conv + mask + residual + LN2 + next layer's QKV
        const bool last = (l == Ln - 1);
        ffn2_ln_qkv<<<256, 512, 0, stream>>>(
            SCR, W2t + (size_t)l * 3 * Cn * FCn, b2 + l * Cn,
            X, ln2g + l * Cn, ln2b + l * Cn, mask,
            last ? nullptr : (Wqkv + (size_t)(l + 1) * 576 * Cn),
            last ? nullptr : (bqkv + (l + 1) * 576),
            QKT, Vb,
            last ? (float*)d_out : nullptr);
    }
}

// Round 10
// 586.147 us; speedup vs baseline: 1.9704x; 1.0266x over previous
//
#include <hip/hip_runtime.h>
#include <hip/hip_bf16.h>

// Problem constants
constexpr int Bn  = 8;
constexpr int Cn  = 192;   // hidden channels
constexpr int Tn  = 1024;  // sequence length
constexpr int Hn  = 2;     // heads
constexpr int DKn = 96;    // head dim
constexpr int FCn = 768;   // filter channels
constexpr int Ln  = 6;     // layers
constexpr int WINn = 4;    // rel-attn window
constexpr int QKS = 384;   // QK transposed row stride (Q|K concat)
constexpr int NSPLIT = 4;  // attention s-split (flash-decoding)
constexpr int RN  = Bn * Hn * Tn;  // 16384 attention rows

typedef __hip_bfloat16 bf16;
typedef __attribute__((ext_vector_type(8))) short short8;
typedef __attribute__((ext_vector_type(4))) float f32x4;

// ---------------------------------------------------------------------------
// One-time weight transforms in a single grid-stride kernel (R6).
__global__ void prep_all(
        const float* __restrict__ Wq, const float* __restrict__ Wk,
        const float* __restrict__ Wv, const float* __restrict__ bq,
        const float* __restrict__ bk, const float* __restrict__ bv,
        const float* __restrict__ Wo, const float* __restrict__ w1,
        const float* __restrict__ w2, const float* __restrict__ erk,
        const float* __restrict__ erv,
        bf16* __restrict__ Wqkv, float* __restrict__ bqkv,
        bf16* __restrict__ Wob, bf16* __restrict__ W1t, bf16* __restrict__ W2t,
        bf16* __restrict__ ERKB, bf16* __restrict__ ERVB, float qscale) {
    size_t i = (size_t)blockIdx.x * 256 + threadIdx.x;
    const size_t nW  = (size_t)Ln * 576 * Cn;     // 663,552
    const size_t nB  = (size_t)Ln * 576;
    const size_t WCn = (size_t)Ln * Cn * Cn;      // 221,184
    const size_t WFn = (size_t)Ln * 3 * FCn * Cn; // 2,654,208
    if (i < nW) {        // fused QKV weight (qscale folded into Q)
        int c = i % Cn, f = (i / Cn) % 576, l = i / (Cn * 576);
        float v;
        if (f < 192)      v = Wq[((size_t)l * Cn + f) * Cn + c] * qscale;
        else if (f < 384) v = Wk[((size_t)l * Cn + f - 192) * Cn + c];
        else              v = Wv[((size_t)l * Cn + f - 384) * Cn + c];
        Wqkv[i] = __float2bfloat16(v);
        return;
    }
    i -= nW;
    if (i < nB) {        // fused QKV bias
        int f = i % 576, l = i / 576;
        float v;
        if (f < 192)      v = bq[l * Cn + f] * qscale;
        else if (f < 384) v = bk[l * Cn + f - 192];
        else              v = bv[l * Cn + f - 384];
        bqkv[i] = v;
        return;
    }
    i -= nB;
    if (i < WCn) {       // Wo cast
        Wob[i] = __float2bfloat16(Wo[i]);
        return;
    }
    i -= WCn;
    if (i < WFn) {       // w1 [L][FC][C][3] -> [L][3][FC][C]
        int c = i % Cn;
        int f = (i / Cn) % FCn;
        int ko = (i / (Cn * FCn)) % 3;
        int l = i / (3 * Cn * FCn);
        W1t[i] = __float2bfloat16(w1[(((size_t)(l * FCn + f)) * Cn + c) * 3 + ko]);
        return;
    }
    i -= WFn;
    if (i < WFn) {       // w2 [L][C][FC][3] -> [L][3][C][FC]
        int c = i % FCn;
        int f = (i / FCn) % Cn;
        int ko = (i / (FCn * Cn)) % 3;
        int l = i / (3 * FCn * Cn);
        W2t[i] = __float2bfloat16(w2[(((size_t)(l * Cn + f)) * FCn + c) * 3 + ko]);
        return;
    }
    i -= WFn;
    if (i < (size_t)Ln * 16 * 96) {   // erk -> [L][16][96], rows 9..15 zero
        int d = i % 96, row = (i / 96) % 16, l = i / (96 * 16);
        float v = (row < 9) ? erk[((size_t)l * 9 + row) * 96 + d] : 0.f;
        ERKB[i] = __float2bfloat16(v);
        return;
    }
    i -= (size_t)Ln * 16 * 96;
    if (i < (size_t)Ln * 96 * 32) {   // erv -> [L][96][32] transposed, k 9..31 zero
        int k = i & 31, d = (i >> 5) % 96, l = i / (96 * 32);
        float v = (k < 9) ? erv[((size_t)l * 9 + k) * 96 + d] : 0.f;
        ERVB[i] = __float2bfloat16(v);
    }
}

// ---------------------------------------------------------------------------
// Input: X = x*mask (fp32, NCT) + XT = bf16 transposed [b][t][c]
__global__ __launch_bounds__(256) void cvt_in_k(
        const float* __restrict__ x, const float* __restrict__ mask,
        float* __restrict__ X, bf16* __restrict__ XT) {
    __shared__ float tile[Cn][33];
    const int tid = threadIdx.x, lane = tid & 31, w = tid >> 5;
    const int b = blockIdx.x >> 5;
    const int t0 = (blockIdx.x & 31) * 32;
    const float mk = mask[b * Tn + t0 + lane];
    for (int c = w; c < Cn; c += 8) {
        float v = x[((b * Cn + c) * Tn) + t0 + lane] * mk;
        X[((b * Cn + c) * Tn) + t0 + lane] = v;
        tile[c][lane] = v;
    }
    __syncthreads();
    for (int idx = tid; idx < 32 * Cn; idx += 256) {
        int tl = idx / Cn, c = idx % Cn;
        XT[((size_t)b * Tn + t0 + tl) * Cn + c] = __float2bfloat16(tile[c][tl]);
    }
}

// ---------------------------------------------------------------------------
// MFMA conv1d, LDS-staged, TT=128 for K-heavy convs, T14 async-STAGE (R4).
// MODE 2: bf16 transposed [b][t][CO] out relu(+bias)*mask   [FFN1]
// MODE 4: QKV split: f<384 -> bf16 T (stride QKS) into Y0; else bf16 NCT Y1
//         (used only for layer 0; layers 1..5 get QKV from ffn2_ln_qkv)
template <int KS, int TT, int MODE, int NSP>
__global__ __launch_bounds__(256) void conv_mfma(
        const bf16* __restrict__ Xt, const bf16* __restrict__ W,
        const float* __restrict__ bias, const float* __restrict__ mask,
        void* __restrict__ Y0, void* __restrict__ Y1, int CIN, int CO) {
    constexpr int PAD = KS / 2;
    constexpr int NMB = TT / 16;
    constexpr int AR  = TT + KS - 1;        // A rows staged
    constexpr int RS  = 72;                 // padded row stride (bf16 cols)
    constexpr int NA  = (AR * 8 + 255) / 256;  // per-thread A short8 loads
    constexpr int NB  = KS * 2;                // per-thread B short8 loads
    __shared__ bf16 As[AR][RS];
    __shared__ bf16 Bs[KS][64][RS];

    const int tid = threadIdx.x;
    const int wv = tid >> 6, lane = tid & 63;
    const int m = lane & 15, kq = lane >> 4;
    const int b = blockIdx.z / NSP, ks = blockIdx.z % NSP;
    const int t0 = blockIdx.x * TT;
    const int f0 = blockIdx.y * 64;
    const int f = f0 + wv * 16 + m;

    const bf16* xb = Xt + (size_t)b * Tn * CIN;
    const size_t wko = (size_t)CO * CIN;

    int rA[NA], cA[NA];
    bool vA[NA];
#pragma unroll
    for (int i = 0; i < NA; ++i) {
        int s = tid + i * 256;
        rA[i] = s >> 3; cA[i] = (s & 7) * 8; vA[i] = (s < AR * 8);
    }
    int rB[NB], cB[NB], koB[NB];
#pragma unroll
    for (int i = 0; i < NB; ++i) {
        int s = tid + i * 256;          // always < KS*512
        koB[i] = s >> 9; rB[i] = (s >> 3) & 63; cB[i] = (s & 7) * 8;
    }

    short8 pa[NA], pb[NB];
    const int cbeg = ks * (CIN / NSP);
    const int cend = cbeg + CIN / NSP;

    auto issue = [&](int c0) {
#pragma unroll
        for (int i = 0; i < NA; ++i) {
            short8 v = {0, 0, 0, 0, 0, 0, 0, 0};
            if (vA[i]) {
                int gt = t0 + rA[i] - PAD;
                if (PAD == 0 || (unsigned)gt < (unsigned)Tn)
                    v = *(const short8*)(xb + (size_t)gt * CIN + c0 + cA[i]);
            }
            pa[i] = v;
        }
#pragma unroll
        for (int i = 0; i < NB; ++i)
            pb[i] = *(const short8*)(W + (size_t)koB[i] * wko +
                                     (size_t)(f0 + rB[i]) * CIN + c0 + cB[i]);
    };
    auto commit = [&]() {
#pragma unroll
        for (int i = 0; i < NA; ++i)
            if (vA[i]) *(short8*)&As[rA[i]][cA[i]] = pa[i];
#pragma unroll
        for (int i = 0; i < NB; ++i)
            *(short8*)&Bs[koB[i]][rB[i]][cB[i]] = pb[i];
    };

    f32x4 acc[NMB] = {};

    issue(cbeg);
    commit();
    __syncthreads();

    for (int c0 = cbeg; c0 < cend; c0 += 64) {
        const bool nxt = (c0 + 64 < cend);
        if (nxt) issue(c0 + 64);
#pragma unroll
        for (int kk = 0; kk < 2; ++kk)
#pragma unroll
            for (int ko = 0; ko < KS; ++ko) {
                short8 bfr = *(const short8*)&Bs[ko][wv * 16 + m][kk * 32 + kq * 8];
#pragma unroll
                for (int mb = 0; mb < NMB; ++mb) {
                    short8 afr = *(const short8*)&As[mb * 16 + m + ko][kk * 32 + kq * 8];
                    acc[mb] = __builtin_amdgcn_mfma_f32_16x16x32_bf16(afr, bfr, acc[mb], 0, 0, 0);
                }
            }
        if (nxt) {
            __syncthreads();   // all fragment reads of this chunk complete
            commit();
            __syncthreads();   // staged data visible
        }
    }

    const float bs = bias[f];
    if (MODE == 2) {
        bf16* Y = (bf16*)Y0;
#pragma unroll
        for (int mb = 0; mb < NMB; ++mb)
#pragma unroll
            for (int r = 0; r < 4; ++r) {
                int t = t0 + mb * 16 + kq * 4 + r;
                float v = fmaxf(acc[mb][r] + bs, 0.f) * mask[b * Tn + t];
                Y[((size_t)b * Tn + t) * CO + f] = __float2bfloat16(v);
            }
    } else {  // MODE 4
        if (blockIdx.y < 6) {          // Q|K -> transposed, stride QKS
            bf16* Y = (bf16*)Y0;
#pragma unroll
            for (int mb = 0; mb < NMB; ++mb)
#pragma unroll
                for (int r = 0; r < 4; ++r) {
                    int t = t0 + mb * 16 + kq * 4 + r;
                    Y[((size_t)b * Tn + t) * QKS + f] = __float2bfloat16(acc[mb][r] + bs);
                }
        } else {                        // V -> bf16 NCT
            bf16* Y = (bf16*)Y1 + ((size_t)b * Cn + f - 384) * Tn;
#pragma unroll
            for (int mb = 0; mb < NMB; ++mb) {
                int t = t0 + mb * 16 + kq * 4;
                bf16 tmp[4];
#pragma unroll
                for (int r = 0; r < 4; ++r) tmp[r] = __float2bfloat16(acc[mb][r] + bs);
                *(uint2*)(Y + t) = *(uint2*)tmp;
            }
        }
    }
}

// ---------------------------------------------------------------------------
// R8: wo_ln_k at 512 threads / 8 waves (2 waves/SIMD). Waves map as
// 4 f-groups (48 ch) x 2 t-groups (16 rows); per-wave acc[3].
__global__ __launch_bounds__(512) void wo_ln_k(
        const bf16* __restrict__ Op, const float* __restrict__ Lp,
        const bf16* __restrict__ W, const float* __restrict__ bias,
        float* __restrict__ X, const float* __restrict__ G,
        const float* __restrict__ Bt, const float* __restrict__ mask,
        bf16* __restrict__ XT) {
    __shared__ bf16 As[32][72];       // combined attn out [t][c-chunk]
    __shared__ bf16 Bs[192][72];      // Wo panel [f][c-chunk]
    __shared__ float sm1[8][16];
    __shared__ float sm2[8][16];

    const int tid = threadIdx.x;
    const int wv = tid >> 6, lane = tid & 63;
    const int m = lane & 15, quad = lane >> 4;
    const int fg = wv & 3, tg = wv >> 2;
    const int b = blockIdx.x & 7;
    const int t0 = (blockIdx.x >> 3) * 32;

    const bool vA = (tid < 256);
    const int rA = tid >> 3, cA = (tid & 7) * 8;   // A: 32 rows x 8 short8
    short8 pa6[4]; float pl6[4];
    short8 pb[3];                                   // B: 1536 short8 / 512

    auto issue = [&](int c0) {
        if (vA) {
            int c = c0 + cA;
            int hh = (c >= 96) ? 1 : 0;
            int rid = (b * Hn + hh) * Tn + t0 + rA;
            int d0 = c - 96 * hh;
#pragma unroll
            for (int sp = 0; sp < 4; ++sp) {
                pa6[sp] = *(const short8*)(Op + ((size_t)sp * RN + rid) * 96 + d0);
                pl6[sp] = Lp[sp * RN + rid];
            }
        }
#pragma unroll
        for (int i = 0; i < 3; ++i) {
            int s = tid + i * 512;
            pb[i] = *(const short8*)(W + (size_t)(s >> 3) * Cn + c0 + (s & 7) * 8);
        }
    };
    auto commit = [&]() {
        if (vA) {
            float denom = pl6[0] + pl6[1] + pl6[2] + pl6[3];
            float inv = 1.f / fmaxf(denom, 1e-30f);
            bf16 tmp[8];
#pragma unroll
            for (int e = 0; e < 8; ++e) {
                float o = 0.f;
#pragma unroll
                for (int sp = 0; sp < 4; ++sp)
                    o += __bfloat162float(((const bf16*)&pa6[sp])[e]);
                tmp[e] = __float2bfloat16(o * inv);
            }
            *(short8*)&As[rA][cA] = *(const short8*)tmp;
        }
#pragma unroll
        for (int i = 0; i < 3; ++i) {
            int s = tid + i * 512;
            *(short8*)&Bs[s >> 3][(s & 7) * 8] = pb[i];
        }
    };

    f32x4 acc[3] = {};

    issue(0);
    commit();
    __syncthreads();
    for (int c0 = 0; c0 < Cn; c0 += 64) {
        const bool nxt = (c0 + 64 < Cn);
        if (nxt) issue(c0 + 64);
#pragma unroll
        for (int kk = 0; kk < 2; ++kk) {
            short8 afr = *(const short8*)&As[tg * 16 + m][kk * 32 + quad * 8];
#pragma unroll
            for (int fb = 0; fb < 3; ++fb) {
                short8 bfr = *(const short8*)&Bs[fg * 48 + fb * 16 + m][kk * 32 + quad * 8];
                acc[fb] = __builtin_amdgcn_mfma_f32_16x16x32_bf16(afr, bfr, acc[fb], 0, 0, 0);
            }
        }
        if (nxt) {
            __syncthreads();
            commit();
            __syncthreads();
        }
    }

    // bias + residual; per-t LN stats over this lane's 3 channels
    const int tq = t0 + tg * 16 + quad * 4;
    float s1[4] = {}, s2[4] = {};
#pragma unroll
    for (int fb = 0; fb < 3; ++fb) {
        const int f = fg * 48 + fb * 16 + m;
        const float bsv = bias[f];
        float4 xv = *(const float4*)(X + ((size_t)(b * Cn + f)) * Tn + tq);
        acc[fb][0] += bsv + xv.x;
        acc[fb][1] += bsv + xv.y;
        acc[fb][2] += bsv + xv.z;
        acc[fb][3] += bsv + xv.w;
#pragma unroll
        for (int r = 0; r < 4; ++r) {
            float v = acc[fb][r];
            s1[r] += v;
            s2[r] += v * v;
        }
    }
#pragma unroll
    for (int r = 0; r < 4; ++r)
#pragma unroll
        for (int mk = 1; mk < 16; mk <<= 1) {
            s1[r] += __shfl_xor(s1[r], mk);
            s2[r] += __shfl_xor(s2[r], mk);
        }
    if (m == 0) {
#pragma unroll
        for (int r = 0; r < 4; ++r) {
            sm1[wv][quad * 4 + r] = s1[r];
            sm2[wv][quad * 4 + r] = s2[r];
        }
    }
    __syncthreads();
    float mean[4], rsv[4];
    float4 mk4 = *(const float4*)(mask + b * Tn + tq);
    float mtv[4] = {mk4.x, mk4.y, mk4.z, mk4.w};
#pragma unroll
    for (int r = 0; r < 4; ++r) {
        int tt = quad * 4 + r;
        float a = sm1[tg * 4 + 0][tt] + sm1[tg * 4 + 1][tt] +
                  sm1[tg * 4 + 2][tt] + sm1[tg * 4 + 3][tt];
        float q = sm2[tg * 4 + 0][tt] + sm2[tg * 4 + 1][tt] +
                  sm2[tg * 4 + 2][tt] + sm2[tg * 4 + 3][tt];
        float mn = a / Cn;
        mean[r] = mn;
        rsv[r] = rsqrtf(q / Cn - mn * mn + 1e-5f);
    }
#pragma unroll
    for (int fb = 0; fb < 3; ++fb) {
        const int f = fg * 48 + fb * 16 + m;
        const float gv = G[f], bv = Bt[f];
        float y[4];
#pragma unroll
        for (int r = 0; r < 4; ++r)
            y[r] = (acc[fb][r] - mean[r]) * rsv[r] * gv + bv;
        float4 xo;
        xo.x = y[0]; xo.y = y[1]; xo.z = y[2]; xo.w = y[3];
        *(float4*)(X + ((size_t)(b * Cn + f)) * Tn + tq) = xo;
#pragma unroll
        for (int r = 0; r < 4; ++r)
            XT[((size_t)b * Tn + tq + r) * Cn + f] =
                __float2bfloat16(y[r] * mtv[r]);
    }
}

// ---------------------------------------------------------------------------
// R10: ffn2_ln_qkv at 768 threads / 12 waves (3 waves/SIMD, was 2).
// R9 profile: 46 us/dispatch, MfmaUtil 6.9%, Occ 19% -> latency-bound at
// 1 block/CU with only 2 waves/SIMD; per-chunk MFMA (~90cy) can't hide
// the L2 B-panel loads + commit + barriers. More waves = more contexts.
// Waves: 6 f-groups (32 ch, acc[2]) x 2 t-groups. Phase 2 QKV: fg owns
// 96 ch (acc2[6]). Math identical to R9.
__global__ __launch_bounds__(768) void ffn2_ln_qkv(
        const bf16* __restrict__ Hc, const bf16* __restrict__ W,
        const float* __restrict__ bias, float* __restrict__ X,
        const float* __restrict__ G, const float* __restrict__ Bt,
        const float* __restrict__ mask,
        const bf16* __restrict__ Wqn, const float* __restrict__ bqn,
        bf16* __restrict__ QKT, bf16* __restrict__ Vb,
        float* __restrict__ OUT) {
    __shared__ bf16 As[34][72];        // hidden rows t0-1..t0+32, c-chunk
    __shared__ bf16 Bs[3][192][72];    // W2 panel [ko][f][c-chunk] (~83 KB)
    __shared__ float sm1[12][16];
    __shared__ float sm2[12][16];
    __shared__ bf16 Ys[32][200];       // LN2 output tile [t][c] (phase 2 A)

    const int tid = threadIdx.x;
    const int wv = tid >> 6, lane = tid & 63;
    const int m = lane & 15, quad = lane >> 4;
    const int fg = wv % 6, tg = wv / 6;      // 6 f-groups x 2 t-groups
    const int b = blockIdx.x & 7;
    const int t0 = (blockIdx.x >> 3) * 32;

    const bf16* hb = Hc + (size_t)b * Tn * FCn;

    const bool vA = (tid < 272);
    short8 pa, pb[6];
    auto issue = [&](int c0) {
        short8 v = {0, 0, 0, 0, 0, 0, 0, 0};
        if (vA) {
            int gt = t0 + (tid >> 3) - 1;
            if ((unsigned)gt < (unsigned)Tn)
                v = *(const short8*)(hb + (size_t)gt * FCn + c0 + (tid & 7) * 8);
        }
        pa = v;
#pragma unroll
        for (int i = 0; i < 6; ++i) {
            int s = tid + i * 768;           // < 4608 = 3*192*8
            int ko = s / 1536, rem = s - ko * 1536;
            pb[i] = *(const short8*)(W + (size_t)ko * Cn * FCn +
                                     (size_t)(rem >> 3) * FCn + c0 + (rem & 7) * 8);
        }
    };
    auto commit = [&]() {
        if (vA) *(short8*)&As[tid >> 3][(tid & 7) * 8] = pa;
#pragma unroll
        for (int i = 0; i < 6; ++i) {
            int s = tid + i * 768;
            int ko = s / 1536, rem = s - ko * 1536;
            *(short8*)&Bs[ko][rem >> 3][(rem & 7) * 8] = pb[i];
        }
    };

    f32x4 acc[2] = {};

    issue(0);
    commit();
    __syncthreads();
    for (int c0 = 0; c0 < FCn; c0 += 64) {
        const bool nxt = (c0 + 64 < FCn);
        if (nxt) issue(c0 + 64);
#pragma unroll
        for (int kk = 0; kk < 2; ++kk)
#pragma unroll
            for (int ko = 0; ko < 3; ++ko) {
                short8 afr = *(const short8*)&As[tg * 16 + m + ko][kk * 32 + quad * 8];
#pragma unroll
                for (int fb = 0; fb < 2; ++fb) {
                    short8 bfr = *(const short8*)&Bs[ko][fg * 32 + fb * 16 + m][kk * 32 + quad * 8];
                    acc[fb] = __builtin_amdgcn_mfma_f32_16x16x32_bf16(afr, bfr, acc[fb], 0, 0, 0);
                }
            }
        if (nxt) {
            __syncthreads();
            commit();
            __syncthreads();
        }
    }

    // y = (conv + bias)*mask; v = X + y; LN stats over channels
    const int tq = t0 + tg * 16 + quad * 4;
    float4 mk4 = *(const float4*)(mask + b * Tn + tq);
    float mtv[4] = {mk4.x, mk4.y, mk4.z, mk4.w};
    float s1[4] = {}, s2[4] = {};
#pragma unroll
    for (int fb = 0; fb < 2; ++fb) {
        const int f = fg * 32 + fb * 16 + m;
        const float bsv = bias[f];
        float4 xv = *(const float4*)(X + ((size_t)(b * Cn + f)) * Tn + tq);
        acc[fb][0] = xv.x + (acc[fb][0] + bsv) * mtv[0];
        acc[fb][1] = xv.y + (acc[fb][1] + bsv) * mtv[1];
        acc[fb][2] = xv.z + (acc[fb][2] + bsv) * mtv[2];
        acc[fb][3] = xv.w + (acc[fb][3] + bsv) * mtv[3];
#pragma unroll
        for (int r = 0; r < 4; ++r) {
            float v = acc[fb][r];
            s1[r] += v;
            s2[r] += v * v;
        }
    }
#pragma unroll
    for (int r = 0; r < 4; ++r)
#pragma unroll
        for (int mk = 1; mk < 16; mk <<= 1) {
            s1[r] += __shfl_xor(s1[r], mk);
            s2[r] += __shfl_xor(s2[r], mk);
        }
    if (m == 0) {
#pragma unroll
        for (int r = 0; r < 4; ++r) {
            sm1[wv][quad * 4 + r] = s1[r];
            sm2[wv][quad * 4 + r] = s2[r];
        }
    }
    __syncthreads();   // [E1] also: all Bs/As MFMA reads are now complete
    float mean[4], rsv[4];
#pragma unroll
    for (int r = 0; r < 4; ++r) {
        int tt = quad * 4 + r;
        float a = 0.f, q = 0.f;
#pragma unroll
        for (int j = 0; j < 6; ++j) {
            a += sm1[tg * 6 + j][tt];
            q += sm2[tg * 6 + j][tt];
        }
        float mn = a / Cn;
        mean[r] = mn;
        rsv[r] = rsqrtf(q / Cn - mn * mn + 1e-5f);
    }

    float y3[2][4];
#pragma unroll
    for (int fb = 0; fb < 2; ++fb) {
        const int f = fg * 32 + fb * 16 + m;
        const float gv = G[f], bv = Bt[f];
#pragma unroll
        for (int r = 0; r < 4; ++r)
            y3[fb][r] = (acc[fb][r] - mean[r]) * rsv[r] * gv + bv;
    }

    if (OUT) {      // final layer: OUT = LN(...)*mask, NCT fp32; no QKV
#pragma unroll
        for (int fb = 0; fb < 2; ++fb) {
            const int f = fg * 32 + fb * 16 + m;
            float4 xo;
            xo.x = y3[fb][0] * mtv[0]; xo.y = y3[fb][1] * mtv[1];
            xo.z = y3[fb][2] * mtv[2]; xo.w = y3[fb][3] * mtv[3];
            *(float4*)(OUT + ((size_t)(b * Cn + f)) * Tn + tq) = xo;
        }
        return;
    }

    // write X (residual stream for next layer's wo_ln_k)
#pragma unroll
    for (int fb = 0; fb < 2; ++fb) {
        const int f = fg * 32 + fb * 16 + m;
        float4 xo;
        xo.x = y3[fb][0]; xo.y = y3[fb][1]; xo.z = y3[fb][2]; xo.w = y3[fb][3];
        *(float4*)(X + ((size_t)(b * Cn + f)) * Tn + tq) = xo;
    }

    // ---- phase 2: QKV 1x1 conv for the NEXT layer ----
    bf16 (*Bq)[72] = (bf16 (*)[72])Bs;   // 576 rows x 72 — same footprint

    short8 pbq[6];
    auto issueQ = [&](int c0) {
#pragma unroll
        for (int i = 0; i < 6; ++i) {
            int s = tid + i * 768;           // < 4608 = 576*8
            pbq[i] = *(const short8*)(Wqn + (size_t)(s >> 3) * Cn + c0 + (s & 7) * 8);
        }
    };
    auto commitQ = [&]() {
#pragma unroll
        for (int i = 0; i < 6; ++i) {
            int s = tid + i * 768;
            *(short8*)&Bq[s >> 3][(s & 7) * 8] = pbq[i];
        }
    };

    issueQ(0);
    // drop y (unmasked, matching old XT semantics) into the LDS A-tile
#pragma unroll
    for (int fb = 0; fb < 2; ++fb) {
        const int f = fg * 32 + fb * 16 + m;
#pragma unroll
        for (int r = 0; r < 4; ++r)
            Ys[tg * 16 + quad * 4 + r][f] = __float2bfloat16(y3[fb][r]);
    }
    commitQ();           // safe: all Bs reads precede [E1]
    __syncthreads();     // Ys + Bq chunk 0 visible

    f32x4 acc2[6] = {};
    for (int c0 = 0; c0 < Cn; c0 += 64) {
        const bool nxt = (c0 + 64 < Cn);
        if (nxt) issueQ(c0 + 64);
#pragma unroll
        for (int kk = 0; kk < 2; ++kk) {
            short8 afr = *(const short8*)&Ys[tg * 16 + m][c0 + kk * 32 + quad * 8];
#pragma unroll
            for (int fb = 0; fb < 6; ++fb) {
                short8 bfr = *(const short8*)&Bq[fg * 96 + fb * 16 + m][kk * 32 + quad * 8];
                acc2[fb] = __builtin_amdgcn_mfma_f32_16x16x32_bf16(afr, bfr, acc2[fb], 0, 0, 0);
            }
        }
        if (nxt) {
            __syncthreads();
            commitQ();
            __syncthreads();
        }
    }

    // epilogue: QKT transposed (f<384) / Vb NCT (f>=384), bias added
#pragma unroll
    for (int fb = 0; fb < 6; ++fb) {
        const int f = fg * 96 + fb * 16 + m;
        const float bsv = bqn[f];
        if (f < 384) {
#pragma unroll
            for (int r = 0; r < 4; ++r)
                QKT[((size_t)b * Tn + tq + r) * QKS + f] =
                    __float2bfloat16(acc2[fb][r] + bsv);
        } else {
            bf16 tmp[4];
#pragma unroll
            for (int r = 0; r < 4; ++r) tmp[r] = __float2bfloat16(acc2[fb][r] + bsv);
            *(uint2*)(Vb + ((size_t)b * Cn + f - 384) * Tn + tq) = *(uint2*)tmp;
        }
    }
}

// ---------------------------------------------------------------------------
// MFMA flash attention. R8: 8 waves / QBLK=128 per block (512 threads,
// grid 512). XCD swizzle (R2), T14 async-STAGE (R2), rel-V via MFMA (R3),
// ones-MFMA rowsum + gating + setprio (R5). FIXED-MAX softmax.
// Writes UNNORMALIZED partials: Op bf16 [sp][rid][96], Lp fp32 [sp][rid].
__global__ __launch_bounds__(512) void attn_mfma(
        const bf16* __restrict__ QK, const bf16* __restrict__ V,
        const float* __restrict__ mask, const bf16* __restrict__ erkb,
        const bf16* __restrict__ ervb, bf16* __restrict__ Op,
        float* __restrict__ Lp, int layer) {
    __shared__ bf16 Ks[64][100];      // K chunk [s][d]
    __shared__ bf16 Vs[96][68];       // V chunk [d][s]
    __shared__ float rq[8][16][17];   // per-wave rel-K band: [m][dd]
    __shared__ bf16 pT[8][16][68];    // per-wave P: [m][s]
    __shared__ bf16 pdg[8][16][16];   // per-wave rel-V band: [m][dd], 9..15 zero
    // LDS total: 56064 B -> 2 blocks/CU

    const int tid = threadIdx.x, wv = tid >> 6, lane = tid & 63;
    const int col = lane & 15, quad = lane >> 4;
    // XCD-bijective swizzle (512 = 8 XCD x 64)
    const int w = (blockIdx.x & 7) * 64 + (blockIdx.x >> 3);
    const int t0 = (w & 7) * 128;
    const int yz = w >> 3;
    const int h = yz & 1;
    const int z = yz >> 1;
    const int b = z >> 2, sp = z & 3;
    const int hd = h * DKn;
    const int t0w = t0 + wv * 16;

    *(uint2*)&pdg[wv][col][quad * 4] = (uint2){0, 0};

    const bool g2 = (tid < 256);
    int rK[2], cK[2], rV[2], cV[2];
    {
        int s = tid;
        rK[0] = s / 12; cK[0] = (s % 12) * 8;   // 64 rows x 96 cols
        rV[0] = s >> 3; cV[0] = (s & 7) * 8;    // 96 rows x 64 cols
        s = tid + 512;
        rK[1] = s / 12; cK[1] = (s % 12) * 8;   // valid only if g2
        rV[1] = s >> 3; cV[1] = (s & 7) * 8;
    }
    const bf16* kbase = QK + (size_t)b * Tn * QKS + 192 + hd;
    const bf16* vbase = V + ((size_t)b * Cn + hd) * Tn;

    short8 kst[2], vst[2];
    const int sbeg = sp * (Tn / NSPLIT);
    const int send = sbeg + Tn / NSPLIT;

    kst[0] = *(const short8*)(kbase + (size_t)(sbeg + rK[0]) * QKS + cK[0]);
    vst[0] = *(const short8*)(vbase + (size_t)rV[0] * Tn + sbeg + cV[0]);
    if (g2) {
        kst[1] = *(const short8*)(kbase + (size_t)(sbeg + rK[1]) * QKS + cK[1]);
        vst[1] = *(const short8*)(vbase + (size_t)rV[1] * Tn + sbeg + cV[1]);
    }

    short8 aq[3];
    {
        const bf16* qrow = QK + ((size_t)b * Tn + t0w + col) * QKS + hd + quad * 8;
#pragma unroll
        for (int kd = 0; kd < 3; ++kd) aq[kd] = *(const short8*)(qrow + kd * 32);
    }
    {
        const bf16* erow = erkb + ((size_t)layer * 16 + col) * 96 + quad * 8;
        f32x4 R = {};
#pragma unroll
        for (int kd = 0; kd < 3; ++kd) {
            short8 be = *(const short8*)(erow + kd * 32);
            R = __builtin_amdgcn_mfma_f32_16x16x32_bf16(aq[kd], be, R, 0, 0, 0);
        }
#pragma unroll
        for (int r = 0; r < 4; ++r) rq[wv][quad * 4 + r][col] = R[r];
    }
    float mtv[4];
#pragma unroll
    for (int r = 0; r < 4; ++r) mtv[r] = mask[b * Tn + t0w + quad * 4 + r];
    const bool qok = __all(mtv[0] != 0.f && mtv[1] != 0.f &&
                           mtv[2] != 0.f && mtv[3] != 0.f);
    int okbits = 0;
    if (qok) {
#pragma unroll
        for (int ch = 0; ch < 4; ++ch) {
            int sc = b * Tn + sbeg + ch * 64 + col;
            float a0 = mask[sc], a1 = mask[sc + 16], a2 = mask[sc + 32], a3 = mask[sc + 48];
            if (__all(a0 != 0.f && a1 != 0.f && a2 != 0.f && a3 != 0.f))
                okbits |= 1 << ch;
        }
    }

    *(short8*)&Ks[rK[0]][cK[0]] = kst[0];
    *(short8*)&Vs[rV[0]][cV[0]] = vst[0];
    if (g2) {
        *(short8*)&Ks[rK[1]][cK[1]] = kst[1];
        *(short8*)&Vs[rV[1]][cV[1]] = vst[1];
    }
    __syncthreads();

    f32x4 O[6] = {};
    f32x4 Osum = {};
    short8 ones;
#pragma unroll
    for (int j = 0; j < 8; ++j) ones[j] = (short)0x3F80;   // bf16 1.0

    for (int s0 = sbeg; s0 < send; s0 += 64) {
        const bool nxt = (s0 + 64 < send);
        if (nxt) {
            kst[0] = *(const short8*)(kbase + (size_t)(s0 + 64 + rK[0]) * QKS + cK[0]);
            vst[0] = *(const short8*)(vbase + (size_t)rV[0] * Tn + s0 + 64 + cV[0]);
            if (g2) {
                kst[1] = *(const short8*)(kbase + (size_t)(s0 + 64 + rK[1]) * QKS + cK[1]);
                vst[1] = *(const short8*)(vbase + (size_t)rV[1] * Tn + s0 + 64 + cV[1]);
            }
        }

        f32x4 S[4] = {};
        __builtin_amdgcn_s_setprio(1);
#pragma unroll
        for (int nb = 0; nb < 4; ++nb)
#pragma unroll
            for (int kd = 0; kd < 3; ++kd) {
                short8 bkf = *(const short8*)&Ks[16 * nb + col][kd * 32 + quad * 8];
                S[nb] = __builtin_amdgcn_mfma_f32_16x16x32_bf16(aq[kd], bkf, S[nb], 0, 0, 0);
            }
        __builtin_amdgcn_s_setprio(0);

        const bool diag = (s0 <= t0w + 15 + WINn) && (s0 + 63 >= t0w - WINn);
        if (diag) {
#pragma unroll
            for (int nb = 0; nb < 4; ++nb) {
                const int sg = s0 + 16 * nb + col;
#pragma unroll
                for (int r = 0; r < 4; ++r) {
                    int dd = sg - (t0w + quad * 4 + r) + WINn;
                    if ((unsigned)dd <= 2u * WINn) S[nb][r] += rq[wv][quad * 4 + r][dd];
                }
            }
        }
        if (!((okbits >> ((s0 - sbeg) >> 6)) & 1)) {
#pragma unroll
            for (int nb = 0; nb < 4; ++nb) {
                const float msv = mask[b * Tn + s0 + 16 * nb + col];
#pragma unroll
                for (int r = 0; r < 4; ++r)
                    if (msv * mtv[r] == 0.f) S[nb][r] = -1e4f;
            }
        }

        if (diag) {
#pragma unroll
            for (int nb = 0; nb < 4; ++nb) {
                const int sg = s0 + 16 * nb + col;
#pragma unroll
                for (int r = 0; r < 4; ++r) {
                    bf16 pb_ = __float2bfloat16(__expf(S[nb][r]));
                    pT[wv][quad * 4 + r][16 * nb + col] = pb_;
                    int dd = sg - (t0w + quad * 4 + r) + WINn;
                    if ((unsigned)dd <= 2u * WINn) pdg[wv][quad * 4 + r][dd] = pb_;
                }
            }
        } else {
#pragma unroll
            for (int nb = 0; nb < 4; ++nb)
#pragma unroll
                for (int r = 0; r < 4; ++r)
                    pT[wv][quad * 4 + r][16 * nb + col] =
                        __float2bfloat16(__expf(S[nb][r]));
        }

        short8 aP[2];
#pragma unroll
        for (int kk = 0; kk < 2; ++kk)
            aP[kk] = *(const short8*)&pT[wv][col][kk * 32 + quad * 8];
        __builtin_amdgcn_s_setprio(1);
#pragma unroll
        for (int nd = 0; nd < 6; ++nd)
#pragma unroll
            for (int kk = 0; kk < 2; ++kk) {
                short8 bvf = *(const short8*)&Vs[16 * nd + col][kk * 32 + quad * 8];
                O[nd] = __builtin_amdgcn_mfma_f32_16x16x32_bf16(aP[kk], bvf, O[nd], 0, 0, 0);
            }
#pragma unroll
        for (int kk = 0; kk < 2; ++kk)
            Osum = __builtin_amdgcn_mfma_f32_16x16x32_bf16(aP[kk], ones, Osum, 0, 0, 0);
        __builtin_amdgcn_s_setprio(0);

        __syncthreads();
        if (nxt) {
            *(short8*)&Ks[rK[0]][cK[0]] = kst[0];
            *(short8*)&Vs[rV[0]][cV[0]] = vst[0];
            if (g2) {
                *(short8*)&Ks[rK[1]][cK[1]] = kst[1];
                *(short8*)&Vs[rV[1]][cV[1]] = vst[1];
            }
            __syncthreads();
        }
    }

    // rel-V band contribution: O += pdg(16x16, k 9..15 zero) . ERVB(k x 96)
    {
        short8 ad = {0, 0, 0, 0, 0, 0, 0, 0};
        if (quad < 2) ad = *(const short8*)&pdg[wv][col][quad * 8];
        const bf16* eb = ervb + (size_t)layer * 96 * 32 + (size_t)col * 32 + quad * 8;
#pragma unroll
        for (int nd = 0; nd < 6; ++nd) {
            short8 bd = *(const short8*)(eb + (size_t)nd * 16 * 32);
            O[nd] = __builtin_amdgcn_mfma_f32_16x16x32_bf16(ad, bd, O[nd], 0, 0, 0);
        }
    }

    // epilogue: write unnormalized partials (Lp row-sums come from Osum)
    const int rbase = (b * Hn + h) * Tn + t0w;
#pragma unroll
    for (int r = 0; r < 4; ++r) {
        const int rid = rbase + quad * 4 + r;
        bf16* dst = Op + ((size_t)sp * RN + rid) * 96 + col;
#pragma unroll
        for (int nd = 0; nd < 6; ++nd)
            dst[16 * nd] = __float2bfloat16(O[nd][r]);
        if (col == 0) Lp[sp * RN + rid] = Osum[r];
    }
}

// ---------------------------------------------------------------------------
extern "C" void kernel_launch(void* const* d_in, const int* in_sizes, int n_in,
                              void* d_out, int out_size, void* d_ws, size_t ws_size,
                              hipStream_t stream) {
    const float* x    = (const float*)d_in[0];
    const float* mask = (const float*)d_in[1];
    const float* Wq   = (const float*)d_in[2];
    const float* bq   = (const float*)d_in[3];
    const float* Wk   = (const float*)d_in[4];
    const float* bk   = (const float*)d_in[5];
    const float* Wv   = (const float*)d_in[6];
    const float* bv   = (const float*)d_in[7];
    const float* Wo   = (const float*)d_in[8];
    const float* bo   = (const float*)d_in[9];
    const float* erk  = (const float*)d_in[10];
    const float* erv  = (const float*)d_in[11];
    const float* ln1g = (const float*)d_in[12];
    const float* ln1b = (const float*)d_in[13];
    const float* w1   = (const float*)d_in[14];
    const float* b1   = (const float*)d_in[15];
    const float* w2   = (const float*)d_in[16];
    const float* b2   = (const float*)d_in[17];
    const float* ln2g = (const float*)d_in[18];
    const float* ln2b = (const float*)d_in[19];

    const size_t N = (size_t)Bn * Cn * Tn;         // 1,572,864
    const int WC = Ln * Cn * Cn;                   // 221,184
    const size_t WF = (size_t)Ln * 3 * FCn * Cn;   // 2,654,208
    const size_t WQKV = (size_t)Ln * 576 * Cn;     // 663,552
    const size_t NSCR = (size_t)Bn * Tn * FCn;     // 6,291,456 == NSPLIT*RN*96

    float* X    = (float*)d_ws;
    float* Yb   = X + N;                           // (unused since R7)
    float* bqkv = Yb + N;                          // L*576 floats
    float* Lp   = bqkv + Ln * 576;                 // NSPLIT*RN floats
    bf16* p16 = (bf16*)(Lp + (size_t)NSPLIT * RN);
    bf16* XT   = p16; p16 += N;
    bf16* QKT  = p16; p16 += (size_t)Bn * Tn * QKS;  // 2N bf16
    bf16* Vb   = p16; p16 += N;
    bf16* AT   = p16; p16 += N;      // (unused; kept for layout)
    bf16* SCR  = p16; p16 += NSCR;   // shared: attn O-partials <-> FFN hidden
    bf16* Wqkv = p16; p16 += WQKV;
    bf16* Wob  = p16; p16 += WC;
    bf16* W1t  = p16; p16 += WF;
    bf16* W2t  = p16; p16 += WF;
    bf16* ERKB = p16; p16 += Ln * 16 * 96;
    bf16* ERVB = p16; p16 += Ln * 96 * 32;
    (void)AT; (void)Yb;

    const float qscale = 0.10206207261596575f;  // 1/sqrt(96)

    // one-time transforms: single fused dispatch
    const size_t nprep = WQKV + Ln * 576 + WC + 2 * WF +
                         (size_t)Ln * 16 * 96 + (size_t)Ln * 96 * 32;
    prep_all<<<(int)((nprep + 255) / 256), 256, 0, stream>>>(
        Wq, Wk, Wv, bq, bk, bv, Wo, w1, w2, erk, erv,
        Wqkv, bqkv, Wob, W1t, W2t, ERKB, ERVB, qscale);
    cvt_in_k<<<Bn * 32, 256, 0, stream>>>(x, mask, X, XT);

    // layer 0's QKV from XT (standalone conv); layers 1..5 get QKV fused
    // into the previous layer's ffn2_ln_qkv.
    conv_mfma<1, 128, 4, 1><<<dim3(Tn / 128, 9, Bn), 256, 0, stream>>>(
        XT, Wqkv, bqkv, nullptr, QKT, Vb, Cn, 576);

    for (int l = 0; l < Ln; ++l) {
        attn_mfma<<<dim3(512), 512, 0, stream>>>(
            QKT, Vb, mask, ERKB, ERVB, SCR, Lp, l);
        // fused: split-combine + Wo conv + residual + LN1 + X/XT write
        wo_ln_k<<<256, 512, 0, stream>>>(
            SCR, Lp, Wob + (size_t)l * Cn * Cn, bo + l * Cn,
            X, ln1g + l * Cn, ln1b + l * Cn, mask, XT);
        conv_mfma<3, 128, 2, 1><<<dim3(Tn / 128, FCn / 64, Bn), 256, 0, stream>>>(
            XT, W1t + (size_t)l * 3 * FCn * Cn, b1 + l * FCn, mask, SCR, nullptr, Cn, FCn);
        // fused: FFN2 conv + mask + residual + LN2 + next layer's QKV
        const bool last = (l == Ln - 1);
        ffn2_ln_qkv<<<256, 768, 0, stream>>>(
            SCR, W2t + (size_t)l * 3 * Cn * FCn, b2 + l * Cn,
            X, ln2g + l * Cn, ln2b + l * Cn, mask,
            last ? nullptr : (Wqkv + (size_t)(l + 1) * 576 * Cn),
            last ? nullptr : (bqkv + (l + 1) * 576),
            QKT, Vb,
            last ? (float*)d_out : nullptr);
    }
}